// Round 20
// baseline (1002.501 us; speedup 1.0000x reference)
//
#include <hip/hip_runtime.h>

typedef unsigned short u16;
typedef unsigned int u32;
typedef short s16x8 __attribute__((ext_vector_type(8)));
typedef __bf16 bf16x8 __attribute__((ext_vector_type(8)));
typedef float f32x4 __attribute__((ext_vector_type(4)));

#define DEVI static __device__ __forceinline__

#define SS 512
#define DD 512
#define NFF 2048
#define VV 32000
#define MTOT 4096
#define HD 4096
#define KC 1536   // virtual split-concat K (2-band storage + read-time remap)

DEVI float bf2f(u16 h){ return __uint_as_float(((u32)h) << 16); }
DEVI u16 f2bf(float f){
  u32 u = __float_as_uint(f);
  return (u16)((u + 0x7FFFu + ((u >> 16) & 1u)) >> 16);
}
DEVI float ldf(const void* p, long i, int isbf){
  return isbf ? bf2f(((const u16*)p)[i]) : ((const float*)p)[i];
}

DEVI f32x4 mfma16(s16x8 a, s16x8 b, f32x4 c){
  return __builtin_amdgcn_mfma_f32_16x16x32_bf16(
      __builtin_bit_cast(bf16x8, a), __builtin_bit_cast(bf16x8, b), c, 0, 0, 0);
}

// direct global->LDS 16B copy; dst is wave-uniform base + lane*16, src per-lane
typedef const __attribute__((address_space(1))) unsigned int* gup;
typedef __attribute__((address_space(3))) unsigned int* lup;
DEVI void gload16(const void* g, void* l){
  __builtin_amdgcn_global_load_lds((gup)g, (lup)l, 16, 0, 0);
}

DEVI float wave_redsum(float v){
  #pragma unroll
  for (int off = 32; off > 0; off >>= 1) v += __shfl_xor(v, off, 64);
  return v;
}

// pe row0 = [sin0=0, cos0=1, ...]: first u32 word = 0x3F800000 if bf16, 0x00000000 if f32
__global__ void k_dflag(const void* pe, int* flag){
  flag[0] = (*(const u32*)pe == 0x3F800000u) ? 1 : 0;
}

// embed + residual + masked 2-band split: xm2[m][0:512]=hi, [512:1024]=lo
__global__ __launch_bounds__(256) void k_embed(
    const int* __restrict__ tok, const void* __restrict__ emb, const void* __restrict__ pe,
    float* __restrict__ x, u16* __restrict__ xm2, const int* __restrict__ dflag)
{
  int isbf = dflag[0];
  int blk = blockIdx.x;
  int s = blk & (SS - 1);
  int t = tok[blk];
  long rb = (long)blk * 1024;
  for (int d = threadIdx.x; d < DD; d += 256){
    float e = ldf(emb, (long)t * DD + d, isbf) + ldf(pe, (long)s * DD + d, isbf);
    x[(long)blk * DD + d] = e;
    float m = (d <= s) ? e : 0.f;           // triu(ones(S,D),k=1) zeroes d > s
    u16 hi = f2bf(m);
    u16 lo = f2bf(m - bf2f(hi));
    xm2[rb + d] = hi;
    xm2[rb + 512 + d] = lo;
  }
}

// split-transpose for Wq AND Wk (zz<8: Wq slice zz; else Wk slice zz-8):
// in W[z][512 d][512 e] -> out[z][512 e][1024]: band0=hi, band1=lo
__global__ __launch_bounds__(256) void k_wsplitT(
    const void* __restrict__ Wq, const void* __restrict__ Wk,
    u16* __restrict__ Wq2, u16* __restrict__ Wk2, const int* __restrict__ dflag)
{
  int isbf = dflag[0];
  int zz = blockIdx.z;
  const void* in = (zz < 8) ? Wq : Wk;
  u16* out = (zz < 8) ? Wq2 : Wk2;
  int z = zz & 7;
  long zin = (long)z * DD * DD;
  long zout = (long)z * DD * 1024;
  __shared__ float t[32][33];
  int e0 = blockIdx.x * 32, d0 = blockIdx.y * 32;
  int tx = threadIdx.x & 31, ty = threadIdx.x >> 5;
  #pragma unroll
  for (int i = 0; i < 4; i++){
    int d = ty + i * 8;
    t[d][tx] = ldf(in, zin + (long)(d0 + d) * DD + e0 + tx, isbf);
  }
  __syncthreads();
  #pragma unroll
  for (int i = 0; i < 4; i++){
    int e = ty + i * 8;
    float v = t[tx][e];
    u16 hi = f2bf(v);
    u16 lo = f2bf(v - bf2f(hi));
    long ob = zout + (long)(e0 + e) * 1024 + d0 + tx;
    out[ob] = hi;
    out[ob + 512] = lo;
  }
}

// all 5 plain transposes (f32/bf16 -> bf16) in one flat-grid kernel.
__global__ __launch_bounds__(256) void k_transAll(
    const void* __restrict__ Wv, const void* __restrict__ Wo,
    const void* __restrict__ W1, const void* __restrict__ W2,
    const void* __restrict__ Wf,
    u16* __restrict__ WvT, u16* __restrict__ WoT, u16* __restrict__ W1T,
    u16* __restrict__ W2T, u16* __restrict__ WfT, const int* __restrict__ dflag)
{
  int isbf = dflag[0];
  int f = blockIdx.x;
  const void* in; u16* out; int R, C, gx, loc;
  if (f < 2048)      { in = Wv; out = WvT; R = 512;  C = 512;   gx = 16;   loc = f; }
  else if (f < 4096) { in = Wo; out = WoT; R = 4096; C = 512;   gx = 16;   loc = f - 2048; }
  else if (f < 5120) { in = W1; out = W1T; R = 512;  C = 2048;  gx = 64;   loc = f - 4096; }
  else if (f < 6144) { in = W2; out = W2T; R = 2048; C = 512;   gx = 16;   loc = f - 5120; }
  else               { in = Wf; out = WfT; R = 512;  C = 32000; gx = 1000; loc = f - 6144; }
  int bx = loc % gx;
  int rest = loc / gx;
  int gy = R >> 5;
  int by = rest % gy, z = rest / gy;
  long zo = (long)z * R * C;
  __shared__ float t[32][33];
  int c0 = bx * 32, r0 = by * 32;
  int tx = threadIdx.x & 31, ty = threadIdx.x >> 5;
  #pragma unroll
  for (int i = 0; i < 4; i++){
    int r = ty + i * 8;
    t[r][tx] = ldf(in, zo + (long)(r0 + r) * C + c0 + tx, isbf);
  }
  __syncthreads();
  #pragma unroll
  for (int i = 0; i < 4; i++){
    int c = ty + i * 8;
    out[zo + (long)(c0 + c) * R + r0 + tx] = f2bf(t[tx][c]);
  }
}

enum { EP_QK = 0, EP_SCALE = 1, EP_VT = 2, EP_CAT = 3, EP_OUT = 4,
       EP_F32RES = 5, EP_RELU = 6 };

// ---------- 128x128 tile, 4 waves (small-N GEMMs: Wo, FF1, FF2) ----------
template<int MODE, bool GSWAP>
__global__ __launch_bounds__(256) void k_mfma(
    const u16* __restrict__ A, long sA, int lda,
    const u16* __restrict__ Bt, long sB,
    void* __restrict__ Cv,
    const void* __restrict__ bias,
    const float* __restrict__ res,
    int K, int ldc, float scale,
    const int* __restrict__ dflag)
{
  int isbf = dflag[0];
  int z = blockIdx.z;
  const u16* Ab = A + (long)z * sA;
  const u16* Bb = Bt + (long)z * sB;
  __shared__ __align__(16) u16 As[2][4][128][8];
  __shared__ __align__(16) u16 Bs[2][4][128][8];
  int m0 = (GSWAP ? blockIdx.x : blockIdx.y) * 128;
  int n0 = (GSWAP ? blockIdx.y : blockIdx.x) * 128;
  int tid = threadIdx.x;
  int lane = tid & 63, w = tid >> 6;
  int wr = (w >> 1) * 64, wc = (w & 1) * 64;
  int l15 = lane & 15, l4 = lane >> 4;
  int s0 = w * 64 + lane;
  int ar0 = s0 & 127, ak0 = s0 >> 7;
  int ak1 = ak0 + 2;
  f32x4 zero = {0.f, 0.f, 0.f, 0.f};
  f32x4 acc[4][4];
  #pragma unroll
  for (int i = 0; i < 4; i++)
    #pragma unroll
    for (int j = 0; j < 4; j++) acc[i][j] = zero;

  const long arow0 = (long)(m0 + ar0) * lda;
  const long brow0 = (long)(n0 + ar0) * K;

  #define STAGE(buf, k0) do{ \
    u16* AsF = &As[buf][0][0][0]; \
    u16* BsF = &Bs[buf][0][0][0]; \
    gload16(Ab + arow0 + (k0) + ak0 * 8, AsF + (long)(w * 64) * 8); \
    gload16(Ab + arow0 + (k0) + ak1 * 8, AsF + (long)(256 + w * 64) * 8); \
    gload16(Bb + brow0 + (k0) + ak0 * 8, BsF + (long)(w * 64) * 8); \
    gload16(Bb + brow0 + (k0) + ak1 * 8, BsF + (long)(256 + w * 64) * 8); \
  }while(0)

  #define COMPUTE(buf) do{ \
    s16x8 af[4], bfr[4]; \
    _Pragma("unroll") \
    for (int i = 0; i < 4; i++) af[i] = *(const s16x8*)&As[buf][l4][wr + i * 16 + l15][0]; \
    _Pragma("unroll") \
    for (int j = 0; j < 4; j++) bfr[j] = *(const s16x8*)&Bs[buf][l4][wc + j * 16 + l15][0]; \
    _Pragma("unroll") \
    for (int i = 0; i < 4; i++) \
      _Pragma("unroll") \
      for (int j = 0; j < 4; j++) \
        acc[i][j] = mfma16(af[i], bfr[j], acc[i][j]); \
  }while(0)

  STAGE(0, 0);
  __syncthreads();
  for (int k0 = 0; k0 < K; k0 += 64){
    STAGE(1, k0 + 32);
    COMPUTE(0);
    __syncthreads();
    if (k0 + 64 < K) STAGE(0, k0 + 64);
    COMPUTE(1);
    __syncthreads();
  }
  #undef STAGE
  #undef COMPUTE

  int mbase = m0 + wr + l4 * 4;
  int nbase = n0 + wc + l15;
  if constexpr (MODE == EP_F32RES){
    float* C = (float*)Cv;
    #pragma unroll
    for (int j = 0; j < 4; j++){
      int n = nbase + j * 16;
      float badd = ldf(bias, n, isbf);
      #pragma unroll
      for (int i = 0; i < 4; i++)
        #pragma unroll
        for (int r = 0; r < 4; r++){
          long a = (long)(mbase + i * 16 + r) * ldc + n;
          C[a] = acc[i][j][r] + badd + res[a];
        }
    }
  } else if constexpr (MODE == EP_RELU){
    u16* C = (u16*)Cv;
    #pragma unroll
    for (int j = 0; j < 4; j++){
      int n = nbase + j * 16;
      float badd = ldf(bias, n, isbf);
      #pragma unroll
      for (int i = 0; i < 4; i++)
        #pragma unroll
        for (int r = 0; r < 4; r++)
          C[(long)(mbase + i * 16 + r) * ldc + n] = f2bf(fmaxf(acc[i][j][r] + badd, 0.f));
    }
  }
}

// ---------- 256x256 tile, 8 waves (2M x 4N), BK=32, 2-phase dbuf ----------
// launch_bounds(512,2): 92 VGPR, no spill (512,4 spilled acc -> 2.7x regress, r13)
// GSWAP (logits only): bijective XCD swizzle (nwg%8==0) — one XCD owns
// consecutive n-panels so the 16 m-tiles sharing a Wf panel hit one L2.
// EP_OUT: coalesced LDS-transpose epilogue + NON-TEMPORAL f32x4 stores.
template<int MODE, bool GSWAP, int AMAP, int BMAP>
__global__ __launch_bounds__(512, 2) void k_mfma2(
    const u16* __restrict__ A, long sA, int lda,
    const u16* __restrict__ Bt, long sB, int ldb,
    void* __restrict__ Cv,
    const void* __restrict__ bias,
    const float* __restrict__ res,
    int K, int ldc, float scale,
    const int* __restrict__ dflag)
{
  int isbf = dflag[0];
  int z = blockIdx.z;
  const u16* Ab = A + (long)z * sA;
  const u16* Bb = Bt + (long)z * sB;
  __shared__ __align__(16) char smem[65536];     // As(32KB) | Bs(32KB); epilogue reuses
  u16* SA = (u16*)smem;
  u16* SB = (u16*)(smem + 32768);
  int m0, n0;
  if constexpr (GSWAP){
    int f = blockIdx.x + gridDim.x * blockIdx.y;  // dispatch-linear id
    int q = (gridDim.x * gridDim.y) >> 3;         // nwg/8 (nwg%8==0)
    int L = (f & 7) * q + (f >> 3);               // bijective XCD remap
    m0 = (L % gridDim.x) * 256;                   // n-major within an XCD
    n0 = (L / gridDim.x) * 256;
  } else {
    m0 = blockIdx.y * 256;
    n0 = blockIdx.x * 256;
  }
  int tid = threadIdx.x;
  int lane = tid & 63, w = tid >> 6;
  int wm = (w >> 2) * 128, wn = (w & 3) * 64;
  int l15 = lane & 15, l4 = lane >> 4;
  int row = tid & 255, ob = tid >> 8;
  f32x4 zero = {0.f, 0.f, 0.f, 0.f};
  f32x4 acc[8][4];
  #pragma unroll
  for (int i = 0; i < 8; i++)
    #pragma unroll
    for (int j = 0; j < 4; j++) acc[i][j] = zero;

  const long arow0 = (long)(m0 + row) * lda;
  const long brow0 = (long)(n0 + row) * ldb;

  #define STAGE2(buf, k0_) do{ \
    int ka = (AMAP == 1) ? ((k0_) < 512 ? (k0_) : (k0_) - 512) \
           : (AMAP == 2) ? ((k0_) < 1024 ? (k0_) : (k0_) - 1024) : (k0_); \
    int kb = (BMAP == 1) ? ((k0_) < 512 ? (k0_) : (k0_) - 512) \
           : (BMAP == 2) ? ((k0_) < 1024 ? (k0_) : (k0_) - 1024) : (k0_); \
    gload16(Ab + arow0 + ka + ob * 8,       SA + ((buf) * 8192 + (ob * 256 + row) * 8)); \
    gload16(Ab + arow0 + ka + (ob + 2) * 8, SA + ((buf) * 8192 + ((ob + 2) * 256 + row) * 8)); \
    gload16(Bb + brow0 + kb + ob * 8,       SB + ((buf) * 8192 + (ob * 256 + row) * 8)); \
    gload16(Bb + brow0 + kb + (ob + 2) * 8, SB + ((buf) * 8192 + ((ob + 2) * 256 + row) * 8)); \
  }while(0)

  #define COMPUTE2(buf) do{ \
    s16x8 bfr[4]; \
    _Pragma("unroll") \
    for (int j = 0; j < 4; j++) \
      bfr[j] = *(const s16x8*)(SB + ((buf) * 8192 + l4 * 2048 + (wn + j * 16 + l15) * 8)); \
    _Pragma("unroll") \
    for (int i = 0; i < 8; i++){ \
      s16x8 af = *(const s16x8*)(SA + ((buf) * 8192 + l4 * 2048 + (wm + i * 16 + l15) * 8)); \
      _Pragma("unroll") \
      for (int j = 0; j < 4; j++) \
        acc[i][j] = mfma16(af, bfr[j], acc[i][j]); \
    } \
  }while(0)

  STAGE2(0, 0);
  __syncthreads();
  for (int k0 = 0; k0 < K; k0 += 64){
    STAGE2(1, k0 + 32);
    COMPUTE2(0);
    __syncthreads();
    if (k0 + 64 < K) STAGE2(0, k0 + 64);
    COMPUTE2(1);
    __syncthreads();
  }
  #undef STAGE2
  #undef COMPUTE2

  int mbase = m0 + wm + l4 * 4;
  int nbase = n0 + wn + l15;
  if constexpr (MODE == EP_CAT){
    // cat[(b*S + s)][h*D + n]; z = h*8+b
    u16* C = (u16*)Cv;
    int h = z >> 3, b = z & 7;
    #pragma unroll
    for (int i = 0; i < 8; i++){
      int s = mbase + i * 16;
      #pragma unroll
      for (int j = 0; j < 4; j++){
        int n = nbase + j * 16;
        #pragma unroll
        for (int r = 0; r < 4; r++)
          C[((long)b * SS + s + r) * HD + (long)h * DD + n] = f2bf(acc[i][j][r]);
      }
    }
  } else if constexpr (MODE == EP_OUT){
    // coalesced epilogue: per i-slab (32 rows x 256 cols f32), LDS-transpose
    // then full-row f32x4 NON-TEMPORAL stores (1KB contiguous per wave).
    float* O = (float*)Cv;
    float* ldsT = (float*)smem;
    const int RST = 260;
    int hs16 = (w >> 2) * 16;
    float badd[4];
    #pragma unroll
    for (int j = 0; j < 4; j++) badd[j] = ldf(bias, n0 + wn + j * 16 + l15, isbf);
    #pragma unroll
    for (int i = 0; i < 8; i++){
      __syncthreads();
      #pragma unroll
      for (int j = 0; j < 4; j++){
        int col = wn + j * 16 + l15;
        #pragma unroll
        for (int r = 0; r < 4; r++)
          ldsT[(hs16 + l4 * 4 + r) * RST + col] = acc[i][j][r] + badd[j];
      }
      __syncthreads();
      #pragma unroll
      for (int p = 0; p < 4; p++){
        int chunk = tid + p * 512;
        int lr = chunk >> 6, c4 = chunk & 63;
        int gm = m0 + (lr >> 4) * 128 + i * 16 + (lr & 15);
        f32x4 v = *(f32x4*)&ldsT[lr * RST + c4 * 4];
        __builtin_nontemporal_store(v, (f32x4*)&O[(long)gm * ldc + n0 + c4 * 4]);
      }
    }
  }
}

// ---------- merged q/k/v projection: one launch, 768 blocks ----------
// zz<8: Q (K=1536 virtual, EP_QK->q2) | zz<16: K (->k2) | zz>=16: V (K=512, EP_VT->vT)
__global__ __launch_bounds__(512, 2) void k_proj(
    const u16* __restrict__ xm2,
    const u16* __restrict__ Wq2, const u16* __restrict__ Wk2, const u16* __restrict__ WvT,
    u16* __restrict__ q2, u16* __restrict__ k2, u16* __restrict__ vT,
    const void* __restrict__ bq, const void* __restrict__ bk, const void* __restrict__ bv,
    const int* __restrict__ dflag)
{
  int isbf = dflag[0];
  int zz = blockIdx.z;
  int z, ldb, K, amap, bmap, mode;
  const u16* Bb; const void* bias; u16* C;
  if (zz < 16){
    mode = 0; z = zz & 7;
    Bb = (zz < 8 ? Wq2 : Wk2) + (long)z * 524288;
    ldb = 1024; K = KC; amap = 1; bmap = 2;
    bias = (zz < 8) ? bq : bk;
    C = (zz < 8) ? q2 : k2;
  } else {
    mode = 1; z = zz - 16;
    Bb = WvT + (long)z * 262144;
    ldb = 512; K = 512; amap = 0; bmap = 0;
    bias = bv;
    C = vT;
  }
  const u16* Ab = xm2;
  __shared__ __align__(16) char smem[65536];
  u16* SA = (u16*)smem;
  u16* SB = (u16*)(smem + 32768);
  int m0 = blockIdx.y * 256;
  int n0 = blockIdx.x * 256;
  int tid = threadIdx.x;
  int lane = tid & 63, w = tid >> 6;
  int wm = (w >> 2) * 128, wn = (w & 3) * 64;
  int l15 = lane & 15, l4 = lane >> 4;
  int row = tid & 255, ob = tid >> 8;
  f32x4 zero = {0.f, 0.f, 0.f, 0.f};
  f32x4 acc[8][4];
  #pragma unroll
  for (int i = 0; i < 8; i++)
    #pragma unroll
    for (int j = 0; j < 4; j++) acc[i][j] = zero;

  const long arow0 = (long)(m0 + row) * 1024;
  const long brow0 = (long)(n0 + row) * ldb;

  #define STAGEP(buf, k0_) do{ \
    int ka = (amap == 1) ? ((k0_) < 512 ? (k0_) : (k0_) - 512) : (k0_); \
    int kb = (bmap == 2) ? ((k0_) < 1024 ? (k0_) : (k0_) - 1024) : (k0_); \
    gload16(Ab + arow0 + ka + ob * 8,       SA + ((buf) * 8192 + (ob * 256 + row) * 8)); \
    gload16(Ab + arow0 + ka + (ob + 2) * 8, SA + ((buf) * 8192 + ((ob + 2) * 256 + row) * 8)); \
    gload16(Bb + brow0 + kb + ob * 8,       SB + ((buf) * 8192 + (ob * 256 + row) * 8)); \
    gload16(Bb + brow0 + kb + (ob + 2) * 8, SB + ((buf) * 8192 + ((ob + 2) * 256 + row) * 8)); \
  }while(0)

  #define COMPUTEP(buf) do{ \
    s16x8 bfr[4]; \
    _Pragma("unroll") \
    for (int j = 0; j < 4; j++) \
      bfr[j] = *(const s16x8*)(SB + ((buf) * 8192 + l4 * 2048 + (wn + j * 16 + l15) * 8)); \
    _Pragma("unroll") \
    for (int i = 0; i < 8; i++){ \
      s16x8 af = *(const s16x8*)(SA + ((buf) * 8192 + l4 * 2048 + (wm + i * 16 + l15) * 8)); \
      _Pragma("unroll") \
      for (int j = 0; j < 4; j++) \
        acc[i][j] = mfma16(af, bfr[j], acc[i][j]); \
    } \
  }while(0)

  STAGEP(0, 0);
  __syncthreads();
  for (int k0 = 0; k0 < K; k0 += 64){
    STAGEP(1, k0 + 32);
    COMPUTEP(0);
    __syncthreads();
    if (k0 + 64 < K) STAGEP(0, k0 + 64);
    COMPUTEP(1);
    __syncthreads();
  }
  #undef STAGEP
  #undef COMPUTEP

  int mbase = m0 + wm + l4 * 4;
  int nbase = n0 + wn + l15;
  if (mode == 0){
    // 2-band out: C[row][n]=hi, C[row][512+n]=lo, row stride 1024
    u16* Cz = C + (long)z * ((long)MTOT * 1024);
    #pragma unroll
    for (int j = 0; j < 4; j++){
      int n = nbase + j * 16;
      float badd = ldf(bias, (long)z * DD + n, isbf);
      #pragma unroll
      for (int i = 0; i < 8; i++)
        #pragma unroll
        for (int r = 0; r < 4; r++){
          float qv = acc[i][j][r] + badd;
          u16 hi = f2bf(qv);
          u16 lo = f2bf(qv - bf2f(hi));
          long rb = (long)(mbase + i * 16 + r) * 1024;
          Cz[rb + n] = hi;
          Cz[rb + 512 + n] = lo;
        }
    }
  } else {
    // vT[(z*8 + b)][d = n][s]; 4 acc regs = 4 consecutive s
    #pragma unroll
    for (int i = 0; i < 8; i++){
      int mrow = mbase + i * 16;
      int b = mrow >> 9, s = mrow & (SS - 1);
      #pragma unroll
      for (int j = 0; j < 4; j++){
        int n = nbase + j * 16;
        float badd = ldf(bias, (long)z * DD + n, isbf);
        ushort4 pk;
        pk.x = f2bf(acc[i][j][0] + badd); pk.y = f2bf(acc[i][j][1] + badd);
        pk.z = f2bf(acc[i][j][2] + badd); pk.w = f2bf(acc[i][j][3] + badd);
        *(ushort4*)&C[((long)(z * 8 + b) * DD + n) * SS + s] = pk;
      }
    }
  }
}

// ---------- fused scores+softmax: 128 q-rows x full 512 k-cols per block ----------
template<int AMAP, int BMAP>
__global__ __launch_bounds__(512, 2) void k_fsm(
    const u16* __restrict__ A, long sA, int lda,
    const u16* __restrict__ Bt, long sB, int ldb,
    u16* __restrict__ P, int K, float scale,
    const int* __restrict__ dflag)
{
  int z = blockIdx.z;
  const u16* Ab = A + (long)z * sA;
  const u16* Bb = Bt + (long)z * sB;
  __shared__ __align__(16) char smem[81920];
  u16* SA = (u16*)smem;
  u16* SB = (u16*)(smem + 16384);
  int m0 = blockIdx.x * 128;
  int tid = threadIdx.x;
  int lane = tid & 63, w = tid >> 6;
  int wn = w * 64;
  int l15 = lane & 15, l4 = lane >> 4;
  f32x4 zero = {0.f, 0.f, 0.f, 0.f};
  f32x4 acc[8][4];
  #pragma unroll
  for (int i = 0; i < 8; i++)
    #pragma unroll
    for (int j = 0; j < 4; j++) acc[i][j] = zero;

  const long arow0 = (long)(m0 + (tid & 127)) * lda;
  const int akc = tid >> 7;
  const long brow0 = (long)tid * ldb;

  #define STAGEF(buf, k0_) do{ \
    int ka = (AMAP == 1) ? ((k0_) < 512 ? (k0_) : (k0_) - 512) \
           : (AMAP == 2) ? ((k0_) < 1024 ? (k0_) : (k0_) - 1024) : (k0_); \
    int kb = (BMAP == 1) ? ((k0_) < 512 ? (k0_) : (k0_) - 512) \
           : (BMAP == 2) ? ((k0_) < 1024 ? (k0_) : (k0_) - 1024) : (k0_); \
    gload16(Ab + arow0 + ka + akc * 8, SA + ((buf) * 4096 + tid * 8)); \
    gload16(Bb + brow0 + kb + 0,  SB + ((buf) * 16384 + (0 * 512 + tid) * 8)); \
    gload16(Bb + brow0 + kb + 8,  SB + ((buf) * 16384 + (1 * 512 + tid) * 8)); \
    gload16(Bb + brow0 + kb + 16, SB + ((buf) * 16384 + (2 * 512 + tid) * 8)); \
    gload16(Bb + brow0 + kb + 24, SB + ((buf) * 16384 + (3 * 512 + tid) * 8)); \
  }while(0)

  #define COMPUTEF(buf) do{ \
    s16x8 bfr[4]; \
    _Pragma("unroll") \
    for (int j = 0; j < 4; j++) \
      bfr[j] = *(const s16x8*)(SB + ((buf) * 16384 + l4 * 4096 + (wn + j * 16 + l15) * 8)); \
    _Pragma("unroll") \
    for (int i = 0; i < 8; i++){ \
      s16x8 af = *(const s16x8*)(SA + ((buf) * 4096 + l4 * 1024 + (i * 16 + l15) * 8)); \
      _Pragma("unroll") \
      for (int j = 0; j < 4; j++) \
        acc[i][j] = mfma16(af, bfr[j], acc[i][j]); \
    } \
  }while(0)

  STAGEF(0, 0);
  __syncthreads();
  for (int k0 = 0; k0 < K; k0 += 64){
    STAGEF(1, k0 + 32);
    COMPUTEF(0);
    __syncthreads();
    if (k0 + 64 < K) STAGEF(0, k0 + 64);
    COMPUTEF(1);
    __syncthreads();
  }
  #undef STAGEF
  #undef COMPUTEF

  float* sred = (float*)smem;
  float* srow = (float*)(smem + 4096);

  #pragma unroll
  for (int i = 0; i < 8; i++)
    #pragma unroll
    for (int j = 0; j < 4; j++)
      acc[i][j] *= scale;

  #pragma unroll
  for (int i = 0; i < 8; i++)
    #pragma unroll
    for (int r = 0; r < 4; r++){
      float m = fmaxf(fmaxf(acc[i][0][r], acc[i][1][r]),
                      fmaxf(acc[i][2][r], acc[i][3][r]));
      #pragma unroll
      for (int off = 1; off < 16; off <<= 1) m = fmaxf(m, __shfl_xor(m, off, 64));
      if (l15 == 0) sred[w * 128 + l4 * 4 + i * 16 + r] = m;
    }
  __syncthreads();
  if (tid < 128){
    float m = sred[tid];
    #pragma unroll
    for (int w2 = 1; w2 < 8; w2++) m = fmaxf(m, sred[w2 * 128 + tid]);
    srow[tid] = m;
  }
  __syncthreads();
  #pragma unroll
  for (int i = 0; i < 8; i++)
    #pragma unroll
    for (int r = 0; r < 4; r++){
      float rm = srow[l4 * 4 + i * 16 + r];
      float s = 0.f;
      #pragma unroll
      for (int j = 0; j < 4; j++){
        float e = expf(acc[i][j][r] - rm);
        acc[i][j][r] = e;
        s += e;
      }
      #pragma unroll
      for (int off = 1; off < 16; off <<= 1) s += __shfl_xor(s, off, 64);
      if (l15 == 0) sred[w * 128 + l4 * 4 + i * 16 + r] = s;
    }
  __syncthreads();
  if (tid < 128){
    float s = 0.f;
    #pragma unroll
    for (int w2 = 0; w2 < 8; w2++) s += sred[w2 * 128 + tid];
    srow[tid] = 1.f / s;
  }
  __syncthreads();
  // coalesced attn store: 32-row LDS slabs (u16, pad 520) then 8B-chunk writes
  // (wave = 512B contiguous). Same math/rounding as the scalar path.
  u16* Pz = P + (long)z * ((long)SS * SS);
  u16* pb = (u16*)(smem + 8192);        // [32][520] u16 = 33,280B (sred/srow preserved)
  const int PST = 520;
  #pragma unroll
  for (int ii = 0; ii < 4; ii++){
    __syncthreads();                     // prior slab's chunk reads done
    #pragma unroll
    for (int s2 = 0; s2 < 2; s2++){
      int i = ii * 2 + s2;
      #pragma unroll
      for (int r = 0; r < 4; r++){
        int rl = l4 * 4 + i * 16 + r;
        float inv = srow[rl];
        #pragma unroll
        for (int j = 0; j < 4; j++)
          pb[(s2 * 16 + l4 * 4 + r) * PST + wn + j * 16 + l15] = f2bf(acc[i][j][r] * inv);
      }
    }
    __syncthreads();
    #pragma unroll
    for (int p = 0; p < 8; p++){
      int chunk = tid + p * 512;         // 4096 chunks = 32 rows x 128 x 8B
      int lr = chunk >> 7, c8 = chunk & 127;
      ushort4 v = *(ushort4*)&pb[lr * PST + c8 * 4];
      *(ushort4*)&Pz[(long)(m0 + ii * 32 + lr) * SS + c8 * 4] = v;
    }
  }
}

// LayerNorm f32 -> bf16 (+ optional f32), one wave per row of 512
template<bool WF32>
__global__ __launch_bounds__(256) void k_ln(
    const float* __restrict__ X, const void* __restrict__ g, const void* __restrict__ be,
    u16* __restrict__ Yb, float* __restrict__ Yf, const int* __restrict__ dflag)
{
  int isbf = dflag[0];
  int row = blockIdx.x * 4 + (threadIdx.x >> 6);
  int lane = threadIdx.x & 63;
  const float* p = X + (long)row * DD + lane * 8;
  float4 v0 = *(const float4*)p;
  float4 v1 = *(const float4*)(p + 4);
  float v[8] = {v0.x, v0.y, v0.z, v0.w, v1.x, v1.y, v1.z, v1.w};
  float s = 0.f;
  #pragma unroll
  for (int i = 0; i < 8; i++) s += v[i];
  s = wave_redsum(s);
  float mu = s * (1.f / DD);
  float d_[8], sq = 0.f;
  #pragma unroll
  for (int i = 0; i < 8; i++){ d_[i] = v[i] - mu; sq += d_[i] * d_[i]; }
  sq = wave_redsum(sq);
  float rs = 1.f / sqrtf(sq * (1.f / DD) + 1e-5f);
  #pragma unroll
  for (int i = 0; i < 8; i++){
    int dd = lane * 8 + i;
    float y = ldf(g, dd, isbf) * d_[i] * rs + ldf(be, dd, isbf);
    Yb[(long)row * DD + dd] = f2bf(y);
    if (WF32) Yf[(long)row * DD + dd] = y;
  }
}

extern "C" void kernel_launch(void* const* d_in, const int* in_sizes, int n_in,
                              void* d_out, int out_size, void* d_ws, size_t ws_size,
                              hipStream_t stream)
{
  const int* tokens = (const int*)d_in[0];
  const void* emb = d_in[1];
  const void* pe  = d_in[2];
  const void* Wq  = d_in[3];
  const void* bq  = d_in[4];
  const void* Wk  = d_in[5];
  const void* bk  = d_in[6];
  const void* Wv  = d_in[7];
  const void* bv  = d_in[8];
  const void* Wo  = d_in[9];
  const void* bo  = d_in[10];
  const void* g1  = d_in[11];
  const void* be1 = d_in[12];
  const void* W1  = d_in[13];
  const void* b1  = d_in[14];
  const void* W2  = d_in[15];
  const void* b2  = d_in[16];
  const void* g2  = d_in[17];
  const void* be2 = d_in[18];
  const void* Wf  = d_in[19];
  const void* bfb = d_in[20];
  float* out = (float*)d_out;   // reference output dtype = float32
  char* ws = (char*)d_ws;
  char* DO = (char*)d_out;

  const size_t MB = 1ull << 20;
  // ---- d_ws (39.3 MiB; <=69 MiB evidenced safe) ----
  int* dflag = (int*)ws;
  u16* x2b   = (u16*)(ws + 1 * MB);        // [1,5)
  u16* WfT   = (u16*)(ws + 8 * MB);        // [8,39.25)  bf16 [32000][512]

  // ---- d_out as scratch (380 of 500 MiB; all dead before logits) ----
  float* x    = (float*)(DO + 0 * MB);     // [0,8)
  u16*   xm2  = (u16*)(DO + 8 * MB);       // [8,16)    [4096][1024] = [xh|xl]
  u16*   Wq2  = (u16*)(DO + 16 * MB);      // [16,24)   [8][512][1024] = [wh|wl]
  u16*   Wk2  = (u16*)(DO + 24 * MB);      // [24,32)
  u16*   WvT  = (u16*)(DO + 32 * MB);      // [32,36)   [8][512][512]
  u16*   WoT  = (u16*)(DO + 36 * MB);      // [36,40)   [512][4096]
  u16*   W1T  = (u16*)(DO + 40 * MB);      // [40,42)   [2048][512]
  u16*   W2T  = (u16*)(DO + 42 * MB);      // [42,44)   [512][2048]
  u16*   q2   = (u16*)(DO + 48 * MB);      // [48,112)  [8][4096][1024] = [qh|ql]
  u16*   k2   = (u16*)(DO + 112 * MB);     // [112,176) [8][4096][1024] = [kh|kl]
  u16*   attn = (u16*)(DO + 240 * MB);     // [240,272) [64][512][512] bf16
  u16*   vT   = (u16*)(DO + 272 * MB);     // [272,304) [64][512 d][512 s]
  u16*   cat  = (u16*)(DO + 304 * MB);     // [304,336) [4096][4096]
  float* proj = (float*)(DO + 336 * MB);   // [336,344)
  float* x1f  = (float*)(DO + 344 * MB);   // [344,352)
  u16*   x1b  = (u16*)(DO + 352 * MB);     // [352,356)
  u16*   ff1  = (u16*)(DO + 356 * MB);     // [356,372) [4096][2048]
  float* ff2  = (float*)(DO + 372 * MB);   // [372,380)

  const float scale = 0.04419417382415922f;  // 1/sqrt(512)
  const long HSL = 262144;                   // 512*512
  const long QSL = 524288;                   // 512*1024 (2-band q/k rows per z)

  k_dflag<<<1, 1, 0, stream>>>(pe, dflag);
  k_embed<<<dim3(4096), 256, 0, stream>>>(tokens, emb, pe, x, xm2, dflag);

  // one-time weight prep (2 launches)
  k_wsplitT<<<dim3(16, 16, 16), 256, 0, stream>>>(Wq, Wk, Wq2, Wk2, dflag);
  k_transAll<<<dim3(22144), 256, 0, stream>>>(
      Wv, Wo, W1, W2, Wf, WvT, WoT, W1T, W2T, WfT, dflag);

  // merged q/k/v projections: one 768-block launch (z<8 Q, z<16 K, z>=16 V)
  k_proj<<<dim3(2, 16, 24), 512, 0, stream>>>(
      xm2, Wq2, Wk2, WvT, q2, k2, vT, bq, bk, bv, dflag);

  // fused scores+softmax -> attn bf16 (no sc buffer); z = h*8+b
  k_fsm<1, 2><<<dim3(4, 1, 64), 512, 0, stream>>>(
      q2, QSL, 1024, k2, QSL, 1024, attn, KC, scale, dflag);

  // o = attn @ v -> cat (torch.cat head order)
  k_mfma2<EP_CAT, false, 0, 0><<<dim3(2, 2, 64), 512, 0, stream>>>(
      attn, HSL, SS, vT, HSL, 512, cat, nullptr, nullptr, SS, 0, 0.f, dflag);

  // proj = cat @ Wo + bo + x (128^2 kernel)
  k_mfma<EP_F32RES, false><<<dim3(4, 32, 1), 256, 0, stream>>>(
      cat, 0, HD, WoT, 0, proj, bo, x, HD, DD, 0.f, dflag);
  k_ln<true><<<dim3(1024), 256, 0, stream>>>(proj, g1, be1, x1b, x1f, dflag);

  // ff = relu(x1 @ W1 + b1) @ W2 + b2 + x1
  k_mfma<EP_RELU, false><<<dim3(16, 32, 1), 256, 0, stream>>>(
      x1b, 0, DD, W1T, 0, ff1, b1, nullptr, DD, NFF, 0.f, dflag);
  k_mfma<EP_F32RES, false><<<dim3(4, 32, 1), 256, 0, stream>>>(
      ff1, 0, NFF, W2T, 0, ff2, b2, x1f, NFF, DD, 0.f, dflag);
  k_ln<false><<<dim3(1024), 256, 0, stream>>>(ff2, g2, be2, x2b, nullptr, dflag);

  // logits = x2 @ Wf + bf -> f32 out (XCD-swizzled; coalesced epilogue + NT stores)
  k_mfma2<EP_OUT, true, 0, 0><<<dim3(16, 125, 1), 512, 0, stream>>>(
      x2b, 0, DD, WfT, 0, 512, out, bfb, nullptr, DD, VV, 0.f, dflag);
}

// Round 21
// 970.380 us; speedup vs baseline: 1.0331x; 1.0331x over previous
//
#include <hip/hip_runtime.h>

typedef unsigned short u16;
typedef unsigned int u32;
typedef short s16x8 __attribute__((ext_vector_type(8)));
typedef __bf16 bf16x8 __attribute__((ext_vector_type(8)));
typedef float f32x4 __attribute__((ext_vector_type(4)));

#define DEVI static __device__ __forceinline__

#define SS 512
#define DD 512
#define NFF 2048
#define VV 32000
#define MTOT 4096
#define HD 4096
#define KC 1536   // virtual split-concat K (2-band storage + read-time remap)

DEVI float bf2f(u16 h){ return __uint_as_float(((u32)h) << 16); }
DEVI u16 f2bf(float f){
  u32 u = __float_as_uint(f);
  return (u16)((u + 0x7FFFu + ((u >> 16) & 1u)) >> 16);
}
DEVI float ldf(const void* p, long i, int isbf){
  return isbf ? bf2f(((const u16*)p)[i]) : ((const float*)p)[i];
}

DEVI f32x4 mfma16(s16x8 a, s16x8 b, f32x4 c){
  return __builtin_amdgcn_mfma_f32_16x16x32_bf16(
      __builtin_bit_cast(bf16x8, a), __builtin_bit_cast(bf16x8, b), c, 0, 0, 0);
}

// direct global->LDS 16B copy; dst is wave-uniform base + lane*16, src per-lane
typedef const __attribute__((address_space(1))) unsigned int* gup;
typedef __attribute__((address_space(3))) unsigned int* lup;
DEVI void gload16(const void* g, void* l){
  __builtin_amdgcn_global_load_lds((gup)g, (lup)l, 16, 0, 0);
}

DEVI float wave_redsum(float v){
  #pragma unroll
  for (int off = 32; off > 0; off >>= 1) v += __shfl_xor(v, off, 64);
  return v;
}

// pe row0 = [sin0=0, cos0=1, ...]: first u32 word = 0x3F800000 if bf16, 0x00000000 if f32
__global__ void k_dflag(const void* pe, int* flag){
  flag[0] = (*(const u32*)pe == 0x3F800000u) ? 1 : 0;
}

// embed + residual + masked 2-band split: xm2[m][0:512]=hi, [512:1024]=lo
__global__ __launch_bounds__(256) void k_embed(
    const int* __restrict__ tok, const void* __restrict__ emb, const void* __restrict__ pe,
    float* __restrict__ x, u16* __restrict__ xm2, const int* __restrict__ dflag)
{
  int isbf = dflag[0];
  int blk = blockIdx.x;
  int s = blk & (SS - 1);
  int t = tok[blk];
  long rb = (long)blk * 1024;
  for (int d = threadIdx.x; d < DD; d += 256){
    float e = ldf(emb, (long)t * DD + d, isbf) + ldf(pe, (long)s * DD + d, isbf);
    x[(long)blk * DD + d] = e;
    float m = (d <= s) ? e : 0.f;           // triu(ones(S,D),k=1) zeroes d > s
    u16 hi = f2bf(m);
    u16 lo = f2bf(m - bf2f(hi));
    xm2[rb + d] = hi;
    xm2[rb + 512 + d] = lo;
  }
}

// split-transpose for Wq AND Wk (zz<8: Wq slice zz; else Wk slice zz-8):
// in W[z][512 d][512 e] -> out[z][512 e][1024]: band0=hi, band1=lo
__global__ __launch_bounds__(256) void k_wsplitT(
    const void* __restrict__ Wq, const void* __restrict__ Wk,
    u16* __restrict__ Wq2, u16* __restrict__ Wk2, const int* __restrict__ dflag)
{
  int isbf = dflag[0];
  int zz = blockIdx.z;
  const void* in = (zz < 8) ? Wq : Wk;
  u16* out = (zz < 8) ? Wq2 : Wk2;
  int z = zz & 7;
  long zin = (long)z * DD * DD;
  long zout = (long)z * DD * 1024;
  __shared__ float t[32][33];
  int e0 = blockIdx.x * 32, d0 = blockIdx.y * 32;
  int tx = threadIdx.x & 31, ty = threadIdx.x >> 5;
  #pragma unroll
  for (int i = 0; i < 4; i++){
    int d = ty + i * 8;
    t[d][tx] = ldf(in, zin + (long)(d0 + d) * DD + e0 + tx, isbf);
  }
  __syncthreads();
  #pragma unroll
  for (int i = 0; i < 4; i++){
    int e = ty + i * 8;
    float v = t[tx][e];
    u16 hi = f2bf(v);
    u16 lo = f2bf(v - bf2f(hi));
    long ob = zout + (long)(e0 + e) * 1024 + d0 + tx;
    out[ob] = hi;
    out[ob + 512] = lo;
  }
}

// all 5 plain transposes (f32/bf16 -> bf16) in one flat-grid kernel.
__global__ __launch_bounds__(256) void k_transAll(
    const void* __restrict__ Wv, const void* __restrict__ Wo,
    const void* __restrict__ W1, const void* __restrict__ W2,
    const void* __restrict__ Wf,
    u16* __restrict__ WvT, u16* __restrict__ WoT, u16* __restrict__ W1T,
    u16* __restrict__ W2T, u16* __restrict__ WfT, const int* __restrict__ dflag)
{
  int isbf = dflag[0];
  int f = blockIdx.x;
  const void* in; u16* out; int R, C, gx, loc;
  if (f < 2048)      { in = Wv; out = WvT; R = 512;  C = 512;   gx = 16;   loc = f; }
  else if (f < 4096) { in = Wo; out = WoT; R = 4096; C = 512;   gx = 16;   loc = f - 2048; }
  else if (f < 5120) { in = W1; out = W1T; R = 512;  C = 2048;  gx = 64;   loc = f - 4096; }
  else if (f < 6144) { in = W2; out = W2T; R = 2048; C = 512;   gx = 16;   loc = f - 5120; }
  else               { in = Wf; out = WfT; R = 512;  C = 32000; gx = 1000; loc = f - 6144; }
  int bx = loc % gx;
  int rest = loc / gx;
  int gy = R >> 5;
  int by = rest % gy, z = rest / gy;
  long zo = (long)z * R * C;
  __shared__ float t[32][33];
  int c0 = bx * 32, r0 = by * 32;
  int tx = threadIdx.x & 31, ty = threadIdx.x >> 5;
  #pragma unroll
  for (int i = 0; i < 4; i++){
    int r = ty + i * 8;
    t[r][tx] = ldf(in, zo + (long)(r0 + r) * C + c0 + tx, isbf);
  }
  __syncthreads();
  #pragma unroll
  for (int i = 0; i < 4; i++){
    int c = ty + i * 8;
    out[zo + (long)(c0 + c) * R + r0 + tx] = f2bf(t[tx][c]);
  }
}

enum { EP_QK = 0, EP_SCALE = 1, EP_VT = 2, EP_CAT = 3, EP_OUT = 4,
       EP_F32RES = 5, EP_RELU = 6 };

// ---------- 128x128 tile, 4 waves (small-N GEMMs: Wo, FF1, FF2) ----------
template<int MODE, bool GSWAP>
__global__ __launch_bounds__(256) void k_mfma(
    const u16* __restrict__ A, long sA, int lda,
    const u16* __restrict__ Bt, long sB,
    void* __restrict__ Cv,
    const void* __restrict__ bias,
    const float* __restrict__ res,
    int K, int ldc, float scale,
    const int* __restrict__ dflag)
{
  int isbf = dflag[0];
  int z = blockIdx.z;
  const u16* Ab = A + (long)z * sA;
  const u16* Bb = Bt + (long)z * sB;
  __shared__ __align__(16) u16 As[2][4][128][8];
  __shared__ __align__(16) u16 Bs[2][4][128][8];
  int m0 = (GSWAP ? blockIdx.x : blockIdx.y) * 128;
  int n0 = (GSWAP ? blockIdx.y : blockIdx.x) * 128;
  int tid = threadIdx.x;
  int lane = tid & 63, w = tid >> 6;
  int wr = (w >> 1) * 64, wc = (w & 1) * 64;
  int l15 = lane & 15, l4 = lane >> 4;
  int s0 = w * 64 + lane;
  int ar0 = s0 & 127, ak0 = s0 >> 7;
  int ak1 = ak0 + 2;
  f32x4 zero = {0.f, 0.f, 0.f, 0.f};
  f32x4 acc[4][4];
  #pragma unroll
  for (int i = 0; i < 4; i++)
    #pragma unroll
    for (int j = 0; j < 4; j++) acc[i][j] = zero;

  const long arow0 = (long)(m0 + ar0) * lda;
  const long brow0 = (long)(n0 + ar0) * K;

  #define STAGE(buf, k0) do{ \
    u16* AsF = &As[buf][0][0][0]; \
    u16* BsF = &Bs[buf][0][0][0]; \
    gload16(Ab + arow0 + (k0) + ak0 * 8, AsF + (long)(w * 64) * 8); \
    gload16(Ab + arow0 + (k0) + ak1 * 8, AsF + (long)(256 + w * 64) * 8); \
    gload16(Bb + brow0 + (k0) + ak0 * 8, BsF + (long)(w * 64) * 8); \
    gload16(Bb + brow0 + (k0) + ak1 * 8, BsF + (long)(256 + w * 64) * 8); \
  }while(0)

  #define COMPUTE(buf) do{ \
    s16x8 af[4], bfr[4]; \
    _Pragma("unroll") \
    for (int i = 0; i < 4; i++) af[i] = *(const s16x8*)&As[buf][l4][wr + i * 16 + l15][0]; \
    _Pragma("unroll") \
    for (int j = 0; j < 4; j++) bfr[j] = *(const s16x8*)&Bs[buf][l4][wc + j * 16 + l15][0]; \
    _Pragma("unroll") \
    for (int i = 0; i < 4; i++) \
      _Pragma("unroll") \
      for (int j = 0; j < 4; j++) \
        acc[i][j] = mfma16(af[i], bfr[j], acc[i][j]); \
  }while(0)

  STAGE(0, 0);
  __syncthreads();
  for (int k0 = 0; k0 < K; k0 += 64){
    STAGE(1, k0 + 32);
    COMPUTE(0);
    __syncthreads();
    if (k0 + 64 < K) STAGE(0, k0 + 64);
    COMPUTE(1);
    __syncthreads();
  }
  #undef STAGE
  #undef COMPUTE

  int mbase = m0 + wr + l4 * 4;
  int nbase = n0 + wc + l15;
  if constexpr (MODE == EP_F32RES){
    float* C = (float*)Cv;
    #pragma unroll
    for (int j = 0; j < 4; j++){
      int n = nbase + j * 16;
      float badd = ldf(bias, n, isbf);
      #pragma unroll
      for (int i = 0; i < 4; i++)
        #pragma unroll
        for (int r = 0; r < 4; r++){
          long a = (long)(mbase + i * 16 + r) * ldc + n;
          C[a] = acc[i][j][r] + badd + res[a];
        }
    }
  } else if constexpr (MODE == EP_RELU){
    u16* C = (u16*)Cv;
    #pragma unroll
    for (int j = 0; j < 4; j++){
      int n = nbase + j * 16;
      float badd = ldf(bias, n, isbf);
      #pragma unroll
      for (int i = 0; i < 4; i++)
        #pragma unroll
        for (int r = 0; r < 4; r++)
          C[(long)(mbase + i * 16 + r) * ldc + n] = f2bf(fmaxf(acc[i][j][r] + badd, 0.f));
    }
  }
}

// ---------- 256x256 tile, 8 waves (2M x 4N), BK=32, 2-phase dbuf ----------
// (used for attn@v; launch_bounds(512,2): 92 VGPR, no spill)
template<int MODE, bool GSWAP, int AMAP, int BMAP>
__global__ __launch_bounds__(512, 2) void k_mfma2(
    const u16* __restrict__ A, long sA, int lda,
    const u16* __restrict__ Bt, long sB, int ldb,
    void* __restrict__ Cv,
    const void* __restrict__ bias,
    const float* __restrict__ res,
    int K, int ldc, float scale,
    const int* __restrict__ dflag)
{
  int isbf = dflag[0];
  int z = blockIdx.z;
  const u16* Ab = A + (long)z * sA;
  const u16* Bb = Bt + (long)z * sB;
  __shared__ __align__(16) char smem[65536];
  u16* SA = (u16*)smem;
  u16* SB = (u16*)(smem + 32768);
  int m0 = (GSWAP ? blockIdx.x : blockIdx.y) * 256;
  int n0 = (GSWAP ? blockIdx.y : blockIdx.x) * 256;
  int tid = threadIdx.x;
  int lane = tid & 63, w = tid >> 6;
  int wm = (w >> 2) * 128, wn = (w & 3) * 64;
  int l15 = lane & 15, l4 = lane >> 4;
  int row = tid & 255, ob = tid >> 8;
  f32x4 zero = {0.f, 0.f, 0.f, 0.f};
  f32x4 acc[8][4];
  #pragma unroll
  for (int i = 0; i < 8; i++)
    #pragma unroll
    for (int j = 0; j < 4; j++) acc[i][j] = zero;

  const long arow0 = (long)(m0 + row) * lda;
  const long brow0 = (long)(n0 + row) * ldb;

  #define STAGE2(buf, k0_) do{ \
    int ka = (AMAP == 1) ? ((k0_) < 512 ? (k0_) : (k0_) - 512) \
           : (AMAP == 2) ? ((k0_) < 1024 ? (k0_) : (k0_) - 1024) : (k0_); \
    int kb = (BMAP == 1) ? ((k0_) < 512 ? (k0_) : (k0_) - 512) \
           : (BMAP == 2) ? ((k0_) < 1024 ? (k0_) : (k0_) - 1024) : (k0_); \
    gload16(Ab + arow0 + ka + ob * 8,       SA + ((buf) * 8192 + (ob * 256 + row) * 8)); \
    gload16(Ab + arow0 + ka + (ob + 2) * 8, SA + ((buf) * 8192 + ((ob + 2) * 256 + row) * 8)); \
    gload16(Bb + brow0 + kb + ob * 8,       SB + ((buf) * 8192 + (ob * 256 + row) * 8)); \
    gload16(Bb + brow0 + kb + (ob + 2) * 8, SB + ((buf) * 8192 + ((ob + 2) * 256 + row) * 8)); \
  }while(0)

  #define COMPUTE2(buf) do{ \
    s16x8 bfr[4]; \
    _Pragma("unroll") \
    for (int j = 0; j < 4; j++) \
      bfr[j] = *(const s16x8*)(SB + ((buf) * 8192 + l4 * 2048 + (wn + j * 16 + l15) * 8)); \
    _Pragma("unroll") \
    for (int i = 0; i < 8; i++){ \
      s16x8 af = *(const s16x8*)(SA + ((buf) * 8192 + l4 * 2048 + (wm + i * 16 + l15) * 8)); \
      _Pragma("unroll") \
      for (int j = 0; j < 4; j++) \
        acc[i][j] = mfma16(af, bfr[j], acc[i][j]); \
    } \
  }while(0)

  STAGE2(0, 0);
  __syncthreads();
  for (int k0 = 0; k0 < K; k0 += 64){
    STAGE2(1, k0 + 32);
    COMPUTE2(0);
    __syncthreads();
    if (k0 + 64 < K) STAGE2(0, k0 + 64);
    COMPUTE2(1);
    __syncthreads();
  }
  #undef STAGE2
  #undef COMPUTE2

  int mbase = m0 + wm + l4 * 4;
  int nbase = n0 + wn + l15;
  if constexpr (MODE == EP_CAT){
    // cat[(b*S + s)][h*D + n]; z = h*8+b
    u16* C = (u16*)Cv;
    int h = z >> 3, b = z & 7;
    #pragma unroll
    for (int i = 0; i < 8; i++){
      int s = mbase + i * 16;
      #pragma unroll
      for (int j = 0; j < 4; j++){
        int n = nbase + j * 16;
        #pragma unroll
        for (int r = 0; r < 4; r++)
          C[((long)b * SS + s + r) * HD + (long)h * DD + n] = f2bf(acc[i][j][r]);
      }
    }
  }
}

// ---------- 8-phase counted-vmcnt 256x256 GEMM for logits (K=NT*64) ----------
// BK=64 K-tiles, 2x64KB LDS buffers, half-tile staging (4 units/tile, one per
// phase), 4 MFMA phases/tile (ks x jh quadrants, 16 MFMA each). One counted
// s_waitcnt vmcnt(2) per tile (never 0 in steady state); raw s_barrier +
// sched_barrier(0) fences (no __syncthreads vmcnt-drain in the loop).
// A = x2b [4096][512] bf16, B = WfT [32000][512] bf16, C = out f32 [4096][VV].
__global__ __launch_bounds__(512, 2) void k_out8(
    const u16* __restrict__ A, const u16* __restrict__ Bt,
    float* __restrict__ O, const void* __restrict__ bias,
    int NT, const int* __restrict__ dflag)
{
  int isbf = dflag[0];
  __shared__ __align__(16) char smem[131072];   // 2 bufs x (A 32KB | B 32KB)
  u16* SM = (u16*)smem;
  // bijective XCD remap (nwg = 16*125 = 2000, %8 == 0)
  int f = blockIdx.x + gridDim.x * blockIdx.y;
  int qx = (gridDim.x * gridDim.y) >> 3;
  int L = (f & 7) * qx + (f >> 3);
  int m0 = (L % gridDim.x) * 256;
  int n0 = (L / gridDim.x) * 256;
  int tid = threadIdx.x;
  int lane = tid & 63, w = tid >> 6;
  int wm = (w >> 2) * 128, wn = (w & 3) * 64;
  int l15 = lane & 15, l4 = lane >> 4;
  f32x4 zero = {0.f, 0.f, 0.f, 0.f};
  f32x4 acc[8][4];
  #pragma unroll
  for (int i = 0; i < 8; i++)
    #pragma unroll
    for (int j = 0; j < 4; j++) acc[i][j] = zero;

  int rr = tid & 127, kc1 = tid >> 7;   // staging: row-in-half, k-chunk 0..3

  // unit u of tile T into buffer c: u0=A rows0-127, u1=B rows0-127,
  // u2=A rows128-255, u3=B rows128-255. 2 gloads (kc1, kc1+4), lane-linear dst.
  #define STAGEU(c, Tt, u) do{ \
    const u16* gb = (((u) & 1) == 0) ? A : Bt; \
    int base0 = (((u) & 1) == 0) ? m0 : n0; \
    int r2 = ((u) >> 1) * 128 + rr; \
    long gsrc = (long)(base0 + r2) * 512 + (Tt) * 64; \
    u16* lb = SM + (c) * 32768 + ((((u) & 1) == 0) ? 0 : 16384); \
    gload16(gb + gsrc + kc1 * 8,       lb + (kc1 * 256 + r2) * 8); \
    gload16(gb + gsrc + (kc1 + 4) * 8, lb + ((kc1 + 4) * 256 + r2) * 8); \
  }while(0)

  // prologue: tile 0 fully staged (8 loads in flight)
  STAGEU(0, 0, 0); STAGEU(0, 0, 1); STAGEU(0, 0, 2); STAGEU(0, 0, 3);

  int cur = 0;
  for (int T = 0; T < NT; T++){
    int nxt = cur ^ 1;
    int more = (T + 1 < NT);
    s16x8 af[8];
    #pragma unroll
    for (int q = 0; q < 4; q++){
      if (more) STAGEU(nxt, T + 1, q);    // issue next tile's unit q
      if (q == 0){
        // tile T's 8 loads are the oldest outstanding; allow the 2 just issued
        if (more) asm volatile("s_waitcnt vmcnt(2)" ::: "memory");
        else      asm volatile("s_waitcnt vmcnt(0)" ::: "memory");
      }
      __builtin_amdgcn_s_barrier();
      __builtin_amdgcn_sched_barrier(0);
      int ks = q >> 1, jh = q & 1;
      if (jh == 0){
        #pragma unroll
        for (int i = 0; i < 8; i++)
          af[i] = *(const s16x8*)(SM + cur * 32768 +
                    ((ks * 4 + l4) * 256 + (wm + i * 16 + l15)) * 8);
      }
      s16x8 b0 = *(const s16x8*)(SM + cur * 32768 + 16384 +
                    ((ks * 4 + l4) * 256 + (wn + (jh * 2) * 16 + l15)) * 8);
      s16x8 b1 = *(const s16x8*)(SM + cur * 32768 + 16384 +
                    ((ks * 4 + l4) * 256 + (wn + (jh * 2 + 1) * 16 + l15)) * 8);
      __builtin_amdgcn_s_setprio(1);
      #pragma unroll
      for (int i = 0; i < 8; i++){
        acc[i][jh * 2]     = mfma16(af[i], b0, acc[i][jh * 2]);
        acc[i][jh * 2 + 1] = mfma16(af[i], b1, acc[i][jh * 2 + 1]);
      }
      __builtin_amdgcn_s_setprio(0);
    }
    __builtin_amdgcn_s_barrier();         // reads of buf cur done before re-stage
    __builtin_amdgcn_sched_barrier(0);
    cur = nxt;
  }
  #undef STAGEU

  // coalesced epilogue (proven r14/r19): LDS-transpose slabs + NT f32x4 stores
  float* ldsT = (float*)smem;
  const int RST = 260;
  int hs16 = (w >> 2) * 16;
  float badd[4];
  #pragma unroll
  for (int j = 0; j < 4; j++) badd[j] = ldf(bias, n0 + wn + j * 16 + l15, isbf);
  #pragma unroll
  for (int i = 0; i < 8; i++){
    __syncthreads();
    #pragma unroll
    for (int j = 0; j < 4; j++){
      int col = wn + j * 16 + l15;
      #pragma unroll
      for (int r = 0; r < 4; r++)
        ldsT[(hs16 + l4 * 4 + r) * RST + col] = acc[i][j][r] + badd[j];
    }
    __syncthreads();
    #pragma unroll
    for (int p = 0; p < 4; p++){
      int chunk = tid + p * 512;
      int lr = chunk >> 6, c4 = chunk & 63;
      int gm = m0 + (lr >> 4) * 128 + i * 16 + (lr & 15);
      f32x4 v = *(f32x4*)&ldsT[lr * RST + c4 * 4];
      __builtin_nontemporal_store(v, (f32x4*)&O[(long)gm * VV + n0 + c4 * 4]);
    }
  }
}

// ---------- merged q/k/v projection: one launch, 768 blocks ----------
__global__ __launch_bounds__(512, 2) void k_proj(
    const u16* __restrict__ xm2,
    const u16* __restrict__ Wq2, const u16* __restrict__ Wk2, const u16* __restrict__ WvT,
    u16* __restrict__ q2, u16* __restrict__ k2, u16* __restrict__ vT,
    const void* __restrict__ bq, const void* __restrict__ bk, const void* __restrict__ bv,
    const int* __restrict__ dflag)
{
  int isbf = dflag[0];
  int zz = blockIdx.z;
  int z, ldb, K, amap, bmap, mode;
  const u16* Bb; const void* bias; u16* C;
  if (zz < 16){
    mode = 0; z = zz & 7;
    Bb = (zz < 8 ? Wq2 : Wk2) + (long)z * 524288;
    ldb = 1024; K = KC; amap = 1; bmap = 2;
    bias = (zz < 8) ? bq : bk;
    C = (zz < 8) ? q2 : k2;
  } else {
    mode = 1; z = zz - 16;
    Bb = WvT + (long)z * 262144;
    ldb = 512; K = 512; amap = 0; bmap = 0;
    bias = bv;
    C = vT;
  }
  const u16* Ab = xm2;
  __shared__ __align__(16) char smem[65536];
  u16* SA = (u16*)smem;
  u16* SB = (u16*)(smem + 32768);
  int m0 = blockIdx.y * 256;
  int n0 = blockIdx.x * 256;
  int tid = threadIdx.x;
  int lane = tid & 63, w = tid >> 6;
  int wm = (w >> 2) * 128, wn = (w & 3) * 64;
  int l15 = lane & 15, l4 = lane >> 4;
  int row = tid & 255, ob = tid >> 8;
  f32x4 zero = {0.f, 0.f, 0.f, 0.f};
  f32x4 acc[8][4];
  #pragma unroll
  for (int i = 0; i < 8; i++)
    #pragma unroll
    for (int j = 0; j < 4; j++) acc[i][j] = zero;

  const long arow0 = (long)(m0 + row) * 1024;
  const long brow0 = (long)(n0 + row) * ldb;

  #define STAGEP(buf, k0_) do{ \
    int ka = (amap == 1) ? ((k0_) < 512 ? (k0_) : (k0_) - 512) : (k0_); \
    int kb = (bmap == 2) ? ((k0_) < 1024 ? (k0_) : (k0_) - 1024) : (k0_); \
    gload16(Ab + arow0 + ka + ob * 8,       SA + ((buf) * 8192 + (ob * 256 + row) * 8)); \
    gload16(Ab + arow0 + ka + (ob + 2) * 8, SA + ((buf) * 8192 + ((ob + 2) * 256 + row) * 8)); \
    gload16(Bb + brow0 + kb + ob * 8,       SB + ((buf) * 8192 + (ob * 256 + row) * 8)); \
    gload16(Bb + brow0 + kb + (ob + 2) * 8, SB + ((buf) * 8192 + ((ob + 2) * 256 + row) * 8)); \
  }while(0)

  #define COMPUTEP(buf) do{ \
    s16x8 bfr[4]; \
    _Pragma("unroll") \
    for (int j = 0; j < 4; j++) \
      bfr[j] = *(const s16x8*)(SB + ((buf) * 8192 + l4 * 2048 + (wn + j * 16 + l15) * 8)); \
    _Pragma("unroll") \
    for (int i = 0; i < 8; i++){ \
      s16x8 af = *(const s16x8*)(SA + ((buf) * 8192 + l4 * 2048 + (wm + i * 16 + l15) * 8)); \
      _Pragma("unroll") \
      for (int j = 0; j < 4; j++) \
        acc[i][j] = mfma16(af, bfr[j], acc[i][j]); \
    } \
  }while(0)

  STAGEP(0, 0);
  __syncthreads();
  for (int k0 = 0; k0 < K; k0 += 64){
    STAGEP(1, k0 + 32);
    COMPUTEP(0);
    __syncthreads();
    if (k0 + 64 < K) STAGEP(0, k0 + 64);
    COMPUTEP(1);
    __syncthreads();
  }
  #undef STAGEP
  #undef COMPUTEP

  int mbase = m0 + wm + l4 * 4;
  int nbase = n0 + wn + l15;
  if (mode == 0){
    u16* Cz = C + (long)z * ((long)MTOT * 1024);
    #pragma unroll
    for (int j = 0; j < 4; j++){
      int n = nbase + j * 16;
      float badd = ldf(bias, (long)z * DD + n, isbf);
      #pragma unroll
      for (int i = 0; i < 8; i++)
        #pragma unroll
        for (int r = 0; r < 4; r++){
          float qv = acc[i][j][r] + badd;
          u16 hi = f2bf(qv);
          u16 lo = f2bf(qv - bf2f(hi));
          long rb = (long)(mbase + i * 16 + r) * 1024;
          Cz[rb + n] = hi;
          Cz[rb + 512 + n] = lo;
        }
    }
  } else {
    #pragma unroll
    for (int i = 0; i < 8; i++){
      int mrow = mbase + i * 16;
      int b = mrow >> 9, s = mrow & (SS - 1);
      #pragma unroll
      for (int j = 0; j < 4; j++){
        int n = nbase + j * 16;
        float badd = ldf(bias, (long)z * DD + n, isbf);
        ushort4 pk;
        pk.x = f2bf(acc[i][j][0] + badd); pk.y = f2bf(acc[i][j][1] + badd);
        pk.z = f2bf(acc[i][j][2] + badd); pk.w = f2bf(acc[i][j][3] + badd);
        *(ushort4*)&C[((long)(z * 8 + b) * DD + n) * SS + s] = pk;
      }
    }
  }
}

// ---------- fused scores+softmax: 128 q-rows x full 512 k-cols per block ----------
template<int AMAP, int BMAP>
__global__ __launch_bounds__(512, 2) void k_fsm(
    const u16* __restrict__ A, long sA, int lda,
    const u16* __restrict__ Bt, long sB, int ldb,
    u16* __restrict__ P, int K, float scale,
    const int* __restrict__ dflag)
{
  int z = blockIdx.z;
  const u16* Ab = A + (long)z * sA;
  const u16* Bb = Bt + (long)z * sB;
  __shared__ __align__(16) char smem[81920];
  u16* SA = (u16*)smem;
  u16* SB = (u16*)(smem + 16384);
  int m0 = blockIdx.x * 128;
  int tid = threadIdx.x;
  int lane = tid & 63, w = tid >> 6;
  int wn = w * 64;
  int l15 = lane & 15, l4 = lane >> 4;
  f32x4 zero = {0.f, 0.f, 0.f, 0.f};
  f32x4 acc[8][4];
  #pragma unroll
  for (int i = 0; i < 8; i++)
    #pragma unroll
    for (int j = 0; j < 4; j++) acc[i][j] = zero;

  const long arow0 = (long)(m0 + (tid & 127)) * lda;
  const int akc = tid >> 7;
  const long brow0 = (long)tid * ldb;

  #define STAGEF(buf, k0_) do{ \
    int ka = (AMAP == 1) ? ((k0_) < 512 ? (k0_) : (k0_) - 512) \
           : (AMAP == 2) ? ((k0_) < 1024 ? (k0_) : (k0_) - 1024) : (k0_); \
    int kb = (BMAP == 1) ? ((k0_) < 512 ? (k0_) : (k0_) - 512) \
           : (BMAP == 2) ? ((k0_) < 1024 ? (k0_) : (k0_) - 1024) : (k0_); \
    gload16(Ab + arow0 + ka + akc * 8, SA + ((buf) * 4096 + tid * 8)); \
    gload16(Bb + brow0 + kb + 0,  SB + ((buf) * 16384 + (0 * 512 + tid) * 8)); \
    gload16(Bb + brow0 + kb + 8,  SB + ((buf) * 16384 + (1 * 512 + tid) * 8)); \
    gload16(Bb + brow0 + kb + 16, SB + ((buf) * 16384 + (2 * 512 + tid) * 8)); \
    gload16(Bb + brow0 + kb + 24, SB + ((buf) * 16384 + (3 * 512 + tid) * 8)); \
  }while(0)

  #define COMPUTEF(buf) do{ \
    s16x8 bfr[4]; \
    _Pragma("unroll") \
    for (int j = 0; j < 4; j++) \
      bfr[j] = *(const s16x8*)(SB + ((buf) * 16384 + l4 * 4096 + (wn + j * 16 + l15) * 8)); \
    _Pragma("unroll") \
    for (int i = 0; i < 8; i++){ \
      s16x8 af = *(const s16x8*)(SA + ((buf) * 4096 + l4 * 1024 + (i * 16 + l15) * 8)); \
      _Pragma("unroll") \
      for (int j = 0; j < 4; j++) \
        acc[i][j] = mfma16(af, bfr[j], acc[i][j]); \
    } \
  }while(0)

  STAGEF(0, 0);
  __syncthreads();
  for (int k0 = 0; k0 < K; k0 += 64){
    STAGEF(1, k0 + 32);
    COMPUTEF(0);
    __syncthreads();
    if (k0 + 64 < K) STAGEF(0, k0 + 64);
    COMPUTEF(1);
    __syncthreads();
  }
  #undef STAGEF
  #undef COMPUTEF

  float* sred = (float*)smem;
  float* srow = (float*)(smem + 4096);

  #pragma unroll
  for (int i = 0; i < 8; i++)
    #pragma unroll
    for (int j = 0; j < 4; j++)
      acc[i][j] *= scale;

  #pragma unroll
  for (int i = 0; i < 8; i++)
    #pragma unroll
    for (int r = 0; r < 4; r++){
      float m = fmaxf(fmaxf(acc[i][0][r], acc[i][1][r]),
                      fmaxf(acc[i][2][r], acc[i][3][r]));
      #pragma unroll
      for (int off = 1; off < 16; off <<= 1) m = fmaxf(m, __shfl_xor(m, off, 64));
      if (l15 == 0) sred[w * 128 + l4 * 4 + i * 16 + r] = m;
    }
  __syncthreads();
  if (tid < 128){
    float m = sred[tid];
    #pragma unroll
    for (int w2 = 1; w2 < 8; w2++) m = fmaxf(m, sred[w2 * 128 + tid]);
    srow[tid] = m;
  }
  __syncthreads();
  #pragma unroll
  for (int i = 0; i < 8; i++)
    #pragma unroll
    for (int r = 0; r < 4; r++){
      float rm = srow[l4 * 4 + i * 16 + r];
      float s = 0.f;
      #pragma unroll
      for (int j = 0; j < 4; j++){
        float e = expf(acc[i][j][r] - rm);
        acc[i][j][r] = e;
        s += e;
      }
      #pragma unroll
      for (int off = 1; off < 16; off <<= 1) s += __shfl_xor(s, off, 64);
      if (l15 == 0) sred[w * 128 + l4 * 4 + i * 16 + r] = s;
    }
  __syncthreads();
  if (tid < 128){
    float s = 0.f;
    #pragma unroll
    for (int w2 = 0; w2 < 8; w2++) s += sred[w2 * 128 + tid];
    srow[tid] = 1.f / s;
  }
  __syncthreads();
  // coalesced attn store: 32-row LDS slabs (u16, pad 520) then 8B-chunk writes
  u16* Pz = P + (long)z * ((long)SS * SS);
  u16* pb = (u16*)(smem + 8192);
  const int PST = 520;
  #pragma unroll
  for (int ii = 0; ii < 4; ii++){
    __syncthreads();
    #pragma unroll
    for (int s2 = 0; s2 < 2; s2++){
      int i = ii * 2 + s2;
      #pragma unroll
      for (int r = 0; r < 4; r++){
        int rl = l4 * 4 + i * 16 + r;
        float inv = srow[rl];
        #pragma unroll
        for (int j = 0; j < 4; j++)
          pb[(s2 * 16 + l4 * 4 + r) * PST + wn + j * 16 + l15] = f2bf(acc[i][j][r] * inv);
      }
    }
    __syncthreads();
    #pragma unroll
    for (int p = 0; p < 8; p++){
      int chunk = tid + p * 512;
      int lr = chunk >> 7, c8 = chunk & 127;
      ushort4 v = *(ushort4*)&pb[lr * PST + c8 * 4];
      *(ushort4*)&Pz[(long)(m0 + ii * 32 + lr) * SS + c8 * 4] = v;
    }
  }
}

// LayerNorm f32 -> bf16 (+ optional f32), one wave per row of 512
template<bool WF32>
__global__ __launch_bounds__(256) void k_ln(
    const float* __restrict__ X, const void* __restrict__ g, const void* __restrict__ be,
    u16* __restrict__ Yb, float* __restrict__ Yf, const int* __restrict__ dflag)
{
  int isbf = dflag[0];
  int row = blockIdx.x * 4 + (threadIdx.x >> 6);
  int lane = threadIdx.x & 63;
  const float* p = X + (long)row * DD + lane * 8;
  float4 v0 = *(const float4*)p;
  float4 v1 = *(const float4*)(p + 4);
  float v[8] = {v0.x, v0.y, v0.z, v0.w, v1.x, v1.y, v1.z, v1.w};
  float s = 0.f;
  #pragma unroll
  for (int i = 0; i < 8; i++) s += v[i];
  s = wave_redsum(s);
  float mu = s * (1.f / DD);
  float d_[8], sq = 0.f;
  #pragma unroll
  for (int i = 0; i < 8; i++){ d_[i] = v[i] - mu; sq += d_[i] * d_[i]; }
  sq = wave_redsum(sq);
  float rs = 1.f / sqrtf(sq * (1.f / DD) + 1e-5f);
  #pragma unroll
  for (int i = 0; i < 8; i++){
    int dd = lane * 8 + i;
    float y = ldf(g, dd, isbf) * d_[i] * rs + ldf(be, dd, isbf);
    Yb[(long)row * DD + dd] = f2bf(y);
    if (WF32) Yf[(long)row * DD + dd] = y;
  }
}

extern "C" void kernel_launch(void* const* d_in, const int* in_sizes, int n_in,
                              void* d_out, int out_size, void* d_ws, size_t ws_size,
                              hipStream_t stream)
{
  const int* tokens = (const int*)d_in[0];
  const void* emb = d_in[1];
  const void* pe  = d_in[2];
  const void* Wq  = d_in[3];
  const void* bq  = d_in[4];
  const void* Wk  = d_in[5];
  const void* bk  = d_in[6];
  const void* Wv  = d_in[7];
  const void* bv  = d_in[8];
  const void* Wo  = d_in[9];
  const void* bo  = d_in[10];
  const void* g1  = d_in[11];
  const void* be1 = d_in[12];
  const void* W1  = d_in[13];
  const void* b1  = d_in[14];
  const void* W2  = d_in[15];
  const void* b2  = d_in[16];
  const void* g2  = d_in[17];
  const void* be2 = d_in[18];
  const void* Wf  = d_in[19];
  const void* bfb = d_in[20];
  float* out = (float*)d_out;   // reference output dtype = float32
  char* ws = (char*)d_ws;
  char* DO = (char*)d_out;

  const size_t MB = 1ull << 20;
  // ---- d_ws (39.3 MiB; <=69 MiB evidenced safe) ----
  int* dflag = (int*)ws;
  u16* x2b   = (u16*)(ws + 1 * MB);        // [1,5)
  u16* WfT   = (u16*)(ws + 8 * MB);        // [8,39.25)  bf16 [32000][512]

  // ---- d_out as scratch (380 of 500 MiB; all dead before logits) ----
  float* x    = (float*)(DO + 0 * MB);     // [0,8)
  u16*   xm2  = (u16*)(DO + 8 * MB);       // [8,16)    [4096][1024] = [xh|xl]
  u16*   Wq2  = (u16*)(DO + 16 * MB);      // [16,24)   [8][512][1024] = [wh|wl]
  u16*   Wk2  = (u16*)(DO + 24 * MB);      // [24,32)
  u16*   WvT  = (u16*)(DO + 32 * MB);      // [32,36)   [8][512][512]
  u16*   WoT  = (u16*)(DO + 36 * MB);      // [36,40)   [512][4096]
  u16*   W1T  = (u16*)(DO + 40 * MB);      // [40,42)   [2048][512]
  u16*   W2T  = (u16*)(DO + 42 * MB);      // [42,44)   [512][2048]
  u16*   q2   = (u16*)(DO + 48 * MB);      // [48,112)  [8][4096][1024] = [qh|ql]
  u16*   k2   = (u16*)(DO + 112 * MB);     // [112,176) [8][4096][1024] = [kh|kl]
  u16*   attn = (u16*)(DO + 240 * MB);     // [240,272) [64][512][512] bf16
  u16*   vT   = (u16*)(DO + 272 * MB);     // [272,304) [64][512 d][512 s]
  u16*   cat  = (u16*)(DO + 304 * MB);     // [304,336) [4096][4096]
  float* proj = (float*)(DO + 336 * MB);   // [336,344)
  float* x1f  = (float*)(DO + 344 * MB);   // [344,352)
  u16*   x1b  = (u16*)(DO + 352 * MB);     // [352,356)
  u16*   ff1  = (u16*)(DO + 356 * MB);     // [356,372) [4096][2048]
  float* ff2  = (float*)(DO + 372 * MB);   // [372,380)

  const float scale = 0.04419417382415922f;  // 1/sqrt(512)
  const long HSL = 262144;                   // 512*512
  const long QSL = 524288;                   // 512*1024 (2-band q/k rows per z)

  k_dflag<<<1, 1, 0, stream>>>(pe, dflag);
  k_embed<<<dim3(4096), 256, 0, stream>>>(tokens, emb, pe, x, xm2, dflag);

  // one-time weight prep (2 launches)
  k_wsplitT<<<dim3(16, 16, 16), 256, 0, stream>>>(Wq, Wk, Wq2, Wk2, dflag);
  k_transAll<<<dim3(22144), 256, 0, stream>>>(
      Wv, Wo, W1, W2, Wf, WvT, WoT, W1T, W2T, WfT, dflag);

  // merged q/k/v projections: one 768-block launch (z<8 Q, z<16 K, z>=16 V)
  k_proj<<<dim3(2, 16, 24), 512, 0, stream>>>(
      xm2, Wq2, Wk2, WvT, q2, k2, vT, bq, bk, bv, dflag);

  // fused scores+softmax -> attn bf16 (no sc buffer); z = h*8+b
  k_fsm<1, 2><<<dim3(4, 1, 64), 512, 0, stream>>>(
      q2, QSL, 1024, k2, QSL, 1024, attn, KC, scale, dflag);

  // o = attn @ v -> cat (torch.cat head order)
  k_mfma2<EP_CAT, false, 0, 0><<<dim3(2, 2, 64), 512, 0, stream>>>(
      attn, HSL, SS, vT, HSL, 512, cat, nullptr, nullptr, SS, 0, 0.f, dflag);

  // proj = cat @ Wo + bo + x (128^2 kernel)
  k_mfma<EP_F32RES, false><<<dim3(4, 32, 1), 256, 0, stream>>>(
      cat, 0, HD, WoT, 0, proj, bo, x, HD, DD, 0.f, dflag);
  k_ln<true><<<dim3(1024), 256, 0, stream>>>(proj, g1, be1, x1b, x1f, dflag);

  // ff = relu(x1 @ W1 + b1) @ W2 + b2 + x1
  k_mfma<EP_RELU, false><<<dim3(16, 32, 1), 256, 0, stream>>>(
      x1b, 0, DD, W1T, 0, ff1, b1, nullptr, DD, NFF, 0.f, dflag);
  k_mfma<EP_F32RES, false><<<dim3(4, 32, 1), 256, 0, stream>>>(
      ff1, 0, NFF, W2T, 0, ff2, b2, x1f, NFF, DD, 0.f, dflag);
  k_ln<false><<<dim3(1024), 256, 0, stream>>>(ff2, g2, be2, x2b, nullptr, dflag);

  // logits = x2 @ Wf + bf -> f32 out: 8-phase counted-vmcnt kernel (NT = 512/64)
  k_out8<<<dim3(16, 125, 1), 512, 0, stream>>>(x2b, WfT, out, bfb, 8, dflag);
}

// Round 22
// 929.549 us; speedup vs baseline: 1.0785x; 1.0439x over previous
//
#include <hip/hip_runtime.h>

typedef unsigned short u16;
typedef unsigned int u32;
typedef short s16x8 __attribute__((ext_vector_type(8)));
typedef __bf16 bf16x8 __attribute__((ext_vector_type(8)));
typedef float f32x4 __attribute__((ext_vector_type(4)));

#define DEVI static __device__ __forceinline__

#define SS 512
#define DD 512
#define NFF 2048
#define VV 32000
#define MTOT 4096
#define HD 4096
#define KC 1536   // virtual split-concat K (2-band storage + read-time remap)

DEVI float bf2f(u16 h){ return __uint_as_float(((u32)h) << 16); }
DEVI u16 f2bf(float f){
  u32 u = __float_as_uint(f);
  return (u16)((u + 0x7FFFu + ((u >> 16) & 1u)) >> 16);
}
DEVI float ldf(const void* p, long i, int isbf){
  return isbf ? bf2f(((const u16*)p)[i]) : ((const float*)p)[i];
}

DEVI f32x4 mfma16(s16x8 a, s16x8 b, f32x4 c){
  return __builtin_amdgcn_mfma_f32_16x16x32_bf16(
      __builtin_bit_cast(bf16x8, a), __builtin_bit_cast(bf16x8, b), c, 0, 0, 0);
}

// direct global->LDS 16B copy; dst is wave-uniform base + lane*16, src per-lane
typedef const __attribute__((address_space(1))) unsigned int* gup;
typedef __attribute__((address_space(3))) unsigned int* lup;
DEVI void gload16(const void* g, void* l){
  __builtin_amdgcn_global_load_lds((gup)g, (lup)l, 16, 0, 0);
}

DEVI float wave_redsum(float v){
  #pragma unroll
  for (int off = 32; off > 0; off >>= 1) v += __shfl_xor(v, off, 64);
  return v;
}

// pe row0 = [sin0=0, cos0=1, ...]: first u32 word = 0x3F800000 if bf16, 0x00000000 if f32
__global__ void k_dflag(const void* pe, int* flag){
  flag[0] = (*(const u32*)pe == 0x3F800000u) ? 1 : 0;
}

// embed + residual + masked 2-band split: xm2[m][0:512]=hi, [512:1024]=lo
__global__ __launch_bounds__(256) void k_embed(
    const int* __restrict__ tok, const void* __restrict__ emb, const void* __restrict__ pe,
    float* __restrict__ x, u16* __restrict__ xm2, const int* __restrict__ dflag)
{
  int isbf = dflag[0];
  int blk = blockIdx.x;
  int s = blk & (SS - 1);
  int t = tok[blk];
  long rb = (long)blk * 1024;
  for (int d = threadIdx.x; d < DD; d += 256){
    float e = ldf(emb, (long)t * DD + d, isbf) + ldf(pe, (long)s * DD + d, isbf);
    x[(long)blk * DD + d] = e;
    float m = (d <= s) ? e : 0.f;           // triu(ones(S,D),k=1) zeroes d > s
    u16 hi = f2bf(m);
    u16 lo = f2bf(m - bf2f(hi));
    xm2[rb + d] = hi;
    xm2[rb + 512 + d] = lo;
  }
}

// split-transpose for Wq AND Wk (zz<8: Wq slice zz; else Wk slice zz-8):
// in W[z][512 d][512 e] -> out[z][512 e][1024]: band0=hi, band1=lo
__global__ __launch_bounds__(256) void k_wsplitT(
    const void* __restrict__ Wq, const void* __restrict__ Wk,
    u16* __restrict__ Wq2, u16* __restrict__ Wk2, const int* __restrict__ dflag)
{
  int isbf = dflag[0];
  int zz = blockIdx.z;
  const void* in = (zz < 8) ? Wq : Wk;
  u16* out = (zz < 8) ? Wq2 : Wk2;
  int z = zz & 7;
  long zin = (long)z * DD * DD;
  long zout = (long)z * DD * 1024;
  __shared__ float t[32][33];
  int e0 = blockIdx.x * 32, d0 = blockIdx.y * 32;
  int tx = threadIdx.x & 31, ty = threadIdx.x >> 5;
  #pragma unroll
  for (int i = 0; i < 4; i++){
    int d = ty + i * 8;
    t[d][tx] = ldf(in, zin + (long)(d0 + d) * DD + e0 + tx, isbf);
  }
  __syncthreads();
  #pragma unroll
  for (int i = 0; i < 4; i++){
    int e = ty + i * 8;
    float v = t[tx][e];
    u16 hi = f2bf(v);
    u16 lo = f2bf(v - bf2f(hi));
    long ob = zout + (long)(e0 + e) * 1024 + d0 + tx;
    out[ob] = hi;
    out[ob + 512] = lo;
  }
}

// all 5 plain transposes (f32/bf16 -> bf16) in one flat-grid kernel.
__global__ __launch_bounds__(256) void k_transAll(
    const void* __restrict__ Wv, const void* __restrict__ Wo,
    const void* __restrict__ W1, const void* __restrict__ W2,
    const void* __restrict__ Wf,
    u16* __restrict__ WvT, u16* __restrict__ WoT, u16* __restrict__ W1T,
    u16* __restrict__ W2T, u16* __restrict__ WfT, const int* __restrict__ dflag)
{
  int isbf = dflag[0];
  int f = blockIdx.x;
  const void* in; u16* out; int R, C, gx, loc;
  if (f < 2048)      { in = Wv; out = WvT; R = 512;  C = 512;   gx = 16;   loc = f; }
  else if (f < 4096) { in = Wo; out = WoT; R = 4096; C = 512;   gx = 16;   loc = f - 2048; }
  else if (f < 5120) { in = W1; out = W1T; R = 512;  C = 2048;  gx = 64;   loc = f - 4096; }
  else if (f < 6144) { in = W2; out = W2T; R = 2048; C = 512;   gx = 16;   loc = f - 5120; }
  else               { in = Wf; out = WfT; R = 512;  C = 32000; gx = 1000; loc = f - 6144; }
  int bx = loc % gx;
  int rest = loc / gx;
  int gy = R >> 5;
  int by = rest % gy, z = rest / gy;
  long zo = (long)z * R * C;
  __shared__ float t[32][33];
  int c0 = bx * 32, r0 = by * 32;
  int tx = threadIdx.x & 31, ty = threadIdx.x >> 5;
  #pragma unroll
  for (int i = 0; i < 4; i++){
    int r = ty + i * 8;
    t[r][tx] = ldf(in, zo + (long)(r0 + r) * C + c0 + tx, isbf);
  }
  __syncthreads();
  #pragma unroll
  for (int i = 0; i < 4; i++){
    int c = ty + i * 8;
    out[zo + (long)(c0 + c) * R + r0 + tx] = f2bf(t[tx][c]);
  }
}

enum { EP_QK = 0, EP_SCALE = 1, EP_VT = 2, EP_CAT = 3, EP_OUT = 4,
       EP_F32RES = 5, EP_RELU = 6 };

// ---------- 128x128 tile, 4 waves (small-N GEMMs: Wo, FF1, FF2) ----------
template<int MODE, bool GSWAP>
__global__ __launch_bounds__(256) void k_mfma(
    const u16* __restrict__ A, long sA, int lda,
    const u16* __restrict__ Bt, long sB,
    void* __restrict__ Cv,
    const void* __restrict__ bias,
    const float* __restrict__ res,
    int K, int ldc, float scale,
    const int* __restrict__ dflag)
{
  int isbf = dflag[0];
  int z = blockIdx.z;
  const u16* Ab = A + (long)z * sA;
  const u16* Bb = Bt + (long)z * sB;
  __shared__ __align__(16) u16 As[2][4][128][8];
  __shared__ __align__(16) u16 Bs[2][4][128][8];
  int m0 = (GSWAP ? blockIdx.x : blockIdx.y) * 128;
  int n0 = (GSWAP ? blockIdx.y : blockIdx.x) * 128;
  int tid = threadIdx.x;
  int lane = tid & 63, w = tid >> 6;
  int wr = (w >> 1) * 64, wc = (w & 1) * 64;
  int l15 = lane & 15, l4 = lane >> 4;
  int s0 = w * 64 + lane;
  int ar0 = s0 & 127, ak0 = s0 >> 7;
  int ak1 = ak0 + 2;
  f32x4 zero = {0.f, 0.f, 0.f, 0.f};
  f32x4 acc[4][4];
  #pragma unroll
  for (int i = 0; i < 4; i++)
    #pragma unroll
    for (int j = 0; j < 4; j++) acc[i][j] = zero;

  const long arow0 = (long)(m0 + ar0) * lda;
  const long brow0 = (long)(n0 + ar0) * K;

  #define STAGE(buf, k0) do{ \
    u16* AsF = &As[buf][0][0][0]; \
    u16* BsF = &Bs[buf][0][0][0]; \
    gload16(Ab + arow0 + (k0) + ak0 * 8, AsF + (long)(w * 64) * 8); \
    gload16(Ab + arow0 + (k0) + ak1 * 8, AsF + (long)(256 + w * 64) * 8); \
    gload16(Bb + brow0 + (k0) + ak0 * 8, BsF + (long)(w * 64) * 8); \
    gload16(Bb + brow0 + (k0) + ak1 * 8, BsF + (long)(256 + w * 64) * 8); \
  }while(0)

  #define COMPUTE(buf) do{ \
    s16x8 af[4], bfr[4]; \
    _Pragma("unroll") \
    for (int i = 0; i < 4; i++) af[i] = *(const s16x8*)&As[buf][l4][wr + i * 16 + l15][0]; \
    _Pragma("unroll") \
    for (int j = 0; j < 4; j++) bfr[j] = *(const s16x8*)&Bs[buf][l4][wc + j * 16 + l15][0]; \
    _Pragma("unroll") \
    for (int i = 0; i < 4; i++) \
      _Pragma("unroll") \
      for (int j = 0; j < 4; j++) \
        acc[i][j] = mfma16(af[i], bfr[j], acc[i][j]); \
  }while(0)

  STAGE(0, 0);
  __syncthreads();
  for (int k0 = 0; k0 < K; k0 += 64){
    STAGE(1, k0 + 32);
    COMPUTE(0);
    __syncthreads();
    if (k0 + 64 < K) STAGE(0, k0 + 64);
    COMPUTE(1);
    __syncthreads();
  }
  #undef STAGE
  #undef COMPUTE

  int mbase = m0 + wr + l4 * 4;
  int nbase = n0 + wc + l15;
  if constexpr (MODE == EP_F32RES){
    float* C = (float*)Cv;
    #pragma unroll
    for (int j = 0; j < 4; j++){
      int n = nbase + j * 16;
      float badd = ldf(bias, n, isbf);
      #pragma unroll
      for (int i = 0; i < 4; i++)
        #pragma unroll
        for (int r = 0; r < 4; r++){
          long a = (long)(mbase + i * 16 + r) * ldc + n;
          C[a] = acc[i][j][r] + badd + res[a];
        }
    }
  } else if constexpr (MODE == EP_RELU){
    u16* C = (u16*)Cv;
    #pragma unroll
    for (int j = 0; j < 4; j++){
      int n = nbase + j * 16;
      float badd = ldf(bias, n, isbf);
      #pragma unroll
      for (int i = 0; i < 4; i++)
        #pragma unroll
        for (int r = 0; r < 4; r++)
          C[(long)(mbase + i * 16 + r) * ldc + n] = f2bf(fmaxf(acc[i][j][r] + badd, 0.f));
    }
  }
}

// ---------- 256x256 tile, 8 waves (2M x 4N), BK=32, 2-phase dbuf ----------
// (used for attn@v; launch_bounds(512,2): 92 VGPR, no spill)
template<int MODE, bool GSWAP, int AMAP, int BMAP>
__global__ __launch_bounds__(512, 2) void k_mfma2(
    const u16* __restrict__ A, long sA, int lda,
    const u16* __restrict__ Bt, long sB, int ldb,
    void* __restrict__ Cv,
    const void* __restrict__ bias,
    const float* __restrict__ res,
    int K, int ldc, float scale,
    const int* __restrict__ dflag)
{
  int isbf = dflag[0];
  int z = blockIdx.z;
  const u16* Ab = A + (long)z * sA;
  const u16* Bb = Bt + (long)z * sB;
  __shared__ __align__(16) char smem[65536];
  u16* SA = (u16*)smem;
  u16* SB = (u16*)(smem + 32768);
  int m0 = (GSWAP ? blockIdx.x : blockIdx.y) * 256;
  int n0 = (GSWAP ? blockIdx.y : blockIdx.x) * 256;
  int tid = threadIdx.x;
  int lane = tid & 63, w = tid >> 6;
  int wm = (w >> 2) * 128, wn = (w & 3) * 64;
  int l15 = lane & 15, l4 = lane >> 4;
  int row = tid & 255, ob = tid >> 8;
  f32x4 zero = {0.f, 0.f, 0.f, 0.f};
  f32x4 acc[8][4];
  #pragma unroll
  for (int i = 0; i < 8; i++)
    #pragma unroll
    for (int j = 0; j < 4; j++) acc[i][j] = zero;

  const long arow0 = (long)(m0 + row) * lda;
  const long brow0 = (long)(n0 + row) * ldb;

  #define STAGE2(buf, k0_) do{ \
    int ka = (AMAP == 1) ? ((k0_) < 512 ? (k0_) : (k0_) - 512) \
           : (AMAP == 2) ? ((k0_) < 1024 ? (k0_) : (k0_) - 1024) : (k0_); \
    int kb = (BMAP == 1) ? ((k0_) < 512 ? (k0_) : (k0_) - 512) \
           : (BMAP == 2) ? ((k0_) < 1024 ? (k0_) : (k0_) - 1024) : (k0_); \
    gload16(Ab + arow0 + ka + ob * 8,       SA + ((buf) * 8192 + (ob * 256 + row) * 8)); \
    gload16(Ab + arow0 + ka + (ob + 2) * 8, SA + ((buf) * 8192 + ((ob + 2) * 256 + row) * 8)); \
    gload16(Bb + brow0 + kb + ob * 8,       SB + ((buf) * 8192 + (ob * 256 + row) * 8)); \
    gload16(Bb + brow0 + kb + (ob + 2) * 8, SB + ((buf) * 8192 + ((ob + 2) * 256 + row) * 8)); \
  }while(0)

  #define COMPUTE2(buf) do{ \
    s16x8 bfr[4]; \
    _Pragma("unroll") \
    for (int j = 0; j < 4; j++) \
      bfr[j] = *(const s16x8*)(SB + ((buf) * 8192 + l4 * 2048 + (wn + j * 16 + l15) * 8)); \
    _Pragma("unroll") \
    for (int i = 0; i < 8; i++){ \
      s16x8 af = *(const s16x8*)(SA + ((buf) * 8192 + l4 * 2048 + (wm + i * 16 + l15) * 8)); \
      _Pragma("unroll") \
      for (int j = 0; j < 4; j++) \
        acc[i][j] = mfma16(af, bfr[j], acc[i][j]); \
    } \
  }while(0)

  STAGE2(0, 0);
  __syncthreads();
  for (int k0 = 0; k0 < K; k0 += 64){
    STAGE2(1, k0 + 32);
    COMPUTE2(0);
    __syncthreads();
    if (k0 + 64 < K) STAGE2(0, k0 + 64);
    COMPUTE2(1);
    __syncthreads();
  }
  #undef STAGE2
  #undef COMPUTE2

  int mbase = m0 + wm + l4 * 4;
  int nbase = n0 + wn + l15;
  if constexpr (MODE == EP_CAT){
    // cat[(b*S + s)][h*D + n]; z = h*8+b
    u16* C = (u16*)Cv;
    int h = z >> 3, b = z & 7;
    #pragma unroll
    for (int i = 0; i < 8; i++){
      int s = mbase + i * 16;
      #pragma unroll
      for (int j = 0; j < 4; j++){
        int n = nbase + j * 16;
        #pragma unroll
        for (int r = 0; r < 4; r++)
          C[((long)b * SS + s + r) * HD + (long)h * DD + n] = f2bf(acc[i][j][r]);
      }
    }
  }
}

// ---------- 8-phase counted-vmcnt 256x256 GEMM for logits (K=NT*64) ----------
// (r21-proven) BK=64 K-tiles, 2x64KB LDS buffers, half-tile staging, 4 MFMA
// phases/tile; one counted s_waitcnt vmcnt(2) per tile; raw s_barrier fences.
__global__ __launch_bounds__(512, 2) void k_out8(
    const u16* __restrict__ A, const u16* __restrict__ Bt,
    float* __restrict__ O, const void* __restrict__ bias,
    int NT, const int* __restrict__ dflag)
{
  int isbf = dflag[0];
  __shared__ __align__(16) char smem[131072];   // 2 bufs x (A 32KB | B 32KB)
  u16* SM = (u16*)smem;
  // bijective XCD remap (nwg = 16*125 = 2000, %8 == 0)
  int f = blockIdx.x + gridDim.x * blockIdx.y;
  int qx = (gridDim.x * gridDim.y) >> 3;
  int L = (f & 7) * qx + (f >> 3);
  int m0 = (L % gridDim.x) * 256;
  int n0 = (L / gridDim.x) * 256;
  int tid = threadIdx.x;
  int lane = tid & 63, w = tid >> 6;
  int wm = (w >> 2) * 128, wn = (w & 3) * 64;
  int l15 = lane & 15, l4 = lane >> 4;
  f32x4 zero = {0.f, 0.f, 0.f, 0.f};
  f32x4 acc[8][4];
  #pragma unroll
  for (int i = 0; i < 8; i++)
    #pragma unroll
    for (int j = 0; j < 4; j++) acc[i][j] = zero;

  int rr = tid & 127, kc1 = tid >> 7;   // staging: row-in-half, k-chunk 0..3

  #define STAGEU(c, Tt, u) do{ \
    const u16* gb = (((u) & 1) == 0) ? A : Bt; \
    int base0 = (((u) & 1) == 0) ? m0 : n0; \
    int r2 = ((u) >> 1) * 128 + rr; \
    long gsrc = (long)(base0 + r2) * 512 + (Tt) * 64; \
    u16* lb = SM + (c) * 32768 + ((((u) & 1) == 0) ? 0 : 16384); \
    gload16(gb + gsrc + kc1 * 8,       lb + (kc1 * 256 + r2) * 8); \
    gload16(gb + gsrc + (kc1 + 4) * 8, lb + ((kc1 + 4) * 256 + r2) * 8); \
  }while(0)

  STAGEU(0, 0, 0); STAGEU(0, 0, 1); STAGEU(0, 0, 2); STAGEU(0, 0, 3);

  int cur = 0;
  for (int T = 0; T < NT; T++){
    int nxt = cur ^ 1;
    int more = (T + 1 < NT);
    s16x8 af[8];
    #pragma unroll
    for (int q = 0; q < 4; q++){
      if (more) STAGEU(nxt, T + 1, q);
      if (q == 0){
        if (more) asm volatile("s_waitcnt vmcnt(2)" ::: "memory");
        else      asm volatile("s_waitcnt vmcnt(0)" ::: "memory");
      }
      __builtin_amdgcn_s_barrier();
      __builtin_amdgcn_sched_barrier(0);
      int ks = q >> 1, jh = q & 1;
      if (jh == 0){
        #pragma unroll
        for (int i = 0; i < 8; i++)
          af[i] = *(const s16x8*)(SM + cur * 32768 +
                    ((ks * 4 + l4) * 256 + (wm + i * 16 + l15)) * 8);
      }
      s16x8 b0 = *(const s16x8*)(SM + cur * 32768 + 16384 +
                    ((ks * 4 + l4) * 256 + (wn + (jh * 2) * 16 + l15)) * 8);
      s16x8 b1 = *(const s16x8*)(SM + cur * 32768 + 16384 +
                    ((ks * 4 + l4) * 256 + (wn + (jh * 2 + 1) * 16 + l15)) * 8);
      __builtin_amdgcn_s_setprio(1);
      #pragma unroll
      for (int i = 0; i < 8; i++){
        acc[i][jh * 2]     = mfma16(af[i], b0, acc[i][jh * 2]);
        acc[i][jh * 2 + 1] = mfma16(af[i], b1, acc[i][jh * 2 + 1]);
      }
      __builtin_amdgcn_s_setprio(0);
    }
    __builtin_amdgcn_s_barrier();
    __builtin_amdgcn_sched_barrier(0);
    cur = nxt;
  }
  #undef STAGEU

  // coalesced epilogue: LDS-transpose slabs + NT f32x4 stores
  float* ldsT = (float*)smem;
  const int RST = 260;
  int hs16 = (w >> 2) * 16;
  float badd[4];
  #pragma unroll
  for (int j = 0; j < 4; j++) badd[j] = ldf(bias, n0 + wn + j * 16 + l15, isbf);
  #pragma unroll
  for (int i = 0; i < 8; i++){
    __syncthreads();
    #pragma unroll
    for (int j = 0; j < 4; j++){
      int col = wn + j * 16 + l15;
      #pragma unroll
      for (int r = 0; r < 4; r++)
        ldsT[(hs16 + l4 * 4 + r) * RST + col] = acc[i][j][r] + badd[j];
    }
    __syncthreads();
    #pragma unroll
    for (int p = 0; p < 4; p++){
      int chunk = tid + p * 512;
      int lr = chunk >> 6, c4 = chunk & 63;
      int gm = m0 + (lr >> 4) * 128 + i * 16 + (lr & 15);
      f32x4 v = *(f32x4*)&ldsT[lr * RST + c4 * 4];
      __builtin_nontemporal_store(v, (f32x4*)&O[(long)gm * VV + n0 + c4 * 4]);
    }
  }
}

// ---------- 8-phase merged q/k/v projection (r21 k_out8 schedule) ----------
// zz<16: Q/K (virtual K=1536, NT=24, per-tile band remap) | zz>=16: V (NT=8).
// Same STAGEU geometry, vmcnt(2)-per-tile accounting, and barrier placement
// as the r21-verified k_out8; only addressing + epilogue differ.
__global__ __launch_bounds__(512, 2) void k_proj8(
    const u16* __restrict__ xm2,
    const u16* __restrict__ Wq2, const u16* __restrict__ Wk2, const u16* __restrict__ WvT,
    u16* __restrict__ q2, u16* __restrict__ k2, u16* __restrict__ vT,
    const void* __restrict__ bq, const void* __restrict__ bk, const void* __restrict__ bv,
    const int* __restrict__ dflag)
{
  int isbf = dflag[0];
  int zz = blockIdx.z;
  int z, ldb, NT, mode;
  const u16* Bb; const void* bias; u16* C;
  if (zz < 16){
    mode = 0; z = zz & 7;
    Bb = (zz < 8 ? Wq2 : Wk2) + (long)z * 524288;
    ldb = 1024; NT = 24;
    bias = (zz < 8) ? bq : bk;
    C = (zz < 8) ? q2 : k2;
  } else {
    mode = 1; z = zz - 16;
    Bb = WvT + (long)z * 262144;
    ldb = 512; NT = 8;
    bias = bv;
    C = vT;
  }
  const u16* Ab = xm2;
  __shared__ __align__(16) char smem[131072];
  u16* SM = (u16*)smem;
  int m0 = blockIdx.y * 256;
  int n0 = blockIdx.x * 256;
  int tid = threadIdx.x;
  int lane = tid & 63, w = tid >> 6;
  int wm = (w >> 2) * 128, wn = (w & 3) * 64;
  int l15 = lane & 15, l4 = lane >> 4;
  f32x4 zero = {0.f, 0.f, 0.f, 0.f};
  f32x4 acc[8][4];
  #pragma unroll
  for (int i = 0; i < 8; i++)
    #pragma unroll
    for (int j = 0; j < 4; j++) acc[i][j] = zero;

  int rr = tid & 127, kc1 = tid >> 7;

  // per-tile band remap (BK=64 tiles never straddle 512-aligned bands):
  // mode 0: A [xh|xh|xl]: ka = tk<512? tk : tk-512;  B [wh|wl|wh]: kb = tk<1024? tk : tk-1024
  // mode 1: identity (K=512)
  #define KA8(Tt) (mode == 0 ? (((Tt) * 64 < 512) ? (Tt) * 64 : (Tt) * 64 - 512) : (Tt) * 64)
  #define KB8(Tt) (mode == 0 ? (((Tt) * 64 < 1024) ? (Tt) * 64 : (Tt) * 64 - 1024) : (Tt) * 64)

  #define STAGEU(c, Tt, u) do{ \
    const u16* gb = (((u) & 1) == 0) ? Ab : Bb; \
    long rs = (((u) & 1) == 0) ? 1024 : (long)ldb; \
    int base0 = (((u) & 1) == 0) ? m0 : n0; \
    int tk = (((u) & 1) == 0) ? KA8(Tt) : KB8(Tt); \
    int r2 = ((u) >> 1) * 128 + rr; \
    long gsrc = (long)(base0 + r2) * rs + tk; \
    u16* lb = SM + (c) * 32768 + ((((u) & 1) == 0) ? 0 : 16384); \
    gload16(gb + gsrc + kc1 * 8,       lb + (kc1 * 256 + r2) * 8); \
    gload16(gb + gsrc + (kc1 + 4) * 8, lb + ((kc1 + 4) * 256 + r2) * 8); \
  }while(0)

  STAGEU(0, 0, 0); STAGEU(0, 0, 1); STAGEU(0, 0, 2); STAGEU(0, 0, 3);

  int cur = 0;
  for (int T = 0; T < NT; T++){
    int nxt = cur ^ 1;
    int more = (T + 1 < NT);
    s16x8 af[8];
    #pragma unroll
    for (int q = 0; q < 4; q++){
      if (more) STAGEU(nxt, T + 1, q);
      if (q == 0){
        if (more) asm volatile("s_waitcnt vmcnt(2)" ::: "memory");
        else      asm volatile("s_waitcnt vmcnt(0)" ::: "memory");
      }
      __builtin_amdgcn_s_barrier();
      __builtin_amdgcn_sched_barrier(0);
      int ks = q >> 1, jh = q & 1;
      if (jh == 0){
        #pragma unroll
        for (int i = 0; i < 8; i++)
          af[i] = *(const s16x8*)(SM + cur * 32768 +
                    ((ks * 4 + l4) * 256 + (wm + i * 16 + l15)) * 8);
      }
      s16x8 b0 = *(const s16x8*)(SM + cur * 32768 + 16384 +
                    ((ks * 4 + l4) * 256 + (wn + (jh * 2) * 16 + l15)) * 8);
      s16x8 b1 = *(const s16x8*)(SM + cur * 32768 + 16384 +
                    ((ks * 4 + l4) * 256 + (wn + (jh * 2 + 1) * 16 + l15)) * 8);
      __builtin_amdgcn_s_setprio(1);
      #pragma unroll
      for (int i = 0; i < 8; i++){
        acc[i][jh * 2]     = mfma16(af[i], b0, acc[i][jh * 2]);
        acc[i][jh * 2 + 1] = mfma16(af[i], b1, acc[i][jh * 2 + 1]);
      }
      __builtin_amdgcn_s_setprio(0);
    }
    __builtin_amdgcn_s_barrier();
    __builtin_amdgcn_sched_barrier(0);
    cur = nxt;
  }
  #undef STAGEU
  #undef KA8
  #undef KB8

  int mbase = m0 + wm + l4 * 4;
  int nbase = n0 + wn + l15;
  if (mode == 0){
    // 2-band out: C[row][n]=hi, C[row][512+n]=lo, row stride 1024
    u16* Cz = C + (long)z * ((long)MTOT * 1024);
    #pragma unroll
    for (int j = 0; j < 4; j++){
      int n = nbase + j * 16;
      float badd = ldf(bias, (long)z * DD + n, isbf);
      #pragma unroll
      for (int i = 0; i < 8; i++)
        #pragma unroll
        for (int r = 0; r < 4; r++){
          float qv = acc[i][j][r] + badd;
          u16 hi = f2bf(qv);
          u16 lo = f2bf(qv - bf2f(hi));
          long rb = (long)(mbase + i * 16 + r) * 1024;
          Cz[rb + n] = hi;
          Cz[rb + 512 + n] = lo;
        }
    }
  } else {
    // vT[(z*8 + b)][d = n][s]; 4 acc regs = 4 consecutive s
    #pragma unroll
    for (int i = 0; i < 8; i++){
      int mrow = mbase + i * 16;
      int b = mrow >> 9, s = mrow & (SS - 1);
      #pragma unroll
      for (int j = 0; j < 4; j++){
        int n = nbase + j * 16;
        float badd = ldf(bias, (long)z * DD + n, isbf);
        ushort4 pk;
        pk.x = f2bf(acc[i][j][0] + badd); pk.y = f2bf(acc[i][j][1] + badd);
        pk.z = f2bf(acc[i][j][2] + badd); pk.w = f2bf(acc[i][j][3] + badd);
        *(ushort4*)&C[((long)(z * 8 + b) * DD + n) * SS + s] = pk;
      }
    }
  }
}

// ---------- fused scores+softmax: 128 q-rows x full 512 k-cols per block ----------
template<int AMAP, int BMAP>
__global__ __launch_bounds__(512, 2) void k_fsm(
    const u16* __restrict__ A, long sA, int lda,
    const u16* __restrict__ Bt, long sB, int ldb,
    u16* __restrict__ P, int K, float scale,
    const int* __restrict__ dflag)
{
  int z = blockIdx.z;
  const u16* Ab = A + (long)z * sA;
  const u16* Bb = Bt + (long)z * sB;
  __shared__ __align__(16) char smem[81920];
  u16* SA = (u16*)smem;
  u16* SB = (u16*)(smem + 16384);
  int m0 = blockIdx.x * 128;
  int tid = threadIdx.x;
  int lane = tid & 63, w = tid >> 6;
  int wn = w * 64;
  int l15 = lane & 15, l4 = lane >> 4;
  f32x4 zero = {0.f, 0.f, 0.f, 0.f};
  f32x4 acc[8][4];
  #pragma unroll
  for (int i = 0; i < 8; i++)
    #pragma unroll
    for (int j = 0; j < 4; j++) acc[i][j] = zero;

  const long arow0 = (long)(m0 + (tid & 127)) * lda;
  const int akc = tid >> 7;
  const long brow0 = (long)tid * ldb;

  #define STAGEF(buf, k0_) do{ \
    int ka = (AMAP == 1) ? ((k0_) < 512 ? (k0_) : (k0_) - 512) \
           : (AMAP == 2) ? ((k0_) < 1024 ? (k0_) : (k0_) - 1024) : (k0_); \
    int kb = (BMAP == 1) ? ((k0_) < 512 ? (k0_) : (k0_) - 512) \
           : (BMAP == 2) ? ((k0_) < 1024 ? (k0_) : (k0_) - 1024) : (k0_); \
    gload16(Ab + arow0 + ka + akc * 8, SA + ((buf) * 4096 + tid * 8)); \
    gload16(Bb + brow0 + kb + 0,  SB + ((buf) * 16384 + (0 * 512 + tid) * 8)); \
    gload16(Bb + brow0 + kb + 8,  SB + ((buf) * 16384 + (1 * 512 + tid) * 8)); \
    gload16(Bb + brow0 + kb + 16, SB + ((buf) * 16384 + (2 * 512 + tid) * 8)); \
    gload16(Bb + brow0 + kb + 24, SB + ((buf) * 16384 + (3 * 512 + tid) * 8)); \
  }while(0)

  #define COMPUTEF(buf) do{ \
    s16x8 bfr[4]; \
    _Pragma("unroll") \
    for (int j = 0; j < 4; j++) \
      bfr[j] = *(const s16x8*)(SB + ((buf) * 16384 + l4 * 4096 + (wn + j * 16 + l15) * 8)); \
    _Pragma("unroll") \
    for (int i = 0; i < 8; i++){ \
      s16x8 af = *(const s16x8*)(SA + ((buf) * 4096 + l4 * 1024 + (i * 16 + l15) * 8)); \
      _Pragma("unroll") \
      for (int j = 0; j < 4; j++) \
        acc[i][j] = mfma16(af, bfr[j], acc[i][j]); \
    } \
  }while(0)

  STAGEF(0, 0);
  __syncthreads();
  for (int k0 = 0; k0 < K; k0 += 64){
    STAGEF(1, k0 + 32);
    COMPUTEF(0);
    __syncthreads();
    if (k0 + 64 < K) STAGEF(0, k0 + 64);
    COMPUTEF(1);
    __syncthreads();
  }
  #undef STAGEF
  #undef COMPUTEF

  float* sred = (float*)smem;
  float* srow = (float*)(smem + 4096);

  #pragma unroll
  for (int i = 0; i < 8; i++)
    #pragma unroll
    for (int j = 0; j < 4; j++)
      acc[i][j] *= scale;

  #pragma unroll
  for (int i = 0; i < 8; i++)
    #pragma unroll
    for (int r = 0; r < 4; r++){
      float m = fmaxf(fmaxf(acc[i][0][r], acc[i][1][r]),
                      fmaxf(acc[i][2][r], acc[i][3][r]));
      #pragma unroll
      for (int off = 1; off < 16; off <<= 1) m = fmaxf(m, __shfl_xor(m, off, 64));
      if (l15 == 0) sred[w * 128 + l4 * 4 + i * 16 + r] = m;
    }
  __syncthreads();
  if (tid < 128){
    float m = sred[tid];
    #pragma unroll
    for (int w2 = 1; w2 < 8; w2++) m = fmaxf(m, sred[w2 * 128 + tid]);
    srow[tid] = m;
  }
  __syncthreads();
  #pragma unroll
  for (int i = 0; i < 8; i++)
    #pragma unroll
    for (int r = 0; r < 4; r++){
      float rm = srow[l4 * 4 + i * 16 + r];
      float s = 0.f;
      #pragma unroll
      for (int j = 0; j < 4; j++){
        float e = expf(acc[i][j][r] - rm);
        acc[i][j][r] = e;
        s += e;
      }
      #pragma unroll
      for (int off = 1; off < 16; off <<= 1) s += __shfl_xor(s, off, 64);
      if (l15 == 0) sred[w * 128 + l4 * 4 + i * 16 + r] = s;
    }
  __syncthreads();
  if (tid < 128){
    float s = 0.f;
    #pragma unroll
    for (int w2 = 0; w2 < 8; w2++) s += sred[w2 * 128 + tid];
    srow[tid] = 1.f / s;
  }
  __syncthreads();
  // coalesced attn store: 32-row LDS slabs (u16, pad 520) then 8B-chunk writes
  u16* Pz = P + (long)z * ((long)SS * SS);
  u16* pb = (u16*)(smem + 8192);
  const int PST = 520;
  #pragma unroll
  for (int ii = 0; ii < 4; ii++){
    __syncthreads();
    #pragma unroll
    for (int s2 = 0; s2 < 2; s2++){
      int i = ii * 2 + s2;
      #pragma unroll
      for (int r = 0; r < 4; r++){
        int rl = l4 * 4 + i * 16 + r;
        float inv = srow[rl];
        #pragma unroll
        for (int j = 0; j < 4; j++)
          pb[(s2 * 16 + l4 * 4 + r) * PST + wn + j * 16 + l15] = f2bf(acc[i][j][r] * inv);
      }
    }
    __syncthreads();
    #pragma unroll
    for (int p = 0; p < 8; p++){
      int chunk = tid + p * 512;
      int lr = chunk >> 7, c8 = chunk & 127;
      ushort4 v = *(ushort4*)&pb[lr * PST + c8 * 4];
      *(ushort4*)&Pz[(long)(m0 + ii * 32 + lr) * SS + c8 * 4] = v;
    }
  }
}

// LayerNorm f32 -> bf16 (+ optional f32), one wave per row of 512
template<bool WF32>
__global__ __launch_bounds__(256) void k_ln(
    const float* __restrict__ X, const void* __restrict__ g, const void* __restrict__ be,
    u16* __restrict__ Yb, float* __restrict__ Yf, const int* __restrict__ dflag)
{
  int isbf = dflag[0];
  int row = blockIdx.x * 4 + (threadIdx.x >> 6);
  int lane = threadIdx.x & 63;
  const float* p = X + (long)row * DD + lane * 8;
  float4 v0 = *(const float4*)p;
  float4 v1 = *(const float4*)(p + 4);
  float v[8] = {v0.x, v0.y, v0.z, v0.w, v1.x, v1.y, v1.z, v1.w};
  float s = 0.f;
  #pragma unroll
  for (int i = 0; i < 8; i++) s += v[i];
  s = wave_redsum(s);
  float mu = s * (1.f / DD);
  float d_[8], sq = 0.f;
  #pragma unroll
  for (int i = 0; i < 8; i++){ d_[i] = v[i] - mu; sq += d_[i] * d_[i]; }
  sq = wave_redsum(sq);
  float rs = 1.f / sqrtf(sq * (1.f / DD) + 1e-5f);
  #pragma unroll
  for (int i = 0; i < 8; i++){
    int dd = lane * 8 + i;
    float y = ldf(g, dd, isbf) * d_[i] * rs + ldf(be, dd, isbf);
    Yb[(long)row * DD + dd] = f2bf(y);
    if (WF32) Yf[(long)row * DD + dd] = y;
  }
}

extern "C" void kernel_launch(void* const* d_in, const int* in_sizes, int n_in,
                              void* d_out, int out_size, void* d_ws, size_t ws_size,
                              hipStream_t stream)
{
  const int* tokens = (const int*)d_in[0];
  const void* emb = d_in[1];
  const void* pe  = d_in[2];
  const void* Wq  = d_in[3];
  const void* bq  = d_in[4];
  const void* Wk  = d_in[5];
  const void* bk  = d_in[6];
  const void* Wv  = d_in[7];
  const void* bv  = d_in[8];
  const void* Wo  = d_in[9];
  const void* bo  = d_in[10];
  const void* g1  = d_in[11];
  const void* be1 = d_in[12];
  const void* W1  = d_in[13];
  const void* b1  = d_in[14];
  const void* W2  = d_in[15];
  const void* b2  = d_in[16];
  const void* g2  = d_in[17];
  const void* be2 = d_in[18];
  const void* Wf  = d_in[19];
  const void* bfb = d_in[20];
  float* out = (float*)d_out;   // reference output dtype = float32
  char* ws = (char*)d_ws;
  char* DO = (char*)d_out;

  const size_t MB = 1ull << 20;
  // ---- d_ws (39.3 MiB; <=69 MiB evidenced safe) ----
  int* dflag = (int*)ws;
  u16* x2b   = (u16*)(ws + 1 * MB);        // [1,5)
  u16* WfT   = (u16*)(ws + 8 * MB);        // [8,39.25)  bf16 [32000][512]

  // ---- d_out as scratch (380 of 500 MiB; all dead before logits) ----
  float* x    = (float*)(DO + 0 * MB);     // [0,8)
  u16*   xm2  = (u16*)(DO + 8 * MB);       // [8,16)    [4096][1024] = [xh|xl]
  u16*   Wq2  = (u16*)(DO + 16 * MB);      // [16,24)   [8][512][1024] = [wh|wl]
  u16*   Wk2  = (u16*)(DO + 24 * MB);      // [24,32)
  u16*   WvT  = (u16*)(DO + 32 * MB);      // [32,36)   [8][512][512]
  u16*   WoT  = (u16*)(DO + 36 * MB);      // [36,40)   [512][4096]
  u16*   W1T  = (u16*)(DO + 40 * MB);      // [40,42)   [2048][512]
  u16*   W2T  = (u16*)(DO + 42 * MB);      // [42,44)   [512][2048]
  u16*   q2   = (u16*)(DO + 48 * MB);      // [48,112)  [8][4096][1024] = [qh|ql]
  u16*   k2   = (u16*)(DO + 112 * MB);     // [112,176) [8][4096][1024] = [kh|kl]
  u16*   attn = (u16*)(DO + 240 * MB);     // [240,272) [64][512][512] bf16
  u16*   vT   = (u16*)(DO + 272 * MB);     // [272,304) [64][512 d][512 s]
  u16*   cat  = (u16*)(DO + 304 * MB);     // [304,336) [4096][4096]
  float* proj = (float*)(DO + 336 * MB);   // [336,344)
  float* x1f  = (float*)(DO + 344 * MB);   // [344,352)
  u16*   x1b  = (u16*)(DO + 352 * MB);     // [352,356)
  u16*   ff1  = (u16*)(DO + 356 * MB);     // [356,372) [4096][2048]
  float* ff2  = (float*)(DO + 372 * MB);   // [372,380)

  const float scale = 0.04419417382415922f;  // 1/sqrt(512)
  const long HSL = 262144;                   // 512*512
  const long QSL = 524288;                   // 512*1024 (2-band q/k rows per z)

  k_dflag<<<1, 1, 0, stream>>>(pe, dflag);
  k_embed<<<dim3(4096), 256, 0, stream>>>(tokens, emb, pe, x, xm2, dflag);

  // one-time weight prep (2 launches)
  k_wsplitT<<<dim3(16, 16, 16), 256, 0, stream>>>(Wq, Wk, Wq2, Wk2, dflag);
  k_transAll<<<dim3(22144), 256, 0, stream>>>(
      Wv, Wo, W1, W2, Wf, WvT, WoT, W1T, W2T, WfT, dflag);

  // merged q/k/v projections: 8-phase counted-vmcnt schedule (r21-proven)
  k_proj8<<<dim3(2, 16, 24), 512, 0, stream>>>(
      xm2, Wq2, Wk2, WvT, q2, k2, vT, bq, bk, bv, dflag);

  // fused scores+softmax -> attn bf16 (no sc buffer); z = h*8+b
  k_fsm<1, 2><<<dim3(4, 1, 64), 512, 0, stream>>>(
      q2, QSL, 1024, k2, QSL, 1024, attn, KC, scale, dflag);

  // o = attn @ v -> cat (torch.cat head order)
  k_mfma2<EP_CAT, false, 0, 0><<<dim3(2, 2, 64), 512, 0, stream>>>(
      attn, HSL, SS, vT, HSL, 512, cat, nullptr, nullptr, SS, 0, 0.f, dflag);

  // proj = cat @ Wo + bo + x (128^2 kernel)
  k_mfma<EP_F32RES, false><<<dim3(4, 32, 1), 256, 0, stream>>>(
      cat, 0, HD, WoT, 0, proj, bo, x, HD, DD, 0.f, dflag);
  k_ln<true><<<dim3(1024), 256, 0, stream>>>(proj, g1, be1, x1b, x1f, dflag);

  // ff = relu(x1 @ W1 + b1) @ W2 + b2 + x1
  k_mfma<EP_RELU, false><<<dim3(16, 32, 1), 256, 0, stream>>>(
      x1b, 0, DD, W1T, 0, ff1, b1, nullptr, DD, NFF, 0.f, dflag);
  k_mfma<EP_F32RES, false><<<dim3(4, 32, 1), 256, 0, stream>>>(
      ff1, 0, NFF, W2T, 0, ff2, b2, x1f, NFF, DD, 0.f, dflag);
  k_ln<false><<<dim3(1024), 256, 0, stream>>>(ff2, g2, be2, x2b, nullptr, dflag);

  // logits = x2 @ Wf + bf -> f32 out: 8-phase counted-vmcnt kernel (NT = 512/64)
  k_out8<<<dim3(16, 125, 1), 512, 0, stream>>>(x2b, WfT, out, bfb, 8, dflag);
}

// Round 23
// 924.257 us; speedup vs baseline: 1.0847x; 1.0057x over previous
//
#include <hip/hip_runtime.h>

typedef unsigned short u16;
typedef unsigned int u32;
typedef short s16x8 __attribute__((ext_vector_type(8)));
typedef __bf16 bf16x8 __attribute__((ext_vector_type(8)));
typedef float f32x4 __attribute__((ext_vector_type(4)));

#define DEVI static __device__ __forceinline__

#define SS 512
#define DD 512
#define NFF 2048
#define VV 32000
#define MTOT 4096
#define HD 4096
#define KC 1536   // virtual split-concat K (2-band storage + read-time remap)

DEVI float bf2f(u16 h){ return __uint_as_float(((u32)h) << 16); }
DEVI u16 f2bf(float f){
  u32 u = __float_as_uint(f);
  return (u16)((u + 0x7FFFu + ((u >> 16) & 1u)) >> 16);
}
DEVI float ldf(const void* p, long i, int isbf){
  return isbf ? bf2f(((const u16*)p)[i]) : ((const float*)p)[i];
}

DEVI f32x4 mfma16(s16x8 a, s16x8 b, f32x4 c){
  return __builtin_amdgcn_mfma_f32_16x16x32_bf16(
      __builtin_bit_cast(bf16x8, a), __builtin_bit_cast(bf16x8, b), c, 0, 0, 0);
}

// direct global->LDS 16B copy; dst is wave-uniform base + lane*16, src per-lane
typedef const __attribute__((address_space(1))) unsigned int* gup;
typedef __attribute__((address_space(3))) unsigned int* lup;
DEVI void gload16(const void* g, void* l){
  __builtin_amdgcn_global_load_lds((gup)g, (lup)l, 16, 0, 0);
}

DEVI float wave_redsum(float v){
  #pragma unroll
  for (int off = 32; off > 0; off >>= 1) v += __shfl_xor(v, off, 64);
  return v;
}

// pe row0 = [sin0=0, cos0=1, ...]: first u32 word = 0x3F800000 if bf16, 0x00000000 if f32
__global__ void k_dflag(const void* pe, int* flag){
  flag[0] = (*(const u32*)pe == 0x3F800000u) ? 1 : 0;
}

// embed + residual + masked 2-band split: xm2[m][0:512]=hi, [512:1024]=lo
__global__ __launch_bounds__(256) void k_embed(
    const int* __restrict__ tok, const void* __restrict__ emb, const void* __restrict__ pe,
    float* __restrict__ x, u16* __restrict__ xm2, const int* __restrict__ dflag)
{
  int isbf = dflag[0];
  int blk = blockIdx.x;
  int s = blk & (SS - 1);
  int t = tok[blk];
  long rb = (long)blk * 1024;
  for (int d = threadIdx.x; d < DD; d += 256){
    float e = ldf(emb, (long)t * DD + d, isbf) + ldf(pe, (long)s * DD + d, isbf);
    x[(long)blk * DD + d] = e;
    float m = (d <= s) ? e : 0.f;           // triu(ones(S,D),k=1) zeroes d > s
    u16 hi = f2bf(m);
    u16 lo = f2bf(m - bf2f(hi));
    xm2[rb + d] = hi;
    xm2[rb + 512 + d] = lo;
  }
}

// split-transpose for Wq AND Wk (zz<8: Wq slice zz; else Wk slice zz-8):
// in W[z][512 d][512 e] -> out[z][512 e][1024]: band0=hi, band1=lo
__global__ __launch_bounds__(256) void k_wsplitT(
    const void* __restrict__ Wq, const void* __restrict__ Wk,
    u16* __restrict__ Wq2, u16* __restrict__ Wk2, const int* __restrict__ dflag)
{
  int isbf = dflag[0];
  int zz = blockIdx.z;
  const void* in = (zz < 8) ? Wq : Wk;
  u16* out = (zz < 8) ? Wq2 : Wk2;
  int z = zz & 7;
  long zin = (long)z * DD * DD;
  long zout = (long)z * DD * 1024;
  __shared__ float t[32][33];
  int e0 = blockIdx.x * 32, d0 = blockIdx.y * 32;
  int tx = threadIdx.x & 31, ty = threadIdx.x >> 5;
  #pragma unroll
  for (int i = 0; i < 4; i++){
    int d = ty + i * 8;
    t[d][tx] = ldf(in, zin + (long)(d0 + d) * DD + e0 + tx, isbf);
  }
  __syncthreads();
  #pragma unroll
  for (int i = 0; i < 4; i++){
    int e = ty + i * 8;
    float v = t[tx][e];
    u16 hi = f2bf(v);
    u16 lo = f2bf(v - bf2f(hi));
    long ob = zout + (long)(e0 + e) * 1024 + d0 + tx;
    out[ob] = hi;
    out[ob + 512] = lo;
  }
}

// all 5 plain transposes (f32/bf16 -> bf16) in one flat-grid kernel.
__global__ __launch_bounds__(256) void k_transAll(
    const void* __restrict__ Wv, const void* __restrict__ Wo,
    const void* __restrict__ W1, const void* __restrict__ W2,
    const void* __restrict__ Wf,
    u16* __restrict__ WvT, u16* __restrict__ WoT, u16* __restrict__ W1T,
    u16* __restrict__ W2T, u16* __restrict__ WfT, const int* __restrict__ dflag)
{
  int isbf = dflag[0];
  int f = blockIdx.x;
  const void* in; u16* out; int R, C, gx, loc;
  if (f < 2048)      { in = Wv; out = WvT; R = 512;  C = 512;   gx = 16;   loc = f; }
  else if (f < 4096) { in = Wo; out = WoT; R = 4096; C = 512;   gx = 16;   loc = f - 2048; }
  else if (f < 5120) { in = W1; out = W1T; R = 512;  C = 2048;  gx = 64;   loc = f - 4096; }
  else if (f < 6144) { in = W2; out = W2T; R = 2048; C = 512;   gx = 16;   loc = f - 5120; }
  else               { in = Wf; out = WfT; R = 512;  C = 32000; gx = 1000; loc = f - 6144; }
  int bx = loc % gx;
  int rest = loc / gx;
  int gy = R >> 5;
  int by = rest % gy, z = rest / gy;
  long zo = (long)z * R * C;
  __shared__ float t[32][33];
  int c0 = bx * 32, r0 = by * 32;
  int tx = threadIdx.x & 31, ty = threadIdx.x >> 5;
  #pragma unroll
  for (int i = 0; i < 4; i++){
    int r = ty + i * 8;
    t[r][tx] = ldf(in, zo + (long)(r0 + r) * C + c0 + tx, isbf);
  }
  __syncthreads();
  #pragma unroll
  for (int i = 0; i < 4; i++){
    int c = ty + i * 8;
    out[zo + (long)(c0 + c) * R + r0 + tx] = f2bf(t[tx][c]);
  }
}

enum { EP_F32RES = 5, EP_RELU = 6 };

// ---------- 128x128 tile, 4 waves (small-N GEMMs: Wo, FF1, FF2) ----------
template<int MODE, bool GSWAP>
__global__ __launch_bounds__(256) void k_mfma(
    const u16* __restrict__ A, long sA, int lda,
    const u16* __restrict__ Bt, long sB,
    void* __restrict__ Cv,
    const void* __restrict__ bias,
    const float* __restrict__ res,
    int K, int ldc, float scale,
    const int* __restrict__ dflag)
{
  int isbf = dflag[0];
  int z = blockIdx.z;
  const u16* Ab = A + (long)z * sA;
  const u16* Bb = Bt + (long)z * sB;
  __shared__ __align__(16) u16 As[2][4][128][8];
  __shared__ __align__(16) u16 Bs[2][4][128][8];
  int m0 = (GSWAP ? blockIdx.x : blockIdx.y) * 128;
  int n0 = (GSWAP ? blockIdx.y : blockIdx.x) * 128;
  int tid = threadIdx.x;
  int lane = tid & 63, w = tid >> 6;
  int wr = (w >> 1) * 64, wc = (w & 1) * 64;
  int l15 = lane & 15, l4 = lane >> 4;
  int s0 = w * 64 + lane;
  int ar0 = s0 & 127, ak0 = s0 >> 7;
  int ak1 = ak0 + 2;
  f32x4 zero = {0.f, 0.f, 0.f, 0.f};
  f32x4 acc[4][4];
  #pragma unroll
  for (int i = 0; i < 4; i++)
    #pragma unroll
    for (int j = 0; j < 4; j++) acc[i][j] = zero;

  const long arow0 = (long)(m0 + ar0) * lda;
  const long brow0 = (long)(n0 + ar0) * K;

  #define STAGE(buf, k0) do{ \
    u16* AsF = &As[buf][0][0][0]; \
    u16* BsF = &Bs[buf][0][0][0]; \
    gload16(Ab + arow0 + (k0) + ak0 * 8, AsF + (long)(w * 64) * 8); \
    gload16(Ab + arow0 + (k0) + ak1 * 8, AsF + (long)(256 + w * 64) * 8); \
    gload16(Bb + brow0 + (k0) + ak0 * 8, BsF + (long)(w * 64) * 8); \
    gload16(Bb + brow0 + (k0) + ak1 * 8, BsF + (long)(256 + w * 64) * 8); \
  }while(0)

  #define COMPUTE(buf) do{ \
    s16x8 af[4], bfr[4]; \
    _Pragma("unroll") \
    for (int i = 0; i < 4; i++) af[i] = *(const s16x8*)&As[buf][l4][wr + i * 16 + l15][0]; \
    _Pragma("unroll") \
    for (int j = 0; j < 4; j++) bfr[j] = *(const s16x8*)&Bs[buf][l4][wc + j * 16 + l15][0]; \
    _Pragma("unroll") \
    for (int i = 0; i < 4; i++) \
      _Pragma("unroll") \
      for (int j = 0; j < 4; j++) \
        acc[i][j] = mfma16(af[i], bfr[j], acc[i][j]); \
  }while(0)

  STAGE(0, 0);
  __syncthreads();
  for (int k0 = 0; k0 < K; k0 += 64){
    STAGE(1, k0 + 32);
    COMPUTE(0);
    __syncthreads();
    if (k0 + 64 < K) STAGE(0, k0 + 64);
    COMPUTE(1);
    __syncthreads();
  }
  #undef STAGE
  #undef COMPUTE

  int mbase = m0 + wr + l4 * 4;
  int nbase = n0 + wc + l15;
  if constexpr (MODE == EP_F32RES){
    float* C = (float*)Cv;
    #pragma unroll
    for (int j = 0; j < 4; j++){
      int n = nbase + j * 16;
      float badd = ldf(bias, n, isbf);
      #pragma unroll
      for (int i = 0; i < 4; i++)
        #pragma unroll
        for (int r = 0; r < 4; r++){
          long a = (long)(mbase + i * 16 + r) * ldc + n;
          C[a] = acc[i][j][r] + badd + res[a];
        }
    }
  } else if constexpr (MODE == EP_RELU){
    u16* C = (u16*)Cv;
    #pragma unroll
    for (int j = 0; j < 4; j++){
      int n = nbase + j * 16;
      float badd = ldf(bias, n, isbf);
      #pragma unroll
      for (int i = 0; i < 4; i++)
        #pragma unroll
        for (int r = 0; r < 4; r++)
          C[(long)(mbase + i * 16 + r) * ldc + n] = f2bf(fmaxf(acc[i][j][r] + badd, 0.f));
    }
  }
}

// ---------- 8-phase counted-vmcnt 256x256 GEMM for logits (K=NT*64) ----------
// (r21-proven) BK=64 K-tiles, 2x64KB LDS buffers, half-tile staging, 4 MFMA
// phases/tile; one counted s_waitcnt vmcnt(2) per tile; raw s_barrier fences.
__global__ __launch_bounds__(512, 2) void k_out8(
    const u16* __restrict__ A, const u16* __restrict__ Bt,
    float* __restrict__ O, const void* __restrict__ bias,
    int NT, const int* __restrict__ dflag)
{
  int isbf = dflag[0];
  __shared__ __align__(16) char smem[131072];   // 2 bufs x (A 32KB | B 32KB)
  u16* SM = (u16*)smem;
  // bijective XCD remap (nwg = 16*125 = 2000, %8 == 0)
  int f = blockIdx.x + gridDim.x * blockIdx.y;
  int qx = (gridDim.x * gridDim.y) >> 3;
  int L = (f & 7) * qx + (f >> 3);
  int m0 = (L % gridDim.x) * 256;
  int n0 = (L / gridDim.x) * 256;
  int tid = threadIdx.x;
  int lane = tid & 63, w = tid >> 6;
  int wm = (w >> 2) * 128, wn = (w & 3) * 64;
  int l15 = lane & 15, l4 = lane >> 4;
  f32x4 zero = {0.f, 0.f, 0.f, 0.f};
  f32x4 acc[8][4];
  #pragma unroll
  for (int i = 0; i < 8; i++)
    #pragma unroll
    for (int j = 0; j < 4; j++) acc[i][j] = zero;

  int rr = tid & 127, kc1 = tid >> 7;   // staging: row-in-half, k-chunk 0..3

  #define STAGEU(c, Tt, u) do{ \
    const u16* gb = (((u) & 1) == 0) ? A : Bt; \
    int base0 = (((u) & 1) == 0) ? m0 : n0; \
    int r2 = ((u) >> 1) * 128 + rr; \
    long gsrc = (long)(base0 + r2) * 512 + (Tt) * 64; \
    u16* lb = SM + (c) * 32768 + ((((u) & 1) == 0) ? 0 : 16384); \
    gload16(gb + gsrc + kc1 * 8,       lb + (kc1 * 256 + r2) * 8); \
    gload16(gb + gsrc + (kc1 + 4) * 8, lb + ((kc1 + 4) * 256 + r2) * 8); \
  }while(0)

  STAGEU(0, 0, 0); STAGEU(0, 0, 1); STAGEU(0, 0, 2); STAGEU(0, 0, 3);

  int cur = 0;
  for (int T = 0; T < NT; T++){
    int nxt = cur ^ 1;
    int more = (T + 1 < NT);
    s16x8 af[8];
    #pragma unroll
    for (int q = 0; q < 4; q++){
      if (more) STAGEU(nxt, T + 1, q);
      if (q == 0){
        if (more) asm volatile("s_waitcnt vmcnt(2)" ::: "memory");
        else      asm volatile("s_waitcnt vmcnt(0)" ::: "memory");
      }
      __builtin_amdgcn_s_barrier();
      __builtin_amdgcn_sched_barrier(0);
      int ks = q >> 1, jh = q & 1;
      if (jh == 0){
        #pragma unroll
        for (int i = 0; i < 8; i++)
          af[i] = *(const s16x8*)(SM + cur * 32768 +
                    ((ks * 4 + l4) * 256 + (wm + i * 16 + l15)) * 8);
      }
      s16x8 b0 = *(const s16x8*)(SM + cur * 32768 + 16384 +
                    ((ks * 4 + l4) * 256 + (wn + (jh * 2) * 16 + l15)) * 8);
      s16x8 b1 = *(const s16x8*)(SM + cur * 32768 + 16384 +
                    ((ks * 4 + l4) * 256 + (wn + (jh * 2 + 1) * 16 + l15)) * 8);
      __builtin_amdgcn_s_setprio(1);
      #pragma unroll
      for (int i = 0; i < 8; i++){
        acc[i][jh * 2]     = mfma16(af[i], b0, acc[i][jh * 2]);
        acc[i][jh * 2 + 1] = mfma16(af[i], b1, acc[i][jh * 2 + 1]);
      }
      __builtin_amdgcn_s_setprio(0);
    }
    __builtin_amdgcn_s_barrier();
    __builtin_amdgcn_sched_barrier(0);
    cur = nxt;
  }
  #undef STAGEU

  // coalesced epilogue: LDS-transpose slabs + NT f32x4 stores
  float* ldsT = (float*)smem;
  const int RST = 260;
  int hs16 = (w >> 2) * 16;
  float badd[4];
  #pragma unroll
  for (int j = 0; j < 4; j++) badd[j] = ldf(bias, n0 + wn + j * 16 + l15, isbf);
  #pragma unroll
  for (int i = 0; i < 8; i++){
    __syncthreads();
    #pragma unroll
    for (int j = 0; j < 4; j++){
      int col = wn + j * 16 + l15;
      #pragma unroll
      for (int r = 0; r < 4; r++)
        ldsT[(hs16 + l4 * 4 + r) * RST + col] = acc[i][j][r] + badd[j];
    }
    __syncthreads();
    #pragma unroll
    for (int p = 0; p < 4; p++){
      int chunk = tid + p * 512;
      int lr = chunk >> 6, c4 = chunk & 63;
      int gm = m0 + (lr >> 4) * 128 + i * 16 + (lr & 15);
      f32x4 v = *(f32x4*)&ldsT[lr * RST + c4 * 4];
      __builtin_nontemporal_store(v, (f32x4*)&O[(long)gm * VV + n0 + c4 * 4]);
    }
  }
}

// ---------- 8-phase merged q/k/v projection (r21/r22-proven schedule) ----------
__global__ __launch_bounds__(512, 2) void k_proj8(
    const u16* __restrict__ xm2,
    const u16* __restrict__ Wq2, const u16* __restrict__ Wk2, const u16* __restrict__ WvT,
    u16* __restrict__ q2, u16* __restrict__ k2, u16* __restrict__ vT,
    const void* __restrict__ bq, const void* __restrict__ bk, const void* __restrict__ bv,
    const int* __restrict__ dflag)
{
  int isbf = dflag[0];
  int zz = blockIdx.z;
  int z, ldb, NT, mode;
  const u16* Bb; const void* bias; u16* C;
  if (zz < 16){
    mode = 0; z = zz & 7;
    Bb = (zz < 8 ? Wq2 : Wk2) + (long)z * 524288;
    ldb = 1024; NT = 24;
    bias = (zz < 8) ? bq : bk;
    C = (zz < 8) ? q2 : k2;
  } else {
    mode = 1; z = zz - 16;
    Bb = WvT + (long)z * 262144;
    ldb = 512; NT = 8;
    bias = bv;
    C = vT;
  }
  const u16* Ab = xm2;
  __shared__ __align__(16) char smem[131072];
  u16* SM = (u16*)smem;
  int m0 = blockIdx.y * 256;
  int n0 = blockIdx.x * 256;
  int tid = threadIdx.x;
  int lane = tid & 63, w = tid >> 6;
  int wm = (w >> 2) * 128, wn = (w & 3) * 64;
  int l15 = lane & 15, l4 = lane >> 4;
  f32x4 zero = {0.f, 0.f, 0.f, 0.f};
  f32x4 acc[8][4];
  #pragma unroll
  for (int i = 0; i < 8; i++)
    #pragma unroll
    for (int j = 0; j < 4; j++) acc[i][j] = zero;

  int rr = tid & 127, kc1 = tid >> 7;

  #define KA8(Tt) (mode == 0 ? (((Tt) * 64 < 512) ? (Tt) * 64 : (Tt) * 64 - 512) : (Tt) * 64)
  #define KB8(Tt) (mode == 0 ? (((Tt) * 64 < 1024) ? (Tt) * 64 : (Tt) * 64 - 1024) : (Tt) * 64)

  #define STAGEU(c, Tt, u) do{ \
    const u16* gb = (((u) & 1) == 0) ? Ab : Bb; \
    long rs = (((u) & 1) == 0) ? 1024 : (long)ldb; \
    int base0 = (((u) & 1) == 0) ? m0 : n0; \
    int tk = (((u) & 1) == 0) ? KA8(Tt) : KB8(Tt); \
    int r2 = ((u) >> 1) * 128 + rr; \
    long gsrc = (long)(base0 + r2) * rs + tk; \
    u16* lb = SM + (c) * 32768 + ((((u) & 1) == 0) ? 0 : 16384); \
    gload16(gb + gsrc + kc1 * 8,       lb + (kc1 * 256 + r2) * 8); \
    gload16(gb + gsrc + (kc1 + 4) * 8, lb + ((kc1 + 4) * 256 + r2) * 8); \
  }while(0)

  STAGEU(0, 0, 0); STAGEU(0, 0, 1); STAGEU(0, 0, 2); STAGEU(0, 0, 3);

  int cur = 0;
  for (int T = 0; T < NT; T++){
    int nxt = cur ^ 1;
    int more = (T + 1 < NT);
    s16x8 af[8];
    #pragma unroll
    for (int q = 0; q < 4; q++){
      if (more) STAGEU(nxt, T + 1, q);
      if (q == 0){
        if (more) asm volatile("s_waitcnt vmcnt(2)" ::: "memory");
        else      asm volatile("s_waitcnt vmcnt(0)" ::: "memory");
      }
      __builtin_amdgcn_s_barrier();
      __builtin_amdgcn_sched_barrier(0);
      int ks = q >> 1, jh = q & 1;
      if (jh == 0){
        #pragma unroll
        for (int i = 0; i < 8; i++)
          af[i] = *(const s16x8*)(SM + cur * 32768 +
                    ((ks * 4 + l4) * 256 + (wm + i * 16 + l15)) * 8);
      }
      s16x8 b0 = *(const s16x8*)(SM + cur * 32768 + 16384 +
                    ((ks * 4 + l4) * 256 + (wn + (jh * 2) * 16 + l15)) * 8);
      s16x8 b1 = *(const s16x8*)(SM + cur * 32768 + 16384 +
                    ((ks * 4 + l4) * 256 + (wn + (jh * 2 + 1) * 16 + l15)) * 8);
      __builtin_amdgcn_s_setprio(1);
      #pragma unroll
      for (int i = 0; i < 8; i++){
        acc[i][jh * 2]     = mfma16(af[i], b0, acc[i][jh * 2]);
        acc[i][jh * 2 + 1] = mfma16(af[i], b1, acc[i][jh * 2 + 1]);
      }
      __builtin_amdgcn_s_setprio(0);
    }
    __builtin_amdgcn_s_barrier();
    __builtin_amdgcn_sched_barrier(0);
    cur = nxt;
  }
  #undef STAGEU
  #undef KA8
  #undef KB8

  int mbase = m0 + wm + l4 * 4;
  int nbase = n0 + wn + l15;
  if (mode == 0){
    // 2-band out: C[row][n]=hi, C[row][512+n]=lo, row stride 1024
    u16* Cz = C + (long)z * ((long)MTOT * 1024);
    #pragma unroll
    for (int j = 0; j < 4; j++){
      int n = nbase + j * 16;
      float badd = ldf(bias, (long)z * DD + n, isbf);
      #pragma unroll
      for (int i = 0; i < 8; i++)
        #pragma unroll
        for (int r = 0; r < 4; r++){
          float qv = acc[i][j][r] + badd;
          u16 hi = f2bf(qv);
          u16 lo = f2bf(qv - bf2f(hi));
          long rb = (long)(mbase + i * 16 + r) * 1024;
          Cz[rb + n] = hi;
          Cz[rb + 512 + n] = lo;
        }
    }
  } else {
    // vT[(z*8 + b)][d = n][s]; 4 acc regs = 4 consecutive s
    #pragma unroll
    for (int i = 0; i < 8; i++){
      int mrow = mbase + i * 16;
      int b = mrow >> 9, s = mrow & (SS - 1);
      #pragma unroll
      for (int j = 0; j < 4; j++){
        int n = nbase + j * 16;
        float badd = ldf(bias, (long)z * DD + n, isbf);
        ushort4 pk;
        pk.x = f2bf(acc[i][j][0] + badd); pk.y = f2bf(acc[i][j][1] + badd);
        pk.z = f2bf(acc[i][j][2] + badd); pk.w = f2bf(acc[i][j][3] + badd);
        *(ushort4*)&C[((long)(z * 8 + b) * DD + n) * SS + s] = pk;
      }
    }
  }
}

// ---------- 8-phase attn@v -> cat (k_proj8 mode-1 geometry; EP_CAT epilogue) ----------
// A = attn[z][512][512], B = vT[z][512][512], K = 512 (NT=8, identity maps); z = h*8+b.
__global__ __launch_bounds__(512, 2) void k_cat8(
    const u16* __restrict__ attn, const u16* __restrict__ vT,
    u16* __restrict__ cat, const int* __restrict__ dflag)
{
  int z = blockIdx.z;
  const u16* Ab = attn + (long)z * 262144;
  const u16* Bb = vT + (long)z * 262144;
  __shared__ __align__(16) char smem[131072];
  u16* SM = (u16*)smem;
  int m0 = blockIdx.y * 256;
  int n0 = blockIdx.x * 256;
  int tid = threadIdx.x;
  int lane = tid & 63, w = tid >> 6;
  int wm = (w >> 2) * 128, wn = (w & 3) * 64;
  int l15 = lane & 15, l4 = lane >> 4;
  f32x4 zero = {0.f, 0.f, 0.f, 0.f};
  f32x4 acc[8][4];
  #pragma unroll
  for (int i = 0; i < 8; i++)
    #pragma unroll
    for (int j = 0; j < 4; j++) acc[i][j] = zero;

  int rr = tid & 127, kc1 = tid >> 7;

  #define STAGEU(c, Tt, u) do{ \
    const u16* gb = (((u) & 1) == 0) ? Ab : Bb; \
    int base0 = (((u) & 1) == 0) ? m0 : n0; \
    int r2 = ((u) >> 1) * 128 + rr; \
    long gsrc = (long)(base0 + r2) * 512 + (Tt) * 64; \
    u16* lb = SM + (c) * 32768 + ((((u) & 1) == 0) ? 0 : 16384); \
    gload16(gb + gsrc + kc1 * 8,       lb + (kc1 * 256 + r2) * 8); \
    gload16(gb + gsrc + (kc1 + 4) * 8, lb + ((kc1 + 4) * 256 + r2) * 8); \
  }while(0)

  STAGEU(0, 0, 0); STAGEU(0, 0, 1); STAGEU(0, 0, 2); STAGEU(0, 0, 3);

  int cur = 0;
  for (int T = 0; T < 8; T++){
    int nxt = cur ^ 1;
    int more = (T + 1 < 8);
    s16x8 af[8];
    #pragma unroll
    for (int q = 0; q < 4; q++){
      if (more) STAGEU(nxt, T + 1, q);
      if (q == 0){
        if (more) asm volatile("s_waitcnt vmcnt(2)" ::: "memory");
        else      asm volatile("s_waitcnt vmcnt(0)" ::: "memory");
      }
      __builtin_amdgcn_s_barrier();
      __builtin_amdgcn_sched_barrier(0);
      int ks = q >> 1, jh = q & 1;
      if (jh == 0){
        #pragma unroll
        for (int i = 0; i < 8; i++)
          af[i] = *(const s16x8*)(SM + cur * 32768 +
                    ((ks * 4 + l4) * 256 + (wm + i * 16 + l15)) * 8);
      }
      s16x8 b0 = *(const s16x8*)(SM + cur * 32768 + 16384 +
                    ((ks * 4 + l4) * 256 + (wn + (jh * 2) * 16 + l15)) * 8);
      s16x8 b1 = *(const s16x8*)(SM + cur * 32768 + 16384 +
                    ((ks * 4 + l4) * 256 + (wn + (jh * 2 + 1) * 16 + l15)) * 8);
      __builtin_amdgcn_s_setprio(1);
      #pragma unroll
      for (int i = 0; i < 8; i++){
        acc[i][jh * 2]     = mfma16(af[i], b0, acc[i][jh * 2]);
        acc[i][jh * 2 + 1] = mfma16(af[i], b1, acc[i][jh * 2 + 1]);
      }
      __builtin_amdgcn_s_setprio(0);
    }
    __builtin_amdgcn_s_barrier();
    __builtin_amdgcn_sched_barrier(0);
    cur = nxt;
  }
  #undef STAGEU

  // cat[(b*S + s)][h*D + n]; z = h*8+b  (verbatim r22 EP_CAT epilogue)
  int mbase = m0 + wm + l4 * 4;
  int nbase = n0 + wn + l15;
  int h = z >> 3, b = z & 7;
  #pragma unroll
  for (int i = 0; i < 8; i++){
    int s = mbase + i * 16;
    #pragma unroll
    for (int j = 0; j < 4; j++){
      int n = nbase + j * 16;
      #pragma unroll
      for (int r = 0; r < 4; r++)
        cat[((long)b * SS + s + r) * HD + (long)h * DD + n] = f2bf(acc[i][j][r]);
    }
  }
}

// ---------- fused scores+softmax: 128 q-rows x full 512 k-cols per block ----------
template<int AMAP, int BMAP>
__global__ __launch_bounds__(512, 2) void k_fsm(
    const u16* __restrict__ A, long sA, int lda,
    const u16* __restrict__ Bt, long sB, int ldb,
    u16* __restrict__ P, int K, float scale,
    const int* __restrict__ dflag)
{
  int z = blockIdx.z;
  const u16* Ab = A + (long)z * sA;
  const u16* Bb = Bt + (long)z * sB;
  __shared__ __align__(16) char smem[81920];
  u16* SA = (u16*)smem;
  u16* SB = (u16*)(smem + 16384);
  int m0 = blockIdx.x * 128;
  int tid = threadIdx.x;
  int lane = tid & 63, w = tid >> 6;
  int wn = w * 64;
  int l15 = lane & 15, l4 = lane >> 4;
  f32x4 zero = {0.f, 0.f, 0.f, 0.f};
  f32x4 acc[8][4];
  #pragma unroll
  for (int i = 0; i < 8; i++)
    #pragma unroll
    for (int j = 0; j < 4; j++) acc[i][j] = zero;

  const long arow0 = (long)(m0 + (tid & 127)) * lda;
  const int akc = tid >> 7;
  const long brow0 = (long)tid * ldb;

  #define STAGEF(buf, k0_) do{ \
    int ka = (AMAP == 1) ? ((k0_) < 512 ? (k0_) : (k0_) - 512) \
           : (AMAP == 2) ? ((k0_) < 1024 ? (k0_) : (k0_) - 1024) : (k0_); \
    int kb = (BMAP == 1) ? ((k0_) < 512 ? (k0_) : (k0_) - 512) \
           : (BMAP == 2) ? ((k0_) < 1024 ? (k0_) : (k0_) - 1024) : (k0_); \
    gload16(Ab + arow0 + ka + akc * 8, SA + ((buf) * 4096 + tid * 8)); \
    gload16(Bb + brow0 + kb + 0,  SB + ((buf) * 16384 + (0 * 512 + tid) * 8)); \
    gload16(Bb + brow0 + kb + 8,  SB + ((buf) * 16384 + (1 * 512 + tid) * 8)); \
    gload16(Bb + brow0 + kb + 16, SB + ((buf) * 16384 + (2 * 512 + tid) * 8)); \
    gload16(Bb + brow0 + kb + 24, SB + ((buf) * 16384 + (3 * 512 + tid) * 8)); \
  }while(0)

  #define COMPUTEF(buf) do{ \
    s16x8 bfr[4]; \
    _Pragma("unroll") \
    for (int j = 0; j < 4; j++) \
      bfr[j] = *(const s16x8*)(SB + ((buf) * 16384 + l4 * 4096 + (wn + j * 16 + l15) * 8)); \
    _Pragma("unroll") \
    for (int i = 0; i < 8; i++){ \
      s16x8 af = *(const s16x8*)(SA + ((buf) * 4096 + l4 * 1024 + (i * 16 + l15) * 8)); \
      _Pragma("unroll") \
      for (int j = 0; j < 4; j++) \
        acc[i][j] = mfma16(af, bfr[j], acc[i][j]); \
    } \
  }while(0)

  STAGEF(0, 0);
  __syncthreads();
  for (int k0 = 0; k0 < K; k0 += 64){
    STAGEF(1, k0 + 32);
    COMPUTEF(0);
    __syncthreads();
    if (k0 + 64 < K) STAGEF(0, k0 + 64);
    COMPUTEF(1);
    __syncthreads();
  }
  #undef STAGEF
  #undef COMPUTEF

  float* sred = (float*)smem;
  float* srow = (float*)(smem + 4096);

  #pragma unroll
  for (int i = 0; i < 8; i++)
    #pragma unroll
    for (int j = 0; j < 4; j++)
      acc[i][j] *= scale;

  #pragma unroll
  for (int i = 0; i < 8; i++)
    #pragma unroll
    for (int r = 0; r < 4; r++){
      float m = fmaxf(fmaxf(acc[i][0][r], acc[i][1][r]),
                      fmaxf(acc[i][2][r], acc[i][3][r]));
      #pragma unroll
      for (int off = 1; off < 16; off <<= 1) m = fmaxf(m, __shfl_xor(m, off, 64));
      if (l15 == 0) sred[w * 128 + l4 * 4 + i * 16 + r] = m;
    }
  __syncthreads();
  if (tid < 128){
    float m = sred[tid];
    #pragma unroll
    for (int w2 = 1; w2 < 8; w2++) m = fmaxf(m, sred[w2 * 128 + tid]);
    srow[tid] = m;
  }
  __syncthreads();
  #pragma unroll
  for (int i = 0; i < 8; i++)
    #pragma unroll
    for (int r = 0; r < 4; r++){
      float rm = srow[l4 * 4 + i * 16 + r];
      float s = 0.f;
      #pragma unroll
      for (int j = 0; j < 4; j++){
        float e = expf(acc[i][j][r] - rm);
        acc[i][j][r] = e;
        s += e;
      }
      #pragma unroll
      for (int off = 1; off < 16; off <<= 1) s += __shfl_xor(s, off, 64);
      if (l15 == 0) sred[w * 128 + l4 * 4 + i * 16 + r] = s;
    }
  __syncthreads();
  if (tid < 128){
    float s = 0.f;
    #pragma unroll
    for (int w2 = 0; w2 < 8; w2++) s += sred[w2 * 128 + tid];
    srow[tid] = 1.f / s;
  }
  __syncthreads();
  // coalesced attn store: 32-row LDS slabs (u16, pad 520) then 8B-chunk writes
  u16* Pz = P + (long)z * ((long)SS * SS);
  u16* pb = (u16*)(smem + 8192);
  const int PST = 520;
  #pragma unroll
  for (int ii = 0; ii < 4; ii++){
    __syncthreads();
    #pragma unroll
    for (int s2 = 0; s2 < 2; s2++){
      int i = ii * 2 + s2;
      #pragma unroll
      for (int r = 0; r < 4; r++){
        int rl = l4 * 4 + i * 16 + r;
        float inv = srow[rl];
        #pragma unroll
        for (int j = 0; j < 4; j++)
          pb[(s2 * 16 + l4 * 4 + r) * PST + wn + j * 16 + l15] = f2bf(acc[i][j][r] * inv);
      }
    }
    __syncthreads();
    #pragma unroll
    for (int p = 0; p < 8; p++){
      int chunk = tid + p * 512;
      int lr = chunk >> 7, c8 = chunk & 127;
      ushort4 v = *(ushort4*)&pb[lr * PST + c8 * 4];
      *(ushort4*)&Pz[(long)(m0 + ii * 32 + lr) * SS + c8 * 4] = v;
    }
  }
}

// LayerNorm f32 -> bf16 (+ optional f32), one wave per row of 512
template<bool WF32>
__global__ __launch_bounds__(256) void k_ln(
    const float* __restrict__ X, const void* __restrict__ g, const void* __restrict__ be,
    u16* __restrict__ Yb, float* __restrict__ Yf, const int* __restrict__ dflag)
{
  int isbf = dflag[0];
  int row = blockIdx.x * 4 + (threadIdx.x >> 6);
  int lane = threadIdx.x & 63;
  const float* p = X + (long)row * DD + lane * 8;
  float4 v0 = *(const float4*)p;
  float4 v1 = *(const float4*)(p + 4);
  float v[8] = {v0.x, v0.y, v0.z, v0.w, v1.x, v1.y, v1.z, v1.w};
  float s = 0.f;
  #pragma unroll
  for (int i = 0; i < 8; i++) s += v[i];
  s = wave_redsum(s);
  float mu = s * (1.f / DD);
  float d_[8], sq = 0.f;
  #pragma unroll
  for (int i = 0; i < 8; i++){ d_[i] = v[i] - mu; sq += d_[i] * d_[i]; }
  sq = wave_redsum(sq);
  float rs = 1.f / sqrtf(sq * (1.f / DD) + 1e-5f);
  #pragma unroll
  for (int i = 0; i < 8; i++){
    int dd = lane * 8 + i;
    float y = ldf(g, dd, isbf) * d_[i] * rs + ldf(be, dd, isbf);
    Yb[(long)row * DD + dd] = f2bf(y);
    if (WF32) Yf[(long)row * DD + dd] = y;
  }
}

extern "C" void kernel_launch(void* const* d_in, const int* in_sizes, int n_in,
                              void* d_out, int out_size, void* d_ws, size_t ws_size,
                              hipStream_t stream)
{
  const int* tokens = (const int*)d_in[0];
  const void* emb = d_in[1];
  const void* pe  = d_in[2];
  const void* Wq  = d_in[3];
  const void* bq  = d_in[4];
  const void* Wk  = d_in[5];
  const void* bk  = d_in[6];
  const void* Wv  = d_in[7];
  const void* bv  = d_in[8];
  const void* Wo  = d_in[9];
  const void* bo  = d_in[10];
  const void* g1  = d_in[11];
  const void* be1 = d_in[12];
  const void* W1  = d_in[13];
  const void* b1  = d_in[14];
  const void* W2  = d_in[15];
  const void* b2  = d_in[16];
  const void* g2  = d_in[17];
  const void* be2 = d_in[18];
  const void* Wf  = d_in[19];
  const void* bfb = d_in[20];
  float* out = (float*)d_out;   // reference output dtype = float32
  char* ws = (char*)d_ws;
  char* DO = (char*)d_out;

  const size_t MB = 1ull << 20;
  // ---- d_ws (39.3 MiB; <=69 MiB evidenced safe) ----
  int* dflag = (int*)ws;
  u16* x2b   = (u16*)(ws + 1 * MB);        // [1,5)
  u16* WfT   = (u16*)(ws + 8 * MB);        // [8,39.25)  bf16 [32000][512]

  // ---- d_out as scratch (380 of 500 MiB; all dead before logits) ----
  float* x    = (float*)(DO + 0 * MB);     // [0,8)
  u16*   xm2  = (u16*)(DO + 8 * MB);       // [8,16)    [4096][1024] = [xh|xl]
  u16*   Wq2  = (u16*)(DO + 16 * MB);      // [16,24)   [8][512][1024] = [wh|wl]
  u16*   Wk2  = (u16*)(DO + 24 * MB);      // [24,32)
  u16*   WvT  = (u16*)(DO + 32 * MB);      // [32,36)   [8][512][512]
  u16*   WoT  = (u16*)(DO + 36 * MB);      // [36,40)   [512][4096]
  u16*   W1T  = (u16*)(DO + 40 * MB);      // [40,42)   [2048][512]
  u16*   W2T  = (u16*)(DO + 42 * MB);      // [42,44)   [512][2048]
  u16*   q2   = (u16*)(DO + 48 * MB);      // [48,112)  [8][4096][1024] = [qh|ql]
  u16*   k2   = (u16*)(DO + 112 * MB);     // [112,176) [8][4096][1024] = [kh|kl]
  u16*   attn = (u16*)(DO + 240 * MB);     // [240,272) [64][512][512] bf16
  u16*   vT   = (u16*)(DO + 272 * MB);     // [272,304) [64][512 d][512 s]
  u16*   cat  = (u16*)(DO + 304 * MB);     // [304,336) [4096][4096]
  float* proj = (float*)(DO + 336 * MB);   // [336,344)
  float* x1f  = (float*)(DO + 344 * MB);   // [344,352)
  u16*   x1b  = (u16*)(DO + 352 * MB);     // [352,356)
  u16*   ff1  = (u16*)(DO + 356 * MB);     // [356,372) [4096][2048]
  float* ff2  = (float*)(DO + 372 * MB);   // [372,380)

  const float scale = 0.04419417382415922f;  // 1/sqrt(512)
  const long QSL = 524288;                   // 512*1024 (2-band q/k rows per z)

  k_dflag<<<1, 1, 0, stream>>>(pe, dflag);
  k_embed<<<dim3(4096), 256, 0, stream>>>(tokens, emb, pe, x, xm2, dflag);

  // one-time weight prep (2 launches)
  k_wsplitT<<<dim3(16, 16, 16), 256, 0, stream>>>(Wq, Wk, Wq2, Wk2, dflag);
  k_transAll<<<dim3(22144), 256, 0, stream>>>(
      Wv, Wo, W1, W2, Wf, WvT, WoT, W1T, W2T, WfT, dflag);

  // merged q/k/v projections: 8-phase counted-vmcnt schedule (r21/r22-proven)
  k_proj8<<<dim3(2, 16, 24), 512, 0, stream>>>(
      xm2, Wq2, Wk2, WvT, q2, k2, vT, bq, bk, bv, dflag);

  // fused scores+softmax -> attn bf16 (no sc buffer); z = h*8+b
  k_fsm<1, 2><<<dim3(4, 1, 64), 512, 0, stream>>>(
      q2, QSL, 1024, k2, QSL, 1024, attn, KC, scale, dflag);

  // o = attn @ v -> cat (torch.cat head order): 8-phase schedule
  k_cat8<<<dim3(2, 2, 64), 512, 0, stream>>>(attn, vT, cat, dflag);

  // proj = cat @ Wo + bo + x (128^2 kernel)
  k_mfma<EP_F32RES, false><<<dim3(4, 32, 1), 256, 0, stream>>>(
      cat, 0, HD, WoT, 0, proj, bo, x, HD, DD, 0.f, dflag);
  k_ln<true><<<dim3(1024), 256, 0, stream>>>(proj, g1, be1, x1b, x1f, dflag);

  // ff = relu(x1 @ W1 + b1) @ W2 + b2 + x1
  k_mfma<EP_RELU, false><<<dim3(16, 32, 1), 256, 0, stream>>>(
      x1b, 0, DD, W1T, 0, ff1, b1, nullptr, DD, NFF, 0.f, dflag);
  k_mfma<EP_F32RES, false><<<dim3(4, 32, 1), 256, 0, stream>>>(
      ff1, 0, NFF, W2T, 0, ff2, b2, x1f, NFF, DD, 0.f, dflag);
  k_ln<false><<<dim3(1024), 256, 0, stream>>>(ff2, g2, be2, x2b, nullptr, dflag);

  // logits = x2 @ Wf + bf -> f32 out: 8-phase counted-vmcnt kernel (NT = 512/64)
  k_out8<<<dim3(16, 125, 1), 512, 0, stream>>>(x2b, WfT, out, bfb, 8, dflag);
}

// Round 25
// 897.066 us; speedup vs baseline: 1.1175x; 1.0303x over previous
//
#include <hip/hip_runtime.h>

typedef unsigned short u16;
typedef unsigned int u32;
typedef short s16x8 __attribute__((ext_vector_type(8)));
typedef __bf16 bf16x8 __attribute__((ext_vector_type(8)));
typedef float f32x4 __attribute__((ext_vector_type(4)));

#define DEVI static __device__ __forceinline__

#define SS 512
#define DD 512
#define NFF 2048
#define VV 32000
#define MTOT 4096
#define HD 4096
#define KC 1536   // virtual split-concat K (2-band storage + read-time remap)

DEVI float bf2f(u16 h){ return __uint_as_float(((u32)h) << 16); }
DEVI u16 f2bf(float f){
  u32 u = __float_as_uint(f);
  return (u16)((u + 0x7FFFu + ((u >> 16) & 1u)) >> 16);
}
DEVI float ldf(const void* p, long i, int isbf){
  return isbf ? bf2f(((const u16*)p)[i]) : ((const float*)p)[i];
}

DEVI f32x4 mfma16(s16x8 a, s16x8 b, f32x4 c){
  return __builtin_amdgcn_mfma_f32_16x16x32_bf16(
      __builtin_bit_cast(bf16x8, a), __builtin_bit_cast(bf16x8, b), c, 0, 0, 0);
}

// direct global->LDS 16B copy; dst is wave-uniform base + lane*16, src per-lane
typedef const __attribute__((address_space(1))) unsigned int* gup;
typedef __attribute__((address_space(3))) unsigned int* lup;
DEVI void gload16(const void* g, void* l){
  __builtin_amdgcn_global_load_lds((gup)g, (lup)l, 16, 0, 0);
}

DEVI float wave_redsum(float v){
  #pragma unroll
  for (int off = 32; off > 0; off >>= 1) v += __shfl_xor(v, off, 64);
  return v;
}

// pe row0 = [sin0=0, cos0=1, ...]: first u32 word = 0x3F800000 if bf16, 0x00000000 if f32
__global__ void k_dflag(const void* pe, int* flag){
  flag[0] = (*(const u32*)pe == 0x3F800000u) ? 1 : 0;
}

// embed + residual + masked 2-band split: xm2[m][0:512]=hi, [512:1024]=lo
__global__ __launch_bounds__(256) void k_embed(
    const int* __restrict__ tok, const void* __restrict__ emb, const void* __restrict__ pe,
    float* __restrict__ x, u16* __restrict__ xm2, const int* __restrict__ dflag)
{
  int isbf = dflag[0];
  int blk = blockIdx.x;
  int s = blk & (SS - 1);
  int t = tok[blk];
  long rb = (long)blk * 1024;
  for (int d = threadIdx.x; d < DD; d += 256){
    float e = ldf(emb, (long)t * DD + d, isbf) + ldf(pe, (long)s * DD + d, isbf);
    x[(long)blk * DD + d] = e;
    float m = (d <= s) ? e : 0.f;           // triu(ones(S,D),k=1) zeroes d > s
    u16 hi = f2bf(m);
    u16 lo = f2bf(m - bf2f(hi));
    xm2[rb + d] = hi;
    xm2[rb + 512 + d] = lo;
  }
}

// split-transpose for Wq AND Wk (zz<8: Wq slice zz; else Wk slice zz-8):
// in W[z][512 d][512 e] -> out[z][512 e][1024]: band0=hi, band1=lo
__global__ __launch_bounds__(256) void k_wsplitT(
    const void* __restrict__ Wq, const void* __restrict__ Wk,
    u16* __restrict__ Wq2, u16* __restrict__ Wk2, const int* __restrict__ dflag)
{
  int isbf = dflag[0];
  int zz = blockIdx.z;
  const void* in = (zz < 8) ? Wq : Wk;
  u16* out = (zz < 8) ? Wq2 : Wk2;
  int z = zz & 7;
  long zin = (long)z * DD * DD;
  long zout = (long)z * DD * 1024;
  __shared__ float t[32][33];
  int e0 = blockIdx.x * 32, d0 = blockIdx.y * 32;
  int tx = threadIdx.x & 31, ty = threadIdx.x >> 5;
  #pragma unroll
  for (int i = 0; i < 4; i++){
    int d = ty + i * 8;
    t[d][tx] = ldf(in, zin + (long)(d0 + d) * DD + e0 + tx, isbf);
  }
  __syncthreads();
  #pragma unroll
  for (int i = 0; i < 4; i++){
    int e = ty + i * 8;
    float v = t[tx][e];
    u16 hi = f2bf(v);
    u16 lo = f2bf(v - bf2f(hi));
    long ob = zout + (long)(e0 + e) * 1024 + d0 + tx;
    out[ob] = hi;
    out[ob + 512] = lo;
  }
}

// all 5 plain transposes (f32/bf16 -> bf16) in one flat-grid kernel.
__global__ __launch_bounds__(256) void k_transAll(
    const void* __restrict__ Wv, const void* __restrict__ Wo,
    const void* __restrict__ W1, const void* __restrict__ W2,
    const void* __restrict__ Wf,
    u16* __restrict__ WvT, u16* __restrict__ WoT, u16* __restrict__ W1T,
    u16* __restrict__ W2T, u16* __restrict__ WfT, const int* __restrict__ dflag)
{
  int isbf = dflag[0];
  int f = blockIdx.x;
  const void* in; u16* out; int R, C, gx, loc;
  if (f < 2048)      { in = Wv; out = WvT; R = 512;  C = 512;   gx = 16;   loc = f; }
  else if (f < 4096) { in = Wo; out = WoT; R = 4096; C = 512;   gx = 16;   loc = f - 2048; }
  else if (f < 5120) { in = W1; out = W1T; R = 512;  C = 2048;  gx = 64;   loc = f - 4096; }
  else if (f < 6144) { in = W2; out = W2T; R = 2048; C = 512;   gx = 16;   loc = f - 5120; }
  else               { in = Wf; out = WfT; R = 512;  C = 32000; gx = 1000; loc = f - 6144; }
  int bx = loc % gx;
  int rest = loc / gx;
  int gy = R >> 5;
  int by = rest % gy, z = rest / gy;
  long zo = (long)z * R * C;
  __shared__ float t[32][33];
  int c0 = bx * 32, r0 = by * 32;
  int tx = threadIdx.x & 31, ty = threadIdx.x >> 5;
  #pragma unroll
  for (int i = 0; i < 4; i++){
    int r = ty + i * 8;
    t[r][tx] = ldf(in, zo + (long)(r0 + r) * C + c0 + tx, isbf);
  }
  __syncthreads();
  #pragma unroll
  for (int i = 0; i < 4; i++){
    int c = ty + i * 8;
    out[zo + (long)(c0 + c) * R + r0 + tx] = f2bf(t[tx][c]);
  }
}

enum { EP_F32RES = 5, EP_RELU = 6 };

// ---------- 128x128 tile, 4 waves (small-N GEMMs: Wo, FF1, FF2) ----------
template<int MODE, bool GSWAP>
__global__ __launch_bounds__(256) void k_mfma(
    const u16* __restrict__ A, long sA, int lda,
    const u16* __restrict__ Bt, long sB,
    void* __restrict__ Cv,
    const void* __restrict__ bias,
    const float* __restrict__ res,
    int K, int ldc, float scale,
    const int* __restrict__ dflag)
{
  int isbf = dflag[0];
  int z = blockIdx.z;
  const u16* Ab = A + (long)z * sA;
  const u16* Bb = Bt + (long)z * sB;
  __shared__ __align__(16) u16 As[2][4][128][8];
  __shared__ __align__(16) u16 Bs[2][4][128][8];
  int m0 = (GSWAP ? blockIdx.x : blockIdx.y) * 128;
  int n0 = (GSWAP ? blockIdx.y : blockIdx.x) * 128;
  int tid = threadIdx.x;
  int lane = tid & 63, w = tid >> 6;
  int wr = (w >> 1) * 64, wc = (w & 1) * 64;
  int l15 = lane & 15, l4 = lane >> 4;
  int s0 = w * 64 + lane;
  int ar0 = s0 & 127, ak0 = s0 >> 7;
  int ak1 = ak0 + 2;
  f32x4 zero = {0.f, 0.f, 0.f, 0.f};
  f32x4 acc[4][4];
  #pragma unroll
  for (int i = 0; i < 4; i++)
    #pragma unroll
    for (int j = 0; j < 4; j++) acc[i][j] = zero;

  const long arow0 = (long)(m0 + ar0) * lda;
  const long brow0 = (long)(n0 + ar0) * K;

  #define STAGE(buf, k0) do{ \
    u16* AsF = &As[buf][0][0][0]; \
    u16* BsF = &Bs[buf][0][0][0]; \
    gload16(Ab + arow0 + (k0) + ak0 * 8, AsF + (long)(w * 64) * 8); \
    gload16(Ab + arow0 + (k0) + ak1 * 8, AsF + (long)(256 + w * 64) * 8); \
    gload16(Bb + brow0 + (k0) + ak0 * 8, BsF + (long)(w * 64) * 8); \
    gload16(Bb + brow0 + (k0) + ak1 * 8, BsF + (long)(256 + w * 64) * 8); \
  }while(0)

  #define COMPUTE(buf) do{ \
    s16x8 af[4], bfr[4]; \
    _Pragma("unroll") \
    for (int i = 0; i < 4; i++) af[i] = *(const s16x8*)&As[buf][l4][wr + i * 16 + l15][0]; \
    _Pragma("unroll") \
    for (int j = 0; j < 4; j++) bfr[j] = *(const s16x8*)&Bs[buf][l4][wc + j * 16 + l15][0]; \
    _Pragma("unroll") \
    for (int i = 0; i < 4; i++) \
      _Pragma("unroll") \
      for (int j = 0; j < 4; j++) \
        acc[i][j] = mfma16(af[i], bfr[j], acc[i][j]); \
  }while(0)

  STAGE(0, 0);
  __syncthreads();
  for (int k0 = 0; k0 < K; k0 += 64){
    STAGE(1, k0 + 32);
    COMPUTE(0);
    __syncthreads();
    if (k0 + 64 < K) STAGE(0, k0 + 64);
    COMPUTE(1);
    __syncthreads();
  }
  #undef STAGE
  #undef COMPUTE

  int mbase = m0 + wr + l4 * 4;
  int nbase = n0 + wc + l15;
  if constexpr (MODE == EP_F32RES){
    float* C = (float*)Cv;
    #pragma unroll
    for (int j = 0; j < 4; j++){
      int n = nbase + j * 16;
      float badd = ldf(bias, n, isbf);
      #pragma unroll
      for (int i = 0; i < 4; i++)
        #pragma unroll
        for (int r = 0; r < 4; r++){
          long a = (long)(mbase + i * 16 + r) * ldc + n;
          C[a] = acc[i][j][r] + badd + res[a];
        }
    }
  } else if constexpr (MODE == EP_RELU){
    u16* C = (u16*)Cv;
    #pragma unroll
    for (int j = 0; j < 4; j++){
      int n = nbase + j * 16;
      float badd = ldf(bias, n, isbf);
      #pragma unroll
      for (int i = 0; i < 4; i++)
        #pragma unroll
        for (int r = 0; r < 4; r++)
          C[(long)(mbase + i * 16 + r) * ldc + n] = f2bf(fmaxf(acc[i][j][r] + badd, 0.f));
    }
  }
}

// ---------- 8-phase counted-vmcnt 256x256 GEMM for logits (K=NT*64) ----------
// (r21-proven) BK=64 K-tiles, 2x64KB LDS buffers, half-tile staging, 4 MFMA
// phases/tile; one counted s_waitcnt vmcnt(2) per tile; raw s_barrier fences.
__global__ __launch_bounds__(512, 2) void k_out8(
    const u16* __restrict__ A, const u16* __restrict__ Bt,
    float* __restrict__ O, const void* __restrict__ bias,
    int NT, const int* __restrict__ dflag)
{
  int isbf = dflag[0];
  __shared__ __align__(16) char smem[131072];   // 2 bufs x (A 32KB | B 32KB)
  u16* SM = (u16*)smem;
  // bijective XCD remap (nwg = 16*125 = 2000, %8 == 0)
  int f = blockIdx.x + gridDim.x * blockIdx.y;
  int qx = (gridDim.x * gridDim.y) >> 3;
  int L = (f & 7) * qx + (f >> 3);
  int m0 = (L % gridDim.x) * 256;
  int n0 = (L / gridDim.x) * 256;
  int tid = threadIdx.x;
  int lane = tid & 63, w = tid >> 6;
  int wm = (w >> 2) * 128, wn = (w & 3) * 64;
  int l15 = lane & 15, l4 = lane >> 4;
  f32x4 zero = {0.f, 0.f, 0.f, 0.f};
  f32x4 acc[8][4];
  #pragma unroll
  for (int i = 0; i < 8; i++)
    #pragma unroll
    for (int j = 0; j < 4; j++) acc[i][j] = zero;

  int rr = tid & 127, kc1 = tid >> 7;   // staging: row-in-half, k-chunk 0..3

  #define STAGEU(c, Tt, u) do{ \
    const u16* gb = (((u) & 1) == 0) ? A : Bt; \
    int base0 = (((u) & 1) == 0) ? m0 : n0; \
    int r2 = ((u) >> 1) * 128 + rr; \
    long gsrc = (long)(base0 + r2) * 512 + (Tt) * 64; \
    u16* lb = SM + (c) * 32768 + ((((u) & 1) == 0) ? 0 : 16384); \
    gload16(gb + gsrc + kc1 * 8,       lb + (kc1 * 256 + r2) * 8); \
    gload16(gb + gsrc + (kc1 + 4) * 8, lb + ((kc1 + 4) * 256 + r2) * 8); \
  }while(0)

  STAGEU(0, 0, 0); STAGEU(0, 0, 1); STAGEU(0, 0, 2); STAGEU(0, 0, 3);

  int cur = 0;
  for (int T = 0; T < NT; T++){
    int nxt = cur ^ 1;
    int more = (T + 1 < NT);
    s16x8 af[8];
    #pragma unroll
    for (int q = 0; q < 4; q++){
      if (more) STAGEU(nxt, T + 1, q);
      if (q == 0){
        if (more) asm volatile("s_waitcnt vmcnt(2)" ::: "memory");
        else      asm volatile("s_waitcnt vmcnt(0)" ::: "memory");
      }
      __builtin_amdgcn_s_barrier();
      __builtin_amdgcn_sched_barrier(0);
      int ks = q >> 1, jh = q & 1;
      if (jh == 0){
        #pragma unroll
        for (int i = 0; i < 8; i++)
          af[i] = *(const s16x8*)(SM + cur * 32768 +
                    ((ks * 4 + l4) * 256 + (wm + i * 16 + l15)) * 8);
      }
      s16x8 b0 = *(const s16x8*)(SM + cur * 32768 + 16384 +
                    ((ks * 4 + l4) * 256 + (wn + (jh * 2) * 16 + l15)) * 8);
      s16x8 b1 = *(const s16x8*)(SM + cur * 32768 + 16384 +
                    ((ks * 4 + l4) * 256 + (wn + (jh * 2 + 1) * 16 + l15)) * 8);
      __builtin_amdgcn_s_setprio(1);
      #pragma unroll
      for (int i = 0; i < 8; i++){
        acc[i][jh * 2]     = mfma16(af[i], b0, acc[i][jh * 2]);
        acc[i][jh * 2 + 1] = mfma16(af[i], b1, acc[i][jh * 2 + 1]);
      }
      __builtin_amdgcn_s_setprio(0);
    }
    __builtin_amdgcn_s_barrier();
    __builtin_amdgcn_sched_barrier(0);
    cur = nxt;
  }
  #undef STAGEU

  // coalesced epilogue: LDS-transpose slabs + NT f32x4 stores
  float* ldsT = (float*)smem;
  const int RST = 260;
  int hs16 = (w >> 2) * 16;
  float badd[4];
  #pragma unroll
  for (int j = 0; j < 4; j++) badd[j] = ldf(bias, n0 + wn + j * 16 + l15, isbf);
  #pragma unroll
  for (int i = 0; i < 8; i++){
    __syncthreads();
    #pragma unroll
    for (int j = 0; j < 4; j++){
      int col = wn + j * 16 + l15;
      #pragma unroll
      for (int r = 0; r < 4; r++)
        ldsT[(hs16 + l4 * 4 + r) * RST + col] = acc[i][j][r] + badd[j];
    }
    __syncthreads();
    #pragma unroll
    for (int p = 0; p < 4; p++){
      int chunk = tid + p * 512;
      int lr = chunk >> 6, c4 = chunk & 63;
      int gm = m0 + (lr >> 4) * 128 + i * 16 + (lr & 15);
      f32x4 v = *(f32x4*)&ldsT[lr * RST + c4 * 4];
      __builtin_nontemporal_store(v, (f32x4*)&O[(long)gm * VV + n0 + c4 * 4]);
    }
  }
}

// ---------- 8-phase merged q/k/v projection (r21/r22-proven schedule) ----------
__global__ __launch_bounds__(512, 2) void k_proj8(
    const u16* __restrict__ xm2,
    const u16* __restrict__ Wq2, const u16* __restrict__ Wk2, const u16* __restrict__ WvT,
    u16* __restrict__ q2, u16* __restrict__ k2, u16* __restrict__ vT,
    const void* __restrict__ bq, const void* __restrict__ bk, const void* __restrict__ bv,
    const int* __restrict__ dflag)
{
  int isbf = dflag[0];
  int zz = blockIdx.z;
  int z, ldb, NT, mode;
  const u16* Bb; const void* bias; u16* C;
  if (zz < 16){
    mode = 0; z = zz & 7;
    Bb = (zz < 8 ? Wq2 : Wk2) + (long)z * 524288;
    ldb = 1024; NT = 24;
    bias = (zz < 8) ? bq : bk;
    C = (zz < 8) ? q2 : k2;
  } else {
    mode = 1; z = zz - 16;
    Bb = WvT + (long)z * 262144;
    ldb = 512; NT = 8;
    bias = bv;
    C = vT;
  }
  const u16* Ab = xm2;
  __shared__ __align__(16) char smem[131072];
  u16* SM = (u16*)smem;
  int m0 = blockIdx.y * 256;
  int n0 = blockIdx.x * 256;
  int tid = threadIdx.x;
  int lane = tid & 63, w = tid >> 6;
  int wm = (w >> 2) * 128, wn = (w & 3) * 64;
  int l15 = lane & 15, l4 = lane >> 4;
  f32x4 zero = {0.f, 0.f, 0.f, 0.f};
  f32x4 acc[8][4];
  #pragma unroll
  for (int i = 0; i < 8; i++)
    #pragma unroll
    for (int j = 0; j < 4; j++) acc[i][j] = zero;

  int rr = tid & 127, kc1 = tid >> 7;

  #define KA8(Tt) (mode == 0 ? (((Tt) * 64 < 512) ? (Tt) * 64 : (Tt) * 64 - 512) : (Tt) * 64)
  #define KB8(Tt) (mode == 0 ? (((Tt) * 64 < 1024) ? (Tt) * 64 : (Tt) * 64 - 1024) : (Tt) * 64)

  #define STAGEU(c, Tt, u) do{ \
    const u16* gb = (((u) & 1) == 0) ? Ab : Bb; \
    long rs = (((u) & 1) == 0) ? 1024 : (long)ldb; \
    int base0 = (((u) & 1) == 0) ? m0 : n0; \
    int tk = (((u) & 1) == 0) ? KA8(Tt) : KB8(Tt); \
    int r2 = ((u) >> 1) * 128 + rr; \
    long gsrc = (long)(base0 + r2) * rs + tk; \
    u16* lb = SM + (c) * 32768 + ((((u) & 1) == 0) ? 0 : 16384); \
    gload16(gb + gsrc + kc1 * 8,       lb + (kc1 * 256 + r2) * 8); \
    gload16(gb + gsrc + (kc1 + 4) * 8, lb + ((kc1 + 4) * 256 + r2) * 8); \
  }while(0)

  STAGEU(0, 0, 0); STAGEU(0, 0, 1); STAGEU(0, 0, 2); STAGEU(0, 0, 3);

  int cur = 0;
  for (int T = 0; T < NT; T++){
    int nxt = cur ^ 1;
    int more = (T + 1 < NT);
    s16x8 af[8];
    #pragma unroll
    for (int q = 0; q < 4; q++){
      if (more) STAGEU(nxt, T + 1, q);
      if (q == 0){
        if (more) asm volatile("s_waitcnt vmcnt(2)" ::: "memory");
        else      asm volatile("s_waitcnt vmcnt(0)" ::: "memory");
      }
      __builtin_amdgcn_s_barrier();
      __builtin_amdgcn_sched_barrier(0);
      int ks = q >> 1, jh = q & 1;
      if (jh == 0){
        #pragma unroll
        for (int i = 0; i < 8; i++)
          af[i] = *(const s16x8*)(SM + cur * 32768 +
                    ((ks * 4 + l4) * 256 + (wm + i * 16 + l15)) * 8);
      }
      s16x8 b0 = *(const s16x8*)(SM + cur * 32768 + 16384 +
                    ((ks * 4 + l4) * 256 + (wn + (jh * 2) * 16 + l15)) * 8);
      s16x8 b1 = *(const s16x8*)(SM + cur * 32768 + 16384 +
                    ((ks * 4 + l4) * 256 + (wn + (jh * 2 + 1) * 16 + l15)) * 8);
      __builtin_amdgcn_s_setprio(1);
      #pragma unroll
      for (int i = 0; i < 8; i++){
        acc[i][jh * 2]     = mfma16(af[i], b0, acc[i][jh * 2]);
        acc[i][jh * 2 + 1] = mfma16(af[i], b1, acc[i][jh * 2 + 1]);
      }
      __builtin_amdgcn_s_setprio(0);
    }
    __builtin_amdgcn_s_barrier();
    __builtin_amdgcn_sched_barrier(0);
    cur = nxt;
  }
  #undef STAGEU
  #undef KA8
  #undef KB8

  int mbase = m0 + wm + l4 * 4;
  int nbase = n0 + wn + l15;
  if (mode == 0){
    // 2-band out: C[row][n]=hi, C[row][512+n]=lo, row stride 1024
    u16* Cz = C + (long)z * ((long)MTOT * 1024);
    #pragma unroll
    for (int j = 0; j < 4; j++){
      int n = nbase + j * 16;
      float badd = ldf(bias, (long)z * DD + n, isbf);
      #pragma unroll
      for (int i = 0; i < 8; i++)
        #pragma unroll
        for (int r = 0; r < 4; r++){
          float qv = acc[i][j][r] + badd;
          u16 hi = f2bf(qv);
          u16 lo = f2bf(qv - bf2f(hi));
          long rb = (long)(mbase + i * 16 + r) * 1024;
          Cz[rb + n] = hi;
          Cz[rb + 512 + n] = lo;
        }
    }
  } else {
    // vT[(z*8 + b)][d = n][s]; 4 acc regs = 4 consecutive s
    #pragma unroll
    for (int i = 0; i < 8; i++){
      int mrow = mbase + i * 16;
      int b = mrow >> 9, s = mrow & (SS - 1);
      #pragma unroll
      for (int j = 0; j < 4; j++){
        int n = nbase + j * 16;
        float badd = ldf(bias, (long)z * DD + n, isbf);
        ushort4 pk;
        pk.x = f2bf(acc[i][j][0] + badd); pk.y = f2bf(acc[i][j][1] + badd);
        pk.z = f2bf(acc[i][j][2] + badd); pk.w = f2bf(acc[i][j][3] + badd);
        *(ushort4*)&C[((long)(z * 8 + b) * DD + n) * SS + s] = pk;
      }
    }
  }
}

// ---------- 8-phase attn@v -> cat (k_proj8 mode-1 geometry; EP_CAT epilogue) ----------
__global__ __launch_bounds__(512, 2) void k_cat8(
    const u16* __restrict__ attn, const u16* __restrict__ vT,
    u16* __restrict__ cat, const int* __restrict__ dflag)
{
  int z = blockIdx.z;
  const u16* Ab = attn + (long)z * 262144;
  const u16* Bb = vT + (long)z * 262144;
  __shared__ __align__(16) char smem[131072];
  u16* SM = (u16*)smem;
  int m0 = blockIdx.y * 256;
  int n0 = blockIdx.x * 256;
  int tid = threadIdx.x;
  int lane = tid & 63, w = tid >> 6;
  int wm = (w >> 2) * 128, wn = (w & 3) * 64;
  int l15 = lane & 15, l4 = lane >> 4;
  f32x4 zero = {0.f, 0.f, 0.f, 0.f};
  f32x4 acc[8][4];
  #pragma unroll
  for (int i = 0; i < 8; i++)
    #pragma unroll
    for (int j = 0; j < 4; j++) acc[i][j] = zero;

  int rr = tid & 127, kc1 = tid >> 7;

  #define STAGEU(c, Tt, u) do{ \
    const u16* gb = (((u) & 1) == 0) ? Ab : Bb; \
    int base0 = (((u) & 1) == 0) ? m0 : n0; \
    int r2 = ((u) >> 1) * 128 + rr; \
    long gsrc = (long)(base0 + r2) * 512 + (Tt) * 64; \
    u16* lb = SM + (c) * 32768 + ((((u) & 1) == 0) ? 0 : 16384); \
    gload16(gb + gsrc + kc1 * 8,       lb + (kc1 * 256 + r2) * 8); \
    gload16(gb + gsrc + (kc1 + 4) * 8, lb + ((kc1 + 4) * 256 + r2) * 8); \
  }while(0)

  STAGEU(0, 0, 0); STAGEU(0, 0, 1); STAGEU(0, 0, 2); STAGEU(0, 0, 3);

  int cur = 0;
  for (int T = 0; T < 8; T++){
    int nxt = cur ^ 1;
    int more = (T + 1 < 8);
    s16x8 af[8];
    #pragma unroll
    for (int q = 0; q < 4; q++){
      if (more) STAGEU(nxt, T + 1, q);
      if (q == 0){
        if (more) asm volatile("s_waitcnt vmcnt(2)" ::: "memory");
        else      asm volatile("s_waitcnt vmcnt(0)" ::: "memory");
      }
      __builtin_amdgcn_s_barrier();
      __builtin_amdgcn_sched_barrier(0);
      int ks = q >> 1, jh = q & 1;
      if (jh == 0){
        #pragma unroll
        for (int i = 0; i < 8; i++)
          af[i] = *(const s16x8*)(SM + cur * 32768 +
                    ((ks * 4 + l4) * 256 + (wm + i * 16 + l15)) * 8);
      }
      s16x8 b0 = *(const s16x8*)(SM + cur * 32768 + 16384 +
                    ((ks * 4 + l4) * 256 + (wn + (jh * 2) * 16 + l15)) * 8);
      s16x8 b1 = *(const s16x8*)(SM + cur * 32768 + 16384 +
                    ((ks * 4 + l4) * 256 + (wn + (jh * 2 + 1) * 16 + l15)) * 8);
      __builtin_amdgcn_s_setprio(1);
      #pragma unroll
      for (int i = 0; i < 8; i++){
        acc[i][jh * 2]     = mfma16(af[i], b0, acc[i][jh * 2]);
        acc[i][jh * 2 + 1] = mfma16(af[i], b1, acc[i][jh * 2 + 1]);
      }
      __builtin_amdgcn_s_setprio(0);
    }
    __builtin_amdgcn_s_barrier();
    __builtin_amdgcn_sched_barrier(0);
    cur = nxt;
  }
  #undef STAGEU

  // cat[(b*S + s)][h*D + n]; z = h*8+b
  int mbase = m0 + wm + l4 * 4;
  int nbase = n0 + wn + l15;
  int h = z >> 3, b = z & 7;
  #pragma unroll
  for (int i = 0; i < 8; i++){
    int s = mbase + i * 16;
    #pragma unroll
    for (int j = 0; j < 4; j++){
      int n = nbase + j * 16;
      #pragma unroll
      for (int r = 0; r < 4; r++)
        cat[((long)b * SS + s + r) * HD + (long)h * DD + n] = f2bf(acc[i][j][r]);
    }
  }
}

// ---------- 8-phase fused scores+softmax: 128 q-rows x 512 k-cols ----------
// A = q2[z] [4096][1024] 2-band ([qh|qh|ql], ka = tk<512?tk:tk-512)
// B = k2[z] [4096][1024] 2-band ([kh|kl|kh], kb = tk<1024?tk:tk-1024)
// K = 1536 virtual, NT=24 BK=64 tiles. LDS: 2 bufs x (A 16KB + B 64KB) = 160KB.
// u16 units: buffer stride 40960 (81920 B), B-region offset 8192 (16384 B).
// Staging: 5 units/tile (u0 = A, u1..u4 = B rows (u-1)*128), 2 gloads/thread each;
// phases issue (2,1,1,1) units -> per-tile wait vmcnt(4) (10 outstanding + 4 new).
__global__ __launch_bounds__(512, 2) void k_fsm8(
    const u16* __restrict__ q2, const u16* __restrict__ k2,
    u16* __restrict__ P, float scale, const int* __restrict__ dflag)
{
  int z = blockIdx.z;
  const u16* Aq = q2 + (long)z * 524288;
  const u16* Bk = k2 + (long)z * 524288;
  __shared__ __align__(16) char smem[163840];   // 2 x (16KB A + 64KB B)
  u16* SM = (u16*)smem;
  int m0 = blockIdx.x * 128;
  int tid = threadIdx.x;
  int lane = tid & 63, w = tid >> 6;
  int wn = w * 64;
  int l15 = lane & 15, l4 = lane >> 4;
  f32x4 zero = {0.f, 0.f, 0.f, 0.f};
  f32x4 acc[8][4];
  #pragma unroll
  for (int i = 0; i < 8; i++)
    #pragma unroll
    for (int j = 0; j < 4; j++) acc[i][j] = zero;

  int kcl = tid >> 7, rowt = tid & 127;   // staging coords

  #define STAGEUF(c, Tt, u) do{ \
    if ((u) == 0){ \
      int ka = ((Tt) * 64 < 512) ? (Tt) * 64 : (Tt) * 64 - 512; \
      long g0 = (long)(m0 + rowt) * 1024 + ka; \
      u16* lb = SM + (long)(c) * 40960; \
      gload16(Aq + g0 + kcl * 8,       lb + (kcl * 128 + rowt) * 8); \
      gload16(Aq + g0 + (kcl + 4) * 8, lb + ((kcl + 4) * 128 + rowt) * 8); \
    } else { \
      int ub = (u) - 1; \
      int kb = ((Tt) * 64 < 1024) ? (Tt) * 64 : (Tt) * 64 - 1024; \
      long g0 = (long)(ub * 128 + rowt) * 1024 + kb; \
      u16* lb = SM + (long)(c) * 40960 + 8192; \
      gload16(Bk + g0 + kcl * 8,       lb + (kcl * 512 + ub * 128 + rowt) * 8); \
      gload16(Bk + g0 + (kcl + 4) * 8, lb + ((kcl + 4) * 512 + ub * 128 + rowt) * 8); \
    } \
  }while(0)

  // prologue: tile 0 fully staged (5 units = 10 loads/thread)
  STAGEUF(0, 0, 0); STAGEUF(0, 0, 1); STAGEUF(0, 0, 2);
  STAGEUF(0, 0, 3); STAGEUF(0, 0, 4);

  int cur = 0;
  for (int T = 0; T < 24; T++){
    int nxt = cur ^ 1;
    int more = (T + 1 < 24);
    s16x8 af[8];
    #pragma unroll
    for (int q = 0; q < 4; q++){
      if (q == 0){
        if (more){ STAGEUF(nxt, T + 1, 0); STAGEUF(nxt, T + 1, 1); }
        if (more) asm volatile("s_waitcnt vmcnt(4)" ::: "memory");
        else      asm volatile("s_waitcnt vmcnt(0)" ::: "memory");
      } else {
        if (more) STAGEUF(nxt, T + 1, q + 1);
      }
      __builtin_amdgcn_s_barrier();
      __builtin_amdgcn_sched_barrier(0);
      int ks = q >> 1, jh = q & 1;
      if (jh == 0){
        #pragma unroll
        for (int i = 0; i < 8; i++)
          af[i] = *(const s16x8*)(SM + (long)cur * 40960 +
                    ((ks * 4 + l4) * 128 + (i * 16 + l15)) * 8);
      }
      s16x8 b0 = *(const s16x8*)(SM + (long)cur * 40960 + 8192 +
                    ((ks * 4 + l4) * 512 + (wn + (jh * 2) * 16 + l15)) * 8);
      s16x8 b1 = *(const s16x8*)(SM + (long)cur * 40960 + 8192 +
                    ((ks * 4 + l4) * 512 + (wn + (jh * 2 + 1) * 16 + l15)) * 8);
      __builtin_amdgcn_s_setprio(1);
      #pragma unroll
      for (int i = 0; i < 8; i++){
        acc[i][jh * 2]     = mfma16(af[i], b0, acc[i][jh * 2]);
        acc[i][jh * 2 + 1] = mfma16(af[i], b1, acc[i][jh * 2 + 1]);
      }
      __builtin_amdgcn_s_setprio(0);
    }
    __builtin_amdgcn_s_barrier();
    __builtin_amdgcn_sched_barrier(0);
    cur = nxt;
  }
  #undef STAGEUF

  // ---- softmax over 512 cols of each of 128 rows (verbatim r23 epilogue) ----
  float* sred = (float*)smem;           // [8 waves][128 rows]
  float* srow = (float*)(smem + 4096);  // [128]

  #pragma unroll
  for (int i = 0; i < 8; i++)
    #pragma unroll
    for (int j = 0; j < 4; j++)
      acc[i][j] *= scale;

  #pragma unroll
  for (int i = 0; i < 8; i++)
    #pragma unroll
    for (int r = 0; r < 4; r++){
      float m = fmaxf(fmaxf(acc[i][0][r], acc[i][1][r]),
                      fmaxf(acc[i][2][r], acc[i][3][r]));
      #pragma unroll
      for (int off = 1; off < 16; off <<= 1) m = fmaxf(m, __shfl_xor(m, off, 64));
      if (l15 == 0) sred[w * 128 + l4 * 4 + i * 16 + r] = m;
    }
  __syncthreads();
  if (tid < 128){
    float m = sred[tid];
    #pragma unroll
    for (int w2 = 1; w2 < 8; w2++) m = fmaxf(m, sred[w2 * 128 + tid]);
    srow[tid] = m;
  }
  __syncthreads();
  #pragma unroll
  for (int i = 0; i < 8; i++)
    #pragma unroll
    for (int r = 0; r < 4; r++){
      float rm = srow[l4 * 4 + i * 16 + r];
      float s = 0.f;
      #pragma unroll
      for (int j = 0; j < 4; j++){
        float e = expf(acc[i][j][r] - rm);
        acc[i][j][r] = e;
        s += e;
      }
      #pragma unroll
      for (int off = 1; off < 16; off <<= 1) s += __shfl_xor(s, off, 64);
      if (l15 == 0) sred[w * 128 + l4 * 4 + i * 16 + r] = s;
    }
  __syncthreads();
  if (tid < 128){
    float s = 0.f;
    #pragma unroll
    for (int w2 = 0; w2 < 8; w2++) s += sred[w2 * 128 + tid];
    srow[tid] = 1.f / s;
  }
  __syncthreads();
  // coalesced attn store: 32-row LDS slabs (u16, pad 520) then 8B-chunk writes
  u16* Pz = P + (long)z * ((long)SS * SS);
  u16* pb = (u16*)(smem + 8192);
  const int PST = 520;
  #pragma unroll
  for (int ii = 0; ii < 4; ii++){
    __syncthreads();
    #pragma unroll
    for (int s2 = 0; s2 < 2; s2++){
      int i = ii * 2 + s2;
      #pragma unroll
      for (int r = 0; r < 4; r++){
        int rl = l4 * 4 + i * 16 + r;
        float inv = srow[rl];
        #pragma unroll
        for (int j = 0; j < 4; j++)
          pb[(s2 * 16 + l4 * 4 + r) * PST + wn + j * 16 + l15] = f2bf(acc[i][j][r] * inv);
      }
    }
    __syncthreads();
    #pragma unroll
    for (int p = 0; p < 8; p++){
      int chunk = tid + p * 512;
      int lr = chunk >> 7, c8 = chunk & 127;
      ushort4 v = *(ushort4*)&pb[lr * PST + c8 * 4];
      *(ushort4*)&Pz[(long)(m0 + ii * 32 + lr) * SS + c8 * 4] = v;
    }
  }
}

// LayerNorm f32 -> bf16 (+ optional f32), one wave per row of 512
template<bool WF32>
__global__ __launch_bounds__(256) void k_ln(
    const float* __restrict__ X, const void* __restrict__ g, const void* __restrict__ be,
    u16* __restrict__ Yb, float* __restrict__ Yf, const int* __restrict__ dflag)
{
  int isbf = dflag[0];
  int row = blockIdx.x * 4 + (threadIdx.x >> 6);
  int lane = threadIdx.x & 63;
  const float* p = X + (long)row * DD + lane * 8;
  float4 v0 = *(const float4*)p;
  float4 v1 = *(const float4*)(p + 4);
  float v[8] = {v0.x, v0.y, v0.z, v0.w, v1.x, v1.y, v1.z, v1.w};
  float s = 0.f;
  #pragma unroll
  for (int i = 0; i < 8; i++) s += v[i];
  s = wave_redsum(s);
  float mu = s * (1.f / DD);
  float d_[8], sq = 0.f;
  #pragma unroll
  for (int i = 0; i < 8; i++){ d_[i] = v[i] - mu; sq += d_[i] * d_[i]; }
  sq = wave_redsum(sq);
  float rs = 1.f / sqrtf(sq * (1.f / DD) + 1e-5f);
  #pragma unroll
  for (int i = 0; i < 8; i++){
    int dd = lane * 8 + i;
    float y = ldf(g, dd, isbf) * d_[i] * rs + ldf(be, dd, isbf);
    Yb[(long)row * DD + dd] = f2bf(y);
    if (WF32) Yf[(long)row * DD + dd] = y;
  }
}

extern "C" void kernel_launch(void* const* d_in, const int* in_sizes, int n_in,
                              void* d_out, int out_size, void* d_ws, size_t ws_size,
                              hipStream_t stream)
{
  const int* tokens = (const int*)d_in[0];
  const void* emb = d_in[1];
  const void* pe  = d_in[2];
  const void* Wq  = d_in[3];
  const void* bq  = d_in[4];
  const void* Wk  = d_in[5];
  const void* bk  = d_in[6];
  const void* Wv  = d_in[7];
  const void* bv  = d_in[8];
  const void* Wo  = d_in[9];
  const void* bo  = d_in[10];
  const void* g1  = d_in[11];
  const void* be1 = d_in[12];
  const void* W1  = d_in[13];
  const void* b1  = d_in[14];
  const void* W2  = d_in[15];
  const void* b2  = d_in[16];
  const void* g2  = d_in[17];
  const void* be2 = d_in[18];
  const void* Wf  = d_in[19];
  const void* bfb = d_in[20];
  float* out = (float*)d_out;   // reference output dtype = float32
  char* ws = (char*)d_ws;
  char* DO = (char*)d_out;

  const size_t MB = 1ull << 20;
  // ---- d_ws (39.3 MiB; <=69 MiB evidenced safe) ----
  int* dflag = (int*)ws;
  u16* x2b   = (u16*)(ws + 1 * MB);        // [1,5)
  u16* WfT   = (u16*)(ws + 8 * MB);        // [8,39.25)  bf16 [32000][512]

  // ---- d_out as scratch (380 of 500 MiB; all dead before logits) ----
  float* x    = (float*)(DO + 0 * MB);     // [0,8)
  u16*   xm2  = (u16*)(DO + 8 * MB);       // [8,16)    [4096][1024] = [xh|xl]
  u16*   Wq2  = (u16*)(DO + 16 * MB);      // [16,24)   [8][512][1024] = [wh|wl]
  u16*   Wk2  = (u16*)(DO + 24 * MB);      // [24,32)
  u16*   WvT  = (u16*)(DO + 32 * MB);      // [32,36)   [8][512][512]
  u16*   WoT  = (u16*)(DO + 36 * MB);      // [36,40)   [512][4096]
  u16*   W1T  = (u16*)(DO + 40 * MB);      // [40,42)   [2048][512]
  u16*   W2T  = (u16*)(DO + 42 * MB);      // [42,44)   [512][2048]
  u16*   q2   = (u16*)(DO + 48 * MB);      // [48,112)  [8][4096][1024] = [qh|ql]
  u16*   k2   = (u16*)(DO + 112 * MB);     // [112,176) [8][4096][1024] = [kh|kl]
  u16*   attn = (u16*)(DO + 240 * MB);     // [240,272) [64][512][512] bf16
  u16*   vT   = (u16*)(DO + 272 * MB);     // [272,304) [64][512 d][512 s]
  u16*   cat  = (u16*)(DO + 304 * MB);     // [304,336) [4096][4096]
  float* proj = (float*)(DO + 336 * MB);   // [336,344)
  float* x1f  = (float*)(DO + 344 * MB);   // [344,352)
  u16*   x1b  = (u16*)(DO + 352 * MB);     // [352,356)
  u16*   ff1  = (u16*)(DO + 356 * MB);     // [356,372) [4096][2048]
  float* ff2  = (float*)(DO + 372 * MB);   // [372,380)

  const float scale = 0.04419417382415922f;  // 1/sqrt(512)

  k_dflag<<<1, 1, 0, stream>>>(pe, dflag);
  k_embed<<<dim3(4096), 256, 0, stream>>>(tokens, emb, pe, x, xm2, dflag);

  // one-time weight prep (2 launches)
  k_wsplitT<<<dim3(16, 16, 16), 256, 0, stream>>>(Wq, Wk, Wq2, Wk2, dflag);
  k_transAll<<<dim3(22144), 256, 0, stream>>>(
      Wv, Wo, W1, W2, Wf, WvT, WoT, W1T, W2T, WfT, dflag);

  // merged q/k/v projections: 8-phase counted-vmcnt schedule (r21/r22-proven)
  k_proj8<<<dim3(2, 16, 24), 512, 0, stream>>>(
      xm2, Wq2, Wk2, WvT, q2, k2, vT, bq, bk, bv, dflag);

  // fused scores+softmax -> attn bf16: 8-phase counted-vmcnt schedule
  k_fsm8<<<dim3(4, 1, 64), 512, 0, stream>>>(q2, k2, attn, scale, dflag);

  // o = attn @ v -> cat (torch.cat head order): 8-phase schedule
  k_cat8<<<dim3(2, 2, 64), 512, 0, stream>>>(attn, vT, cat, dflag);

  // proj = cat @ Wo + bo + x (128^2 kernel)
  k_mfma<EP_F32RES, false><<<dim3(4, 32, 1), 256, 0, stream>>>(
      cat, 0, HD, WoT, 0, proj, bo, x, HD, DD, 0.f, dflag);
  k_ln<true><<<dim3(1024), 256, 0, stream>>>(proj, g1, be1, x1b, x1f, dflag);

  // ff = relu(x1 @ W1 + b1) @ W2 + b2 + x1
  k_mfma<EP_RELU, false><<<dim3(16, 32, 1), 256, 0, stream>>>(
      x1b, 0, DD, W1T, 0, ff1, b1, nullptr, DD, NFF, 0.f, dflag);
  k_mfma<EP_F32RES, false><<<dim3(4, 32, 1), 256, 0, stream>>>(
      ff1, 0, NFF, W2T, 0, ff2, b2, x1f, NFF, DD, 0.f, dflag);
  k_ln<false><<<dim3(1024), 256, 0, stream>>>(ff2, g2, be2, x2b, nullptr, dflag);

  // logits = x2 @ Wf + bf -> f32 out: 8-phase counted-vmcnt kernel (NT = 512/64)
  k_out8<<<dim3(16, 125, 1), 512, 0, stream>>>(x2b, WfT, out, bfb, 8, dflag);
}

// Round 26
// 895.257 us; speedup vs baseline: 1.1198x; 1.0020x over previous
//
#include <hip/hip_runtime.h>

typedef unsigned short u16;
typedef unsigned int u32;
typedef short s16x8 __attribute__((ext_vector_type(8)));
typedef __bf16 bf16x8 __attribute__((ext_vector_type(8)));
typedef float f32x4 __attribute__((ext_vector_type(4)));

#define DEVI static __device__ __forceinline__

#define SS 512
#define DD 512
#define NFF 2048
#define VV 32000
#define MTOT 4096
#define HD 4096
#define KC 1536   // virtual split-concat K (2-band storage + read-time remap)

DEVI float bf2f(u16 h){ return __uint_as_float(((u32)h) << 16); }
DEVI u16 f2bf(float f){
  u32 u = __float_as_uint(f);
  return (u16)((u + 0x7FFFu + ((u >> 16) & 1u)) >> 16);
}
DEVI float ldf(const void* p, long i, int isbf){
  return isbf ? bf2f(((const u16*)p)[i]) : ((const float*)p)[i];
}

DEVI f32x4 mfma16(s16x8 a, s16x8 b, f32x4 c){
  return __builtin_amdgcn_mfma_f32_16x16x32_bf16(
      __builtin_bit_cast(bf16x8, a), __builtin_bit_cast(bf16x8, b), c, 0, 0, 0);
}

// direct global->LDS 16B copy; dst is wave-uniform base + lane*16, src per-lane
typedef const __attribute__((address_space(1))) unsigned int* gup;
typedef __attribute__((address_space(3))) unsigned int* lup;
DEVI void gload16(const void* g, void* l){
  __builtin_amdgcn_global_load_lds((gup)g, (lup)l, 16, 0, 0);
}

DEVI float wave_redsum(float v){
  #pragma unroll
  for (int off = 32; off > 0; off >>= 1) v += __shfl_xor(v, off, 64);
  return v;
}

// pe row0 = [sin0=0, cos0=1, ...]: first u32 word = 0x3F800000 if bf16, 0x00000000 if f32
__global__ void k_dflag(const void* pe, int* flag){
  flag[0] = (*(const u32*)pe == 0x3F800000u) ? 1 : 0;
}

// embed + residual + masked 2-band split: xm2[m][0:512]=hi, [512:1024]=lo
__global__ __launch_bounds__(256) void k_embed(
    const int* __restrict__ tok, const void* __restrict__ emb, const void* __restrict__ pe,
    float* __restrict__ x, u16* __restrict__ xm2, const int* __restrict__ dflag)
{
  int isbf = dflag[0];
  int blk = blockIdx.x;
  int s = blk & (SS - 1);
  int t = tok[blk];
  long rb = (long)blk * 1024;
  for (int d = threadIdx.x; d < DD; d += 256){
    float e = ldf(emb, (long)t * DD + d, isbf) + ldf(pe, (long)s * DD + d, isbf);
    x[(long)blk * DD + d] = e;
    float m = (d <= s) ? e : 0.f;           // triu(ones(S,D),k=1) zeroes d > s
    u16 hi = f2bf(m);
    u16 lo = f2bf(m - bf2f(hi));
    xm2[rb + d] = hi;
    xm2[rb + 512 + d] = lo;
  }
}

// split-transpose for Wq AND Wk (zz<8: Wq slice zz; else Wk slice zz-8):
// in W[z][512 d][512 e] -> out[z][512 e][1024]: band0=hi, band1=lo
__global__ __launch_bounds__(256) void k_wsplitT(
    const void* __restrict__ Wq, const void* __restrict__ Wk,
    u16* __restrict__ Wq2, u16* __restrict__ Wk2, const int* __restrict__ dflag)
{
  int isbf = dflag[0];
  int zz = blockIdx.z;
  const void* in = (zz < 8) ? Wq : Wk;
  u16* out = (zz < 8) ? Wq2 : Wk2;
  int z = zz & 7;
  long zin = (long)z * DD * DD;
  long zout = (long)z * DD * 1024;
  __shared__ float t[32][33];
  int e0 = blockIdx.x * 32, d0 = blockIdx.y * 32;
  int tx = threadIdx.x & 31, ty = threadIdx.x >> 5;
  #pragma unroll
  for (int i = 0; i < 4; i++){
    int d = ty + i * 8;
    t[d][tx] = ldf(in, zin + (long)(d0 + d) * DD + e0 + tx, isbf);
  }
  __syncthreads();
  #pragma unroll
  for (int i = 0; i < 4; i++){
    int e = ty + i * 8;
    float v = t[tx][e];
    u16 hi = f2bf(v);
    u16 lo = f2bf(v - bf2f(hi));
    long ob = zout + (long)(e0 + e) * 1024 + d0 + tx;
    out[ob] = hi;
    out[ob + 512] = lo;
  }
}

// all 5 plain transposes (f32/bf16 -> bf16) in one flat-grid kernel.
__global__ __launch_bounds__(256) void k_transAll(
    const void* __restrict__ Wv, const void* __restrict__ Wo,
    const void* __restrict__ W1, const void* __restrict__ W2,
    const void* __restrict__ Wf,
    u16* __restrict__ WvT, u16* __restrict__ WoT, u16* __restrict__ W1T,
    u16* __restrict__ W2T, u16* __restrict__ WfT, const int* __restrict__ dflag)
{
  int isbf = dflag[0];
  int f = blockIdx.x;
  const void* in; u16* out; int R, C, gx, loc;
  if (f < 2048)      { in = Wv; out = WvT; R = 512;  C = 512;   gx = 16;   loc = f; }
  else if (f < 4096) { in = Wo; out = WoT; R = 4096; C = 512;   gx = 16;   loc = f - 2048; }
  else if (f < 5120) { in = W1; out = W1T; R = 512;  C = 2048;  gx = 64;   loc = f - 4096; }
  else if (f < 6144) { in = W2; out = W2T; R = 2048; C = 512;   gx = 16;   loc = f - 5120; }
  else               { in = Wf; out = WfT; R = 512;  C = 32000; gx = 1000; loc = f - 6144; }
  int bx = loc % gx;
  int rest = loc / gx;
  int gy = R >> 5;
  int by = rest % gy, z = rest / gy;
  long zo = (long)z * R * C;
  __shared__ float t[32][33];
  int c0 = bx * 32, r0 = by * 32;
  int tx = threadIdx.x & 31, ty = threadIdx.x >> 5;
  #pragma unroll
  for (int i = 0; i < 4; i++){
    int r = ty + i * 8;
    t[r][tx] = ldf(in, zo + (long)(r0 + r) * C + c0 + tx, isbf);
  }
  __syncthreads();
  #pragma unroll
  for (int i = 0; i < 4; i++){
    int c = ty + i * 8;
    out[zo + (long)(c0 + c) * R + r0 + tx] = f2bf(t[tx][c]);
  }
}

enum { EP_F32RES = 5, EP_RELU = 6 };

// ---------- 128x128 tile, 4 waves (small-N GEMMs: Wo, FF2) ----------
template<int MODE, bool GSWAP>
__global__ __launch_bounds__(256) void k_mfma(
    const u16* __restrict__ A, long sA, int lda,
    const u16* __restrict__ Bt, long sB,
    void* __restrict__ Cv,
    const void* __restrict__ bias,
    const float* __restrict__ res,
    int K, int ldc, float scale,
    const int* __restrict__ dflag)
{
  int isbf = dflag[0];
  int z = blockIdx.z;
  const u16* Ab = A + (long)z * sA;
  const u16* Bb = Bt + (long)z * sB;
  __shared__ __align__(16) u16 As[2][4][128][8];
  __shared__ __align__(16) u16 Bs[2][4][128][8];
  int m0 = (GSWAP ? blockIdx.x : blockIdx.y) * 128;
  int n0 = (GSWAP ? blockIdx.y : blockIdx.x) * 128;
  int tid = threadIdx.x;
  int lane = tid & 63, w = tid >> 6;
  int wr = (w >> 1) * 64, wc = (w & 1) * 64;
  int l15 = lane & 15, l4 = lane >> 4;
  int s0 = w * 64 + lane;
  int ar0 = s0 & 127, ak0 = s0 >> 7;
  int ak1 = ak0 + 2;
  f32x4 zero = {0.f, 0.f, 0.f, 0.f};
  f32x4 acc[4][4];
  #pragma unroll
  for (int i = 0; i < 4; i++)
    #pragma unroll
    for (int j = 0; j < 4; j++) acc[i][j] = zero;

  const long arow0 = (long)(m0 + ar0) * lda;
  const long brow0 = (long)(n0 + ar0) * K;

  #define STAGE(buf, k0) do{ \
    u16* AsF = &As[buf][0][0][0]; \
    u16* BsF = &Bs[buf][0][0][0]; \
    gload16(Ab + arow0 + (k0) + ak0 * 8, AsF + (long)(w * 64) * 8); \
    gload16(Ab + arow0 + (k0) + ak1 * 8, AsF + (long)(256 + w * 64) * 8); \
    gload16(Bb + brow0 + (k0) + ak0 * 8, BsF + (long)(w * 64) * 8); \
    gload16(Bb + brow0 + (k0) + ak1 * 8, BsF + (long)(256 + w * 64) * 8); \
  }while(0)

  #define COMPUTE(buf) do{ \
    s16x8 af[4], bfr[4]; \
    _Pragma("unroll") \
    for (int i = 0; i < 4; i++) af[i] = *(const s16x8*)&As[buf][l4][wr + i * 16 + l15][0]; \
    _Pragma("unroll") \
    for (int j = 0; j < 4; j++) bfr[j] = *(const s16x8*)&Bs[buf][l4][wc + j * 16 + l15][0]; \
    _Pragma("unroll") \
    for (int i = 0; i < 4; i++) \
      _Pragma("unroll") \
      for (int j = 0; j < 4; j++) \
        acc[i][j] = mfma16(af[i], bfr[j], acc[i][j]); \
  }while(0)

  STAGE(0, 0);
  __syncthreads();
  for (int k0 = 0; k0 < K; k0 += 64){
    STAGE(1, k0 + 32);
    COMPUTE(0);
    __syncthreads();
    if (k0 + 64 < K) STAGE(0, k0 + 64);
    COMPUTE(1);
    __syncthreads();
  }
  #undef STAGE
  #undef COMPUTE

  int mbase = m0 + wr + l4 * 4;
  int nbase = n0 + wc + l15;
  if constexpr (MODE == EP_F32RES){
    float* C = (float*)Cv;
    #pragma unroll
    for (int j = 0; j < 4; j++){
      int n = nbase + j * 16;
      float badd = ldf(bias, n, isbf);
      #pragma unroll
      for (int i = 0; i < 4; i++)
        #pragma unroll
        for (int r = 0; r < 4; r++){
          long a = (long)(mbase + i * 16 + r) * ldc + n;
          C[a] = acc[i][j][r] + badd + res[a];
        }
    }
  } else if constexpr (MODE == EP_RELU){
    u16* C = (u16*)Cv;
    #pragma unroll
    for (int j = 0; j < 4; j++){
      int n = nbase + j * 16;
      float badd = ldf(bias, n, isbf);
      #pragma unroll
      for (int i = 0; i < 4; i++)
        #pragma unroll
        for (int r = 0; r < 4; r++)
          C[(long)(mbase + i * 16 + r) * ldc + n] = f2bf(fmaxf(acc[i][j][r] + badd, 0.f));
    }
  }
}

// ---------- 8-phase counted-vmcnt 256x256 GEMM for logits (K=NT*64) ----------
__global__ __launch_bounds__(512, 2) void k_out8(
    const u16* __restrict__ A, const u16* __restrict__ Bt,
    float* __restrict__ O, const void* __restrict__ bias,
    int NT, const int* __restrict__ dflag)
{
  int isbf = dflag[0];
  __shared__ __align__(16) char smem[131072];   // 2 bufs x (A 32KB | B 32KB)
  u16* SM = (u16*)smem;
  int f = blockIdx.x + gridDim.x * blockIdx.y;
  int qx = (gridDim.x * gridDim.y) >> 3;
  int L = (f & 7) * qx + (f >> 3);
  int m0 = (L % gridDim.x) * 256;
  int n0 = (L / gridDim.x) * 256;
  int tid = threadIdx.x;
  int lane = tid & 63, w = tid >> 6;
  int wm = (w >> 2) * 128, wn = (w & 3) * 64;
  int l15 = lane & 15, l4 = lane >> 4;
  f32x4 zero = {0.f, 0.f, 0.f, 0.f};
  f32x4 acc[8][4];
  #pragma unroll
  for (int i = 0; i < 8; i++)
    #pragma unroll
    for (int j = 0; j < 4; j++) acc[i][j] = zero;

  int rr = tid & 127, kc1 = tid >> 7;

  #define STAGEU(c, Tt, u) do{ \
    const u16* gb = (((u) & 1) == 0) ? A : Bt; \
    int base0 = (((u) & 1) == 0) ? m0 : n0; \
    int r2 = ((u) >> 1) * 128 + rr; \
    long gsrc = (long)(base0 + r2) * 512 + (Tt) * 64; \
    u16* lb = SM + (c) * 32768 + ((((u) & 1) == 0) ? 0 : 16384); \
    gload16(gb + gsrc + kc1 * 8,       lb + (kc1 * 256 + r2) * 8); \
    gload16(gb + gsrc + (kc1 + 4) * 8, lb + ((kc1 + 4) * 256 + r2) * 8); \
  }while(0)

  STAGEU(0, 0, 0); STAGEU(0, 0, 1); STAGEU(0, 0, 2); STAGEU(0, 0, 3);

  int cur = 0;
  for (int T = 0; T < NT; T++){
    int nxt = cur ^ 1;
    int more = (T + 1 < NT);
    s16x8 af[8];
    #pragma unroll
    for (int q = 0; q < 4; q++){
      if (more) STAGEU(nxt, T + 1, q);
      if (q == 0){
        if (more) asm volatile("s_waitcnt vmcnt(2)" ::: "memory");
        else      asm volatile("s_waitcnt vmcnt(0)" ::: "memory");
      }
      __builtin_amdgcn_s_barrier();
      __builtin_amdgcn_sched_barrier(0);
      int ks = q >> 1, jh = q & 1;
      if (jh == 0){
        #pragma unroll
        for (int i = 0; i < 8; i++)
          af[i] = *(const s16x8*)(SM + cur * 32768 +
                    ((ks * 4 + l4) * 256 + (wm + i * 16 + l15)) * 8);
      }
      s16x8 b0 = *(const s16x8*)(SM + cur * 32768 + 16384 +
                    ((ks * 4 + l4) * 256 + (wn + (jh * 2) * 16 + l15)) * 8);
      s16x8 b1 = *(const s16x8*)(SM + cur * 32768 + 16384 +
                    ((ks * 4 + l4) * 256 + (wn + (jh * 2 + 1) * 16 + l15)) * 8);
      __builtin_amdgcn_s_setprio(1);
      #pragma unroll
      for (int i = 0; i < 8; i++){
        acc[i][jh * 2]     = mfma16(af[i], b0, acc[i][jh * 2]);
        acc[i][jh * 2 + 1] = mfma16(af[i], b1, acc[i][jh * 2 + 1]);
      }
      __builtin_amdgcn_s_setprio(0);
    }
    __builtin_amdgcn_s_barrier();
    __builtin_amdgcn_sched_barrier(0);
    cur = nxt;
  }
  #undef STAGEU

  float* ldsT = (float*)smem;
  const int RST = 260;
  int hs16 = (w >> 2) * 16;
  float badd[4];
  #pragma unroll
  for (int j = 0; j < 4; j++) badd[j] = ldf(bias, n0 + wn + j * 16 + l15, isbf);
  #pragma unroll
  for (int i = 0; i < 8; i++){
    __syncthreads();
    #pragma unroll
    for (int j = 0; j < 4; j++){
      int col = wn + j * 16 + l15;
      #pragma unroll
      for (int r = 0; r < 4; r++)
        ldsT[(hs16 + l4 * 4 + r) * RST + col] = acc[i][j][r] + badd[j];
    }
    __syncthreads();
    #pragma unroll
    for (int p = 0; p < 4; p++){
      int chunk = tid + p * 512;
      int lr = chunk >> 6, c4 = chunk & 63;
      int gm = m0 + (lr >> 4) * 128 + i * 16 + (lr & 15);
      f32x4 v = *(f32x4*)&ldsT[lr * RST + c4 * 4];
      __builtin_nontemporal_store(v, (f32x4*)&O[(long)gm * VV + n0 + c4 * 4]);
    }
  }
}

// ---------- 8-phase merged q/k/v projection (r21/r22-proven schedule) ----------
__global__ __launch_bounds__(512, 2) void k_proj8(
    const u16* __restrict__ xm2,
    const u16* __restrict__ Wq2, const u16* __restrict__ Wk2, const u16* __restrict__ WvT,
    u16* __restrict__ q2, u16* __restrict__ k2, u16* __restrict__ vT,
    const void* __restrict__ bq, const void* __restrict__ bk, const void* __restrict__ bv,
    const int* __restrict__ dflag)
{
  int isbf = dflag[0];
  int zz = blockIdx.z;
  int z, ldb, NT, mode;
  const u16* Bb; const void* bias; u16* C;
  if (zz < 16){
    mode = 0; z = zz & 7;
    Bb = (zz < 8 ? Wq2 : Wk2) + (long)z * 524288;
    ldb = 1024; NT = 24;
    bias = (zz < 8) ? bq : bk;
    C = (zz < 8) ? q2 : k2;
  } else {
    mode = 1; z = zz - 16;
    Bb = WvT + (long)z * 262144;
    ldb = 512; NT = 8;
    bias = bv;
    C = vT;
  }
  const u16* Ab = xm2;
  __shared__ __align__(16) char smem[131072];
  u16* SM = (u16*)smem;
  int m0 = blockIdx.y * 256;
  int n0 = blockIdx.x * 256;
  int tid = threadIdx.x;
  int lane = tid & 63, w = tid >> 6;
  int wm = (w >> 2) * 128, wn = (w & 3) * 64;
  int l15 = lane & 15, l4 = lane >> 4;
  f32x4 zero = {0.f, 0.f, 0.f, 0.f};
  f32x4 acc[8][4];
  #pragma unroll
  for (int i = 0; i < 8; i++)
    #pragma unroll
    for (int j = 0; j < 4; j++) acc[i][j] = zero;

  int rr = tid & 127, kc1 = tid >> 7;

  #define KA8(Tt) (mode == 0 ? (((Tt) * 64 < 512) ? (Tt) * 64 : (Tt) * 64 - 512) : (Tt) * 64)
  #define KB8(Tt) (mode == 0 ? (((Tt) * 64 < 1024) ? (Tt) * 64 : (Tt) * 64 - 1024) : (Tt) * 64)

  #define STAGEU(c, Tt, u) do{ \
    const u16* gb = (((u) & 1) == 0) ? Ab : Bb; \
    long rs = (((u) & 1) == 0) ? 1024 : (long)ldb; \
    int base0 = (((u) & 1) == 0) ? m0 : n0; \
    int tk = (((u) & 1) == 0) ? KA8(Tt) : KB8(Tt); \
    int r2 = ((u) >> 1) * 128 + rr; \
    long gsrc = (long)(base0 + r2) * rs + tk; \
    u16* lb = SM + (c) * 32768 + ((((u) & 1) == 0) ? 0 : 16384); \
    gload16(gb + gsrc + kc1 * 8,       lb + (kc1 * 256 + r2) * 8); \
    gload16(gb + gsrc + (kc1 + 4) * 8, lb + ((kc1 + 4) * 256 + r2) * 8); \
  }while(0)

  STAGEU(0, 0, 0); STAGEU(0, 0, 1); STAGEU(0, 0, 2); STAGEU(0, 0, 3);

  int cur = 0;
  for (int T = 0; T < NT; T++){
    int nxt = cur ^ 1;
    int more = (T + 1 < NT);
    s16x8 af[8];
    #pragma unroll
    for (int q = 0; q < 4; q++){
      if (more) STAGEU(nxt, T + 1, q);
      if (q == 0){
        if (more) asm volatile("s_waitcnt vmcnt(2)" ::: "memory");
        else      asm volatile("s_waitcnt vmcnt(0)" ::: "memory");
      }
      __builtin_amdgcn_s_barrier();
      __builtin_amdgcn_sched_barrier(0);
      int ks = q >> 1, jh = q & 1;
      if (jh == 0){
        #pragma unroll
        for (int i = 0; i < 8; i++)
          af[i] = *(const s16x8*)(SM + cur * 32768 +
                    ((ks * 4 + l4) * 256 + (wm + i * 16 + l15)) * 8);
      }
      s16x8 b0 = *(const s16x8*)(SM + cur * 32768 + 16384 +
                    ((ks * 4 + l4) * 256 + (wn + (jh * 2) * 16 + l15)) * 8);
      s16x8 b1 = *(const s16x8*)(SM + cur * 32768 + 16384 +
                    ((ks * 4 + l4) * 256 + (wn + (jh * 2 + 1) * 16 + l15)) * 8);
      __builtin_amdgcn_s_setprio(1);
      #pragma unroll
      for (int i = 0; i < 8; i++){
        acc[i][jh * 2]     = mfma16(af[i], b0, acc[i][jh * 2]);
        acc[i][jh * 2 + 1] = mfma16(af[i], b1, acc[i][jh * 2 + 1]);
      }
      __builtin_amdgcn_s_setprio(0);
    }
    __builtin_amdgcn_s_barrier();
    __builtin_amdgcn_sched_barrier(0);
    cur = nxt;
  }
  #undef STAGEU
  #undef KA8
  #undef KB8

  int mbase = m0 + wm + l4 * 4;
  int nbase = n0 + wn + l15;
  if (mode == 0){
    u16* Cz = C + (long)z * ((long)MTOT * 1024);
    #pragma unroll
    for (int j = 0; j < 4; j++){
      int n = nbase + j * 16;
      float badd = ldf(bias, (long)z * DD + n, isbf);
      #pragma unroll
      for (int i = 0; i < 8; i++)
        #pragma unroll
        for (int r = 0; r < 4; r++){
          float qv = acc[i][j][r] + badd;
          u16 hi = f2bf(qv);
          u16 lo = f2bf(qv - bf2f(hi));
          long rb = (long)(mbase + i * 16 + r) * 1024;
          Cz[rb + n] = hi;
          Cz[rb + 512 + n] = lo;
        }
    }
  } else {
    #pragma unroll
    for (int i = 0; i < 8; i++){
      int mrow = mbase + i * 16;
      int b = mrow >> 9, s = mrow & (SS - 1);
      #pragma unroll
      for (int j = 0; j < 4; j++){
        int n = nbase + j * 16;
        float badd = ldf(bias, (long)z * DD + n, isbf);
        ushort4 pk;
        pk.x = f2bf(acc[i][j][0] + badd); pk.y = f2bf(acc[i][j][1] + badd);
        pk.z = f2bf(acc[i][j][2] + badd); pk.w = f2bf(acc[i][j][3] + badd);
        *(ushort4*)&C[((long)(z * 8 + b) * DD + n) * SS + s] = pk;
      }
    }
  }
}

// ---------- 8-phase attn@v -> cat (k_proj8 mode-1 geometry; EP_CAT epilogue) ----------
__global__ __launch_bounds__(512, 2) void k_cat8(
    const u16* __restrict__ attn, const u16* __restrict__ vT,
    u16* __restrict__ cat, const int* __restrict__ dflag)
{
  int z = blockIdx.z;
  const u16* Ab = attn + (long)z * 262144;
  const u16* Bb = vT + (long)z * 262144;
  __shared__ __align__(16) char smem[131072];
  u16* SM = (u16*)smem;
  int m0 = blockIdx.y * 256;
  int n0 = blockIdx.x * 256;
  int tid = threadIdx.x;
  int lane = tid & 63, w = tid >> 6;
  int wm = (w >> 2) * 128, wn = (w & 3) * 64;
  int l15 = lane & 15, l4 = lane >> 4;
  f32x4 zero = {0.f, 0.f, 0.f, 0.f};
  f32x4 acc[8][4];
  #pragma unroll
  for (int i = 0; i < 8; i++)
    #pragma unroll
    for (int j = 0; j < 4; j++) acc[i][j] = zero;

  int rr = tid & 127, kc1 = tid >> 7;

  #define STAGEU(c, Tt, u) do{ \
    const u16* gb = (((u) & 1) == 0) ? Ab : Bb; \
    int base0 = (((u) & 1) == 0) ? m0 : n0; \
    int r2 = ((u) >> 1) * 128 + rr; \
    long gsrc = (long)(base0 + r2) * 512 + (Tt) * 64; \
    u16* lb = SM + (c) * 32768 + ((((u) & 1) == 0) ? 0 : 16384); \
    gload16(gb + gsrc + kc1 * 8,       lb + (kc1 * 256 + r2) * 8); \
    gload16(gb + gsrc + (kc1 + 4) * 8, lb + ((kc1 + 4) * 256 + r2) * 8); \
  }while(0)

  STAGEU(0, 0, 0); STAGEU(0, 0, 1); STAGEU(0, 0, 2); STAGEU(0, 0, 3);

  int cur = 0;
  for (int T = 0; T < 8; T++){
    int nxt = cur ^ 1;
    int more = (T + 1 < 8);
    s16x8 af[8];
    #pragma unroll
    for (int q = 0; q < 4; q++){
      if (more) STAGEU(nxt, T + 1, q);
      if (q == 0){
        if (more) asm volatile("s_waitcnt vmcnt(2)" ::: "memory");
        else      asm volatile("s_waitcnt vmcnt(0)" ::: "memory");
      }
      __builtin_amdgcn_s_barrier();
      __builtin_amdgcn_sched_barrier(0);
      int ks = q >> 1, jh = q & 1;
      if (jh == 0){
        #pragma unroll
        for (int i = 0; i < 8; i++)
          af[i] = *(const s16x8*)(SM + cur * 32768 +
                    ((ks * 4 + l4) * 256 + (wm + i * 16 + l15)) * 8);
      }
      s16x8 b0 = *(const s16x8*)(SM + cur * 32768 + 16384 +
                    ((ks * 4 + l4) * 256 + (wn + (jh * 2) * 16 + l15)) * 8);
      s16x8 b1 = *(const s16x8*)(SM + cur * 32768 + 16384 +
                    ((ks * 4 + l4) * 256 + (wn + (jh * 2 + 1) * 16 + l15)) * 8);
      __builtin_amdgcn_s_setprio(1);
      #pragma unroll
      for (int i = 0; i < 8; i++){
        acc[i][jh * 2]     = mfma16(af[i], b0, acc[i][jh * 2]);
        acc[i][jh * 2 + 1] = mfma16(af[i], b1, acc[i][jh * 2 + 1]);
      }
      __builtin_amdgcn_s_setprio(0);
    }
    __builtin_amdgcn_s_barrier();
    __builtin_amdgcn_sched_barrier(0);
    cur = nxt;
  }
  #undef STAGEU

  int mbase = m0 + wm + l4 * 4;
  int nbase = n0 + wn + l15;
  int h = z >> 3, b = z & 7;
  #pragma unroll
  for (int i = 0; i < 8; i++){
    int s = mbase + i * 16;
    #pragma unroll
    for (int j = 0; j < 4; j++){
      int n = nbase + j * 16;
      #pragma unroll
      for (int r = 0; r < 4; r++)
        cat[((long)b * SS + s + r) * HD + (long)h * DD + n] = f2bf(acc[i][j][r]);
    }
  }
}

// ---------- 8-phase fused scores+softmax (r25-proven) ----------
__global__ __launch_bounds__(512, 2) void k_fsm8(
    const u16* __restrict__ q2, const u16* __restrict__ k2,
    u16* __restrict__ P, float scale, const int* __restrict__ dflag)
{
  int z = blockIdx.z;
  const u16* Aq = q2 + (long)z * 524288;
  const u16* Bk = k2 + (long)z * 524288;
  __shared__ __align__(16) char smem[163840];   // 2 x (16KB A + 64KB B)
  u16* SM = (u16*)smem;
  int m0 = blockIdx.x * 128;
  int tid = threadIdx.x;
  int lane = tid & 63, w = tid >> 6;
  int wn = w * 64;
  int l15 = lane & 15, l4 = lane >> 4;
  f32x4 zero = {0.f, 0.f, 0.f, 0.f};
  f32x4 acc[8][4];
  #pragma unroll
  for (int i = 0; i < 8; i++)
    #pragma unroll
    for (int j = 0; j < 4; j++) acc[i][j] = zero;

  int kcl = tid >> 7, rowt = tid & 127;

  #define STAGEUF(c, Tt, u) do{ \
    if ((u) == 0){ \
      int ka = ((Tt) * 64 < 512) ? (Tt) * 64 : (Tt) * 64 - 512; \
      long g0 = (long)(m0 + rowt) * 1024 + ka; \
      u16* lb = SM + (long)(c) * 40960; \
      gload16(Aq + g0 + kcl * 8,       lb + (kcl * 128 + rowt) * 8); \
      gload16(Aq + g0 + (kcl + 4) * 8, lb + ((kcl + 4) * 128 + rowt) * 8); \
    } else { \
      int ub = (u) - 1; \
      int kb = ((Tt) * 64 < 1024) ? (Tt) * 64 : (Tt) * 64 - 1024; \
      long g0 = (long)(ub * 128 + rowt) * 1024 + kb; \
      u16* lb = SM + (long)(c) * 40960 + 8192; \
      gload16(Bk + g0 + kcl * 8,       lb + (kcl * 512 + ub * 128 + rowt) * 8); \
      gload16(Bk + g0 + (kcl + 4) * 8, lb + ((kcl + 4) * 512 + ub * 128 + rowt) * 8); \
    } \
  }while(0)

  STAGEUF(0, 0, 0); STAGEUF(0, 0, 1); STAGEUF(0, 0, 2);
  STAGEUF(0, 0, 3); STAGEUF(0, 0, 4);

  int cur = 0;
  for (int T = 0; T < 24; T++){
    int nxt = cur ^ 1;
    int more = (T + 1 < 24);
    s16x8 af[8];
    #pragma unroll
    for (int q = 0; q < 4; q++){
      if (q == 0){
        if (more){ STAGEUF(nxt, T + 1, 0); STAGEUF(nxt, T + 1, 1); }
        if (more) asm volatile("s_waitcnt vmcnt(4)" ::: "memory");
        else      asm volatile("s_waitcnt vmcnt(0)" ::: "memory");
      } else {
        if (more) STAGEUF(nxt, T + 1, q + 1);
      }
      __builtin_amdgcn_s_barrier();
      __builtin_amdgcn_sched_barrier(0);
      int ks = q >> 1, jh = q & 1;
      if (jh == 0){
        #pragma unroll
        for (int i = 0; i < 8; i++)
          af[i] = *(const s16x8*)(SM + (long)cur * 40960 +
                    ((ks * 4 + l4) * 128 + (i * 16 + l15)) * 8);
      }
      s16x8 b0 = *(const s16x8*)(SM + (long)cur * 40960 + 8192 +
                    ((ks * 4 + l4) * 512 + (wn + (jh * 2) * 16 + l15)) * 8);
      s16x8 b1 = *(const s16x8*)(SM + (long)cur * 40960 + 8192 +
                    ((ks * 4 + l4) * 512 + (wn + (jh * 2 + 1) * 16 + l15)) * 8);
      __builtin_amdgcn_s_setprio(1);
      #pragma unroll
      for (int i = 0; i < 8; i++){
        acc[i][jh * 2]     = mfma16(af[i], b0, acc[i][jh * 2]);
        acc[i][jh * 2 + 1] = mfma16(af[i], b1, acc[i][jh * 2 + 1]);
      }
      __builtin_amdgcn_s_setprio(0);
    }
    __builtin_amdgcn_s_barrier();
    __builtin_amdgcn_sched_barrier(0);
    cur = nxt;
  }
  #undef STAGEUF

  float* sred = (float*)smem;
  float* srow = (float*)(smem + 4096);

  #pragma unroll
  for (int i = 0; i < 8; i++)
    #pragma unroll
    for (int j = 0; j < 4; j++)
      acc[i][j] *= scale;

  #pragma unroll
  for (int i = 0; i < 8; i++)
    #pragma unroll
    for (int r = 0; r < 4; r++){
      float m = fmaxf(fmaxf(acc[i][0][r], acc[i][1][r]),
                      fmaxf(acc[i][2][r], acc[i][3][r]));
      #pragma unroll
      for (int off = 1; off < 16; off <<= 1) m = fmaxf(m, __shfl_xor(m, off, 64));
      if (l15 == 0) sred[w * 128 + l4 * 4 + i * 16 + r] = m;
    }
  __syncthreads();
  if (tid < 128){
    float m = sred[tid];
    #pragma unroll
    for (int w2 = 1; w2 < 8; w2++) m = fmaxf(m, sred[w2 * 128 + tid]);
    srow[tid] = m;
  }
  __syncthreads();
  #pragma unroll
  for (int i = 0; i < 8; i++)
    #pragma unroll
    for (int r = 0; r < 4; r++){
      float rm = srow[l4 * 4 + i * 16 + r];
      float s = 0.f;
      #pragma unroll
      for (int j = 0; j < 4; j++){
        float e = expf(acc[i][j][r] - rm);
        acc[i][j][r] = e;
        s += e;
      }
      #pragma unroll
      for (int off = 1; off < 16; off <<= 1) s += __shfl_xor(s, off, 64);
      if (l15 == 0) sred[w * 128 + l4 * 4 + i * 16 + r] = s;
    }
  __syncthreads();
  if (tid < 128){
    float s = 0.f;
    #pragma unroll
    for (int w2 = 0; w2 < 8; w2++) s += sred[w2 * 128 + tid];
    srow[tid] = 1.f / s;
  }
  __syncthreads();
  u16* Pz = P + (long)z * ((long)SS * SS);
  u16* pb = (u16*)(smem + 8192);
  const int PST = 520;
  #pragma unroll
  for (int ii = 0; ii < 4; ii++){
    __syncthreads();
    #pragma unroll
    for (int s2 = 0; s2 < 2; s2++){
      int i = ii * 2 + s2;
      #pragma unroll
      for (int r = 0; r < 4; r++){
        int rl = l4 * 4 + i * 16 + r;
        float inv = srow[rl];
        #pragma unroll
        for (int j = 0; j < 4; j++)
          pb[(s2 * 16 + l4 * 4 + r) * PST + wn + j * 16 + l15] = f2bf(acc[i][j][r] * inv);
      }
    }
    __syncthreads();
    #pragma unroll
    for (int p = 0; p < 8; p++){
      int chunk = tid + p * 512;
      int lr = chunk >> 7, c8 = chunk & 127;
      ushort4 v = *(ushort4*)&pb[lr * PST + c8 * 4];
      *(ushort4*)&Pz[(long)(m0 + ii * 32 + lr) * SS + c8 * 4] = v;
    }
  }
}

// ---------- 8-phase FF1: relu(x1b @ W1T^T + b1), tile 128(M) x 256(N), K=512 ----------
// LDS: 2 bufs x (A 16KB + B 32KB) = 96 KB. u16 units: buf stride 24576, B off 8192.
// 3 staging units/tile (u0=A, u1/u2=B halves), 2 gloads each; issued at q0/q1/q2.
// FIFO: 6 outstanding at tile entry + 2 issued at q0 -> wait vmcnt(2). 8 waves 2Mx4N.
__global__ __launch_bounds__(512, 2) void k_ff18(
    const u16* __restrict__ A, const u16* __restrict__ Bt,
    u16* __restrict__ C, const void* __restrict__ bias,
    const int* __restrict__ dflag)
{
  int isbf = dflag[0];
  __shared__ __align__(16) char smem[98304];
  u16* SM = (u16*)smem;
  int m0 = blockIdx.y * 128;   // 32 m-tiles
  int n0 = blockIdx.x * 256;   // 8 n-tiles
  int tid = threadIdx.x;
  int lane = tid & 63, w = tid >> 6;
  int wm2 = (w >> 2) * 64, wn2 = (w & 3) * 64;
  int l15 = lane & 15, l4 = lane >> 4;
  f32x4 zero = {0.f, 0.f, 0.f, 0.f};
  f32x4 acc[4][4];
  #pragma unroll
  for (int i = 0; i < 4; i++)
    #pragma unroll
    for (int j = 0; j < 4; j++) acc[i][j] = zero;

  int kc1 = tid >> 7, rr = tid & 127;

  #define STAGEUX(c, Tt, u) do{ \
    if ((u) == 0){ \
      long g0 = (long)(m0 + rr) * 512 + (Tt) * 64; \
      u16* lb = SM + (c) * 24576; \
      gload16(A + g0 + kc1 * 8,       lb + (kc1 * 128 + rr) * 8); \
      gload16(A + g0 + (kc1 + 4) * 8, lb + ((kc1 + 4) * 128 + rr) * 8); \
    } else { \
      int r2 = ((u) - 1) * 128 + rr; \
      long g0 = (long)(n0 + r2) * 512 + (Tt) * 64; \
      u16* lb = SM + (c) * 24576 + 8192; \
      gload16(Bt + g0 + kc1 * 8,       lb + (kc1 * 256 + r2) * 8); \
      gload16(Bt + g0 + (kc1 + 4) * 8, lb + ((kc1 + 4) * 256 + r2) * 8); \
    } \
  }while(0)

  STAGEUX(0, 0, 0); STAGEUX(0, 0, 1); STAGEUX(0, 0, 2);

  int cur = 0;
  for (int T = 0; T < 8; T++){
    int nxt = cur ^ 1;
    int more = (T + 1 < 8);
    s16x8 af[4];
    #pragma unroll
    for (int q = 0; q < 4; q++){
      if (q < 3 && more) STAGEUX(nxt, T + 1, q);
      if (q == 0){
        if (more) asm volatile("s_waitcnt vmcnt(2)" ::: "memory");
        else      asm volatile("s_waitcnt vmcnt(0)" ::: "memory");
      }
      __builtin_amdgcn_s_barrier();
      __builtin_amdgcn_sched_barrier(0);
      int ks = q >> 1, jh = q & 1;
      if (jh == 0){
        #pragma unroll
        for (int i = 0; i < 4; i++)
          af[i] = *(const s16x8*)(SM + cur * 24576 +
                    ((ks * 4 + l4) * 128 + (wm2 + i * 16 + l15)) * 8);
      }
      s16x8 b0 = *(const s16x8*)(SM + cur * 24576 + 8192 +
                    ((ks * 4 + l4) * 256 + (wn2 + (jh * 2) * 16 + l15)) * 8);
      s16x8 b1 = *(const s16x8*)(SM + cur * 24576 + 8192 +
                    ((ks * 4 + l4) * 256 + (wn2 + (jh * 2 + 1) * 16 + l15)) * 8);
      __builtin_amdgcn_s_setprio(1);
      #pragma unroll
      for (int i = 0; i < 4; i++){
        acc[i][jh * 2]     = mfma16(af[i], b0, acc[i][jh * 2]);
        acc[i][jh * 2 + 1] = mfma16(af[i], b1, acc[i][jh * 2 + 1]);
      }
      __builtin_amdgcn_s_setprio(0);
    }
    __builtin_amdgcn_s_barrier();
    __builtin_amdgcn_sched_barrier(0);
    cur = nxt;
  }
  #undef STAGEUX

  int mbase = m0 + wm2 + l4 * 4;
  int nbase = n0 + wn2 + l15;
  #pragma unroll
  for (int j = 0; j < 4; j++){
    int n = nbase + j * 16;
    float badd = ldf(bias, n, isbf);
    #pragma unroll
    for (int i = 0; i < 4; i++)
      #pragma unroll
      for (int r = 0; r < 4; r++)
        C[(long)(mbase + i * 16 + r) * NFF + n] = f2bf(fmaxf(acc[i][j][r] + badd, 0.f));
  }
}

// LayerNorm f32 -> bf16 (+ optional f32), one wave per row of 512
template<bool WF32>
__global__ __launch_bounds__(256) void k_ln(
    const float* __restrict__ X, const void* __restrict__ g, const void* __restrict__ be,
    u16* __restrict__ Yb, float* __restrict__ Yf, const int* __restrict__ dflag)
{
  int isbf = dflag[0];
  int row = blockIdx.x * 4 + (threadIdx.x >> 6);
  int lane = threadIdx.x & 63;
  const float* p = X + (long)row * DD + lane * 8;
  float4 v0 = *(const float4*)p;
  float4 v1 = *(const float4*)(p + 4);
  float v[8] = {v0.x, v0.y, v0.z, v0.w, v1.x, v1.y, v1.z, v1.w};
  float s = 0.f;
  #pragma unroll
  for (int i = 0; i < 8; i++) s += v[i];
  s = wave_redsum(s);
  float mu = s * (1.f / DD);
  float d_[8], sq = 0.f;
  #pragma unroll
  for (int i = 0; i < 8; i++){ d_[i] = v[i] - mu; sq += d_[i] * d_[i]; }
  sq = wave_redsum(sq);
  float rs = 1.f / sqrtf(sq * (1.f / DD) + 1e-5f);
  #pragma unroll
  for (int i = 0; i < 8; i++){
    int dd = lane * 8 + i;
    float y = ldf(g, dd, isbf) * d_[i] * rs + ldf(be, dd, isbf);
    Yb[(long)row * DD + dd] = f2bf(y);
    if (WF32) Yf[(long)row * DD + dd] = y;
  }
}

extern "C" void kernel_launch(void* const* d_in, const int* in_sizes, int n_in,
                              void* d_out, int out_size, void* d_ws, size_t ws_size,
                              hipStream_t stream)
{
  const int* tokens = (const int*)d_in[0];
  const void* emb = d_in[1];
  const void* pe  = d_in[2];
  const void* Wq  = d_in[3];
  const void* bq  = d_in[4];
  const void* Wk  = d_in[5];
  const void* bk  = d_in[6];
  const void* Wv  = d_in[7];
  const void* bv  = d_in[8];
  const void* Wo  = d_in[9];
  const void* bo  = d_in[10];
  const void* g1  = d_in[11];
  const void* be1 = d_in[12];
  const void* W1  = d_in[13];
  const void* b1  = d_in[14];
  const void* W2  = d_in[15];
  const void* b2  = d_in[16];
  const void* g2  = d_in[17];
  const void* be2 = d_in[18];
  const void* Wf  = d_in[19];
  const void* bfb = d_in[20];
  float* out = (float*)d_out;   // reference output dtype = float32
  char* ws = (char*)d_ws;
  char* DO = (char*)d_out;

  const size_t MB = 1ull << 20;
  // ---- d_ws (39.3 MiB; <=69 MiB evidenced safe) ----
  int* dflag = (int*)ws;
  u16* x2b   = (u16*)(ws + 1 * MB);        // [1,5)
  u16* WfT   = (u16*)(ws + 8 * MB);        // [8,39.25)  bf16 [32000][512]

  // ---- d_out as scratch (380 of 500 MiB; all dead before logits) ----
  float* x    = (float*)(DO + 0 * MB);     // [0,8)
  u16*   xm2  = (u16*)(DO + 8 * MB);       // [8,16)    [4096][1024] = [xh|xl]
  u16*   Wq2  = (u16*)(DO + 16 * MB);      // [16,24)   [8][512][1024] = [wh|wl]
  u16*   Wk2  = (u16*)(DO + 24 * MB);      // [24,32)
  u16*   WvT  = (u16*)(DO + 32 * MB);      // [32,36)   [8][512][512]
  u16*   WoT  = (u16*)(DO + 36 * MB);      // [36,40)   [512][4096]
  u16*   W1T  = (u16*)(DO + 40 * MB);      // [40,42)   [2048][512]
  u16*   W2T  = (u16*)(DO + 42 * MB);      // [42,44)   [512][2048]
  u16*   q2   = (u16*)(DO + 48 * MB);      // [48,112)  [8][4096][1024] = [qh|ql]
  u16*   k2   = (u16*)(DO + 112 * MB);     // [112,176) [8][4096][1024] = [kh|kl]
  u16*   attn = (u16*)(DO + 240 * MB);     // [240,272) [64][512][512] bf16
  u16*   vT   = (u16*)(DO + 272 * MB);     // [272,304) [64][512 d][512 s]
  u16*   cat  = (u16*)(DO + 304 * MB);     // [304,336) [4096][4096]
  float* proj = (float*)(DO + 336 * MB);   // [336,344)
  float* x1f  = (float*)(DO + 344 * MB);   // [344,352)
  u16*   x1b  = (u16*)(DO + 352 * MB);     // [352,356)
  u16*   ff1  = (u16*)(DO + 356 * MB);     // [356,372) [4096][2048]
  float* ff2  = (float*)(DO + 372 * MB);   // [372,380)

  const float scale = 0.04419417382415922f;  // 1/sqrt(512)

  k_dflag<<<1, 1, 0, stream>>>(pe, dflag);
  k_embed<<<dim3(4096), 256, 0, stream>>>(tokens, emb, pe, x, xm2, dflag);

  // one-time weight prep (2 launches)
  k_wsplitT<<<dim3(16, 16, 16), 256, 0, stream>>>(Wq, Wk, Wq2, Wk2, dflag);
  k_transAll<<<dim3(22144), 256, 0, stream>>>(
      Wv, Wo, W1, W2, Wf, WvT, WoT, W1T, W2T, WfT, dflag);

  // merged q/k/v projections: 8-phase counted-vmcnt schedule (r21/r22-proven)
  k_proj8<<<dim3(2, 16, 24), 512, 0, stream>>>(
      xm2, Wq2, Wk2, WvT, q2, k2, vT, bq, bk, bv, dflag);

  // fused scores+softmax -> attn bf16: 8-phase counted-vmcnt schedule
  k_fsm8<<<dim3(4, 1, 64), 512, 0, stream>>>(q2, k2, attn, scale, dflag);

  // o = attn @ v -> cat (torch.cat head order): 8-phase schedule
  k_cat8<<<dim3(2, 2, 64), 512, 0, stream>>>(attn, vT, cat, dflag);

  // proj = cat @ Wo + bo + x (128^2 kernel)
  k_mfma<EP_F32RES, false><<<dim3(4, 32, 1), 256, 0, stream>>>(
      cat, 0, HD, WoT, 0, proj, bo, x, HD, DD, 0.f, dflag);
  k_ln<true><<<dim3(1024), 256, 0, stream>>>(proj, g1, be1, x1b, x1f, dflag);

  // ff1 = relu(x1 @ W1 + b1): 8-phase 128x256 kernel (256 blocks)
  k_ff18<<<dim3(8, 32, 1), 512, 0, stream>>>(x1b, W1T, ff1, b1, dflag);
  // ff2 = ff1 @ W2 + b2 + x1 (128^2 kernel)
  k_mfma<EP_F32RES, false><<<dim3(4, 32, 1), 256, 0, stream>>>(
      ff1, 0, NFF, W2T, 0, ff2, b2, x1f, NFF, DD, 0.f, dflag);
  k_ln<false><<<dim3(1024), 256, 0, stream>>>(ff2, g2, be2, x2b, nullptr, dflag);

  // logits = x2 @ Wf + bf -> f32 out: 8-phase counted-vmcnt kernel (NT = 512/64)
  k_out8<<<dim3(16, 125, 1), 512, 0, stream>>>(x2b, WfT, out, bfb, 8, dflag);
}